// Round 2
// baseline (1363.748 us; speedup 1.0000x reference)
//
#include <hip/hip_runtime.h>
#include <cstddef>
#include <cstdint>

// Problem constants
#define BB   64
#define NN   512
#define BN   (BB*NN)          // 32768
#define HBN  16384            // nodes per half
#define EE   524288
#define DA   70
#define DE   14
#define DH   200
#define DI   6
#define T_SCALE 0.07071067811865475f   // sqrt(1/200)

typedef __attribute__((ext_vector_type(8))) short short8;
typedef __attribute__((ext_vector_type(4))) float f32x4;

__device__ __forceinline__ short f2bf(float x) {
    union { float f; unsigned u; } v; v.f = x;
    const unsigned r = v.u + 0x7FFFu + ((v.u >> 16) & 1u);   // RNE
    return (short)(r >> 16);
}
__device__ __forceinline__ float bf2f(short s) {
    union { unsigned u; float f; } v;
    v.u = ((unsigned)(unsigned short)s) << 16;
    return v.f;
}

// ---------------------------------------------------------------------------
// Kernel 1: per-node  h = layernorm(relu(atom @ W_atom))
// ---------------------------------------------------------------------------
__global__ __launch_bounds__(256) void node_kernel(
    const float* __restrict__ atom1, const float* __restrict__ atom2,
    const float* __restrict__ W_atom,
    const float* __restrict__ ln_g, const float* __restrict__ ln_b,
    float* __restrict__ h1, float* __restrict__ h2)
{
    const int side = blockIdx.y;
    const float* atom = side ? atom2 : atom1;
    float* h = side ? h2 : h1;
    const int node0 = blockIdx.x * 4;
    const int tid = threadIdx.x;

    __shared__ float arow[4][DA];
    __shared__ float vals[4][DH];

    for (int i = tid; i < 4*DA; i += 256) {
        const int n = i / DA, k = i % DA;
        arow[n][k] = atom[(size_t)(node0+n)*DA + k];
    }
    __syncthreads();

    if (tid < DH) {
        float a0 = 0.f, a1 = 0.f, a2 = 0.f, a3 = 0.f;
        #pragma unroll 7
        for (int k = 0; k < DA; k++) {
            const float w = W_atom[k*DH + tid];
            a0 += arow[0][k]*w; a1 += arow[1][k]*w;
            a2 += arow[2][k]*w; a3 += arow[3][k]*w;
        }
        vals[0][tid] = fmaxf(a0, 0.f);
        vals[1][tid] = fmaxf(a1, 0.f);
        vals[2][tid] = fmaxf(a2, 0.f);
        vals[3][tid] = fmaxf(a3, 0.f);
    }
    __syncthreads();

    const int wv = tid >> 6, lane = tid & 63;
    float v0 = vals[wv][lane];
    float v1 = vals[wv][64+lane];
    float v2 = vals[wv][128+lane];
    float v3 = (lane < 8) ? vals[wv][192+lane] : 0.0f;
    float s  = v0+v1+v2+v3;
    float s2 = v0*v0+v1*v1+v2*v2+v3*v3;
    #pragma unroll
    for (int off = 1; off < 64; off <<= 1) {
        s  += __shfl_xor(s,  off, 64);
        s2 += __shfl_xor(s2, off, 64);
    }
    const float mean = s * (1.0f/DH);
    const float var  = s2 * (1.0f/DH) - mean*mean;
    const float rstd = rsqrtf(var + 1e-5f);
    const size_t base = (size_t)(node0+wv)*DH;
    h[base + lane]       = ln_g[lane]     *(v0-mean)*rstd + ln_b[lane];
    h[base + 64 + lane]  = ln_g[64+lane]  *(v1-mean)*rstd + ln_b[64+lane];
    h[base + 128 + lane] = ln_g[128+lane] *(v2-mean)*rstd + ln_b[128+lane];
    if (lane < 8)
        h[base + 192 + lane] = ln_g[192+lane]*(v3-mean)*rstd + ln_b[192+lane];
}

// ---------------------------------------------------------------------------
// Counting sort by dst: hist -> scan(+sentinel) -> scatter (rank only)
// ---------------------------------------------------------------------------
__global__ __launch_bounds__(256) void hist_kernel(
    const int* __restrict__ edst1, const int* __restrict__ edst2,
    int* __restrict__ deg1, int* __restrict__ deg2)
{
    const int e = blockIdx.x*256 + threadIdx.x;
    atomicAdd(&deg1[edst1[e]], 1);
    atomicAdd(&deg2[edst2[e]], 1);
}

__global__ __launch_bounds__(1024) void scan_kernel(
    const int* __restrict__ deg1, const int* __restrict__ deg2,
    int* __restrict__ start1, int* __restrict__ start2,
    int* __restrict__ cursor1, int* __restrict__ cursor2)
{
    const int side = blockIdx.x;
    const int* deg   = side ? deg2 : deg1;
    int* start  = side ? start2 : start1;
    int* cursor = side ? cursor2 : cursor1;

    __shared__ int part[1024];
    const int t = threadIdx.x;
    const int base = t * 32;
    int local[32];
    int sum = 0;
    #pragma unroll
    for (int i = 0; i < 32; i++) { local[i] = deg[base+i]; sum += local[i]; }
    part[t] = sum;
    __syncthreads();
    for (int off = 1; off < 1024; off <<= 1) {
        int v = (t >= off) ? part[t-off] : 0;
        __syncthreads();
        part[t] += v;
        __syncthreads();
    }
    int run = part[t] - sum;   // exclusive
    #pragma unroll
    for (int i = 0; i < 32; i++) {
        start[base+i] = run;
        cursor[base+i] = run;
        run += local[i];
    }
    if (t == 1023) start[BN] = run;   // sentinel == EE
}

__global__ __launch_bounds__(256) void scatter_kernel(
    const int* __restrict__ edst1, const int* __restrict__ edst2,
    int* __restrict__ cursor1, int* __restrict__ cursor2,
    int* __restrict__ rank1, int* __restrict__ rank2)
{
    const int e = blockIdx.x*256 + threadIdx.x;
    {
        const int d = edst1[e];
        rank1[e] = atomicAdd(&cursor1[d], 1);
    }
    {
        const int d = edst2[e];
        rank2[e] = atomicAdd(&cursor2[d], 1);
    }
}

// ---------------------------------------------------------------------------
// featgen: per-edge feature row (rank-ordered) -> featH[rank][32] bf16
//   k 0..13 = ef, 14..29 = rbf, 30 = 1.0 (bias hook), 31 = 0
// ---------------------------------------------------------------------------
__global__ __launch_bounds__(256) void featgen_kernel(
    const float* __restrict__ efeat1, const float* __restrict__ efeat2,
    const int* __restrict__ esrc1, const int* __restrict__ esrc2,
    const int* __restrict__ edst1, const int* __restrict__ edst2,
    const float* __restrict__ coords1, const float* __restrict__ coords2,
    const int* __restrict__ rank1, const int* __restrict__ rank2,
    short* __restrict__ featH1, short* __restrict__ featH2)
{
    const int side = blockIdx.y;
    const float* ef     = side ? efeat2  : efeat1;
    const int*   esrc   = side ? esrc2   : esrc1;
    const int*   edst   = side ? edst2   : edst1;
    const float* coords = side ? coords2 : coords1;
    const int*   rank   = side ? rank2   : rank1;
    short* featH = side ? featH2 : featH1;

    const int e = blockIdx.x*256 + threadIdx.x;
    const int src = esrc[e], dst = edst[e];

    short f[32];
    #pragma unroll
    for (int k = 0; k < 14; k++) f[k] = f2bf(ef[(size_t)e*DE + k]);

    const float dx = coords[src*3+0] - coords[dst*3+0];
    const float dy = coords[src*3+1] - coords[dst*3+1];
    const float dz = coords[src*3+2] - coords[dst*3+2];
    const float dist = sqrtf(dx*dx + dy*dy + dz*dz + 1e-12f);
    #pragma unroll
    for (int k = 0; k < 16; k++) {
        const float t = 3.2f*dist - 1.0666666667f*(float)k;
        f[14+k] = f2bf(__expf(-t*t));
    }
    f[30] = f2bf(1.0f);
    f[31] = 0;

    short* out = featH + (size_t)rank[e]*32;
    #pragma unroll
    for (int q = 0; q < 4; q++)
        *(short8*)&out[q*8] = *(short8*)&f[q*8];
}

// ---------------------------------------------------------------------------
// featpad: zero the 16-row pad past EE so tail tiles read finite zeros
// ---------------------------------------------------------------------------
__global__ __launch_bounds__(256) void featpad_kernel(
    short* __restrict__ featH1, short* __restrict__ featH2)
{
    const int i = threadIdx.x;   // 16*32 = 512 shorts... use 256 threads x2
    featH1[(size_t)EE*32 + i] = 0;
    featH1[(size_t)EE*32 + 256 + i] = 0;
    featH2[(size_t)EE*32 + i] = 0;
    featH2[(size_t)EE*32 + 256 + i] = 0;
}

// ---------------------------------------------------------------------------
// prep_wt: build WT[208][32] hi/lo for the edge projection.
// ---------------------------------------------------------------------------
__global__ __launch_bounds__(256) void prep_wt_kernel(
    const float* __restrict__ W_edge, const float* __restrict__ W_rbf,
    const float* __restrict__ b_rbf,
    short* __restrict__ WTH, short* __restrict__ WTL)
{
    const int idx = blockIdx.x*256 + threadIdx.x;
    if (idx >= 208*32) return;
    const int c = idx >> 5, k = idx & 31;
    float v = 0.f;
    if (c < 100) {
        if (k < 14) v = W_edge[k*100 + c];
    } else if (c < 200) {
        const int cc = c - 100;
        if (k >= 14 && k < 30) v = W_rbf[(k-14)*100 + cc];
        else if (k == 30) v = b_rbf[cc];
    }
    const short hi = f2bf(v);
    WTH[idx] = hi;
    WTL[idx] = f2bf(v - bf2f(hi));
}

// ---------------------------------------------------------------------------
// gather_mfma v4: persistent chunks. One wave owns 16 CONSECUTIVE nodes
// (contiguous edge range -> streaming feat reads). W staged once per block
// into LDS with stride-40 rows: bank = 4*((5*arow+aq) mod 8) -> exactly
// 8 words/bank, balanced (old stride-32 was 8-way serialized). start[] read
// once per wave (17 lanes) and served via v_readlane (SALU). Feat tile for
// the NEXT (node,tile) prefetched one full tile ahead; h-row RMW loads and
// ln_g/ln_b hoisted off the tail. Tail rows masked via rstd=0; feat has a
// zeroed 16-row pad, start[BN]=EE sentinel covers the last prefetch.
// ---------------------------------------------------------------------------
__global__ __launch_bounds__(256, 4) void gather_mfma(
    const short* __restrict__ featH1, const short* __restrict__ featH2,
    const int* __restrict__ start1, const int* __restrict__ start2,
    const short* __restrict__ WTH, const short* __restrict__ WTL,
    const float* __restrict__ ln_g, const float* __restrict__ ln_b,
    float* __restrict__ h1, float* __restrict__ h2)
{
    __shared__ short sWH[208*40];    // 16.6 KB, stride-40 (80B) rows
    __shared__ short sWL[208*40];    // 16.6 KB
    __shared__ float plane[4][216];

    const int tid = threadIdx.x;
    const int wv = tid >> 6, lane = tid & 63;
    const int arow = lane & 15, aq = lane >> 4;

    // stage W once per block (832 short8 per array)
    for (int f = tid; f < 832; f += 256) {
        const int d = f >> 2, cc = (f & 3) * 8;
        *(short8*)&sWH[d*40 + cc] = *(const short8*)&WTH[f*8];
        *(short8*)&sWL[d*40 + cc] = *(const short8*)&WTL[f*8];
    }
    __syncthreads();

    const int wid  = blockIdx.x*4 + wv;      // 0..4095
    const int side = wid >> 11;
    const int c0   = (wid & 2047) * 16;      // local node base for this wave
    const short* feat = side ? featH2 : featH1;
    const int*  start = side ? start2 : start1;
    float* h = side ? h2 : h1;

    // hoist ln params (lane-mapped)
    const float g0 = ln_g[lane],      b0 = ln_b[lane];
    const float g1 = ln_g[64+lane],   b1 = ln_b[64+lane];
    const float g2 = ln_g[128+lane],  b2 = ln_b[128+lane];
    const float g3 = (lane < 8) ? ln_g[192+lane] : 0.f;
    const float b3 = (lane < 8) ? ln_b[192+lane] : 0.f;

    // 17 start values for the chunk, one load, then readlane
    const int sidx = (lane < 17) ? lane : 0;
    const int sv = start[c0 + sidx];

    const int lb = arow*40 + aq*8;           // LDS element offset in a W tile

    int iC = 0;
    int stC = __builtin_amdgcn_readlane(sv, 0);
    int enC = __builtin_amdgcn_readlane(sv, 1);
    int t0 = 0;
    short8 aC = *(const short8*)&feat[(size_t)(stC + arow)*32 + aq*8];

    float colacc[13];
    #pragma unroll
    for (int nt = 0; nt < 13; nt++) colacc[nt] = 0.f;
    float musum = 0.f;

    while (true) {
        const int dgC = enC - stC;
        const bool last = (t0 + 16 >= dgC);
        const int iN = last ? iC + 1 : iC;           // uniform (SGPR)
        const int tN = last ? 0 : t0 + 16;
        const int stN = __builtin_amdgcn_readlane(sv, iN);
        // prefetch next tile (always valid: pad rows past EE are zero,
        // start[BN]=EE sentinel; within-chunk it is the next node's tile0)
        const short8 aN = *(const short8*)&feat[(size_t)(stN + tN + arow)*32 + aq*8];

        // prefetch the h row RMW loads when this node finishes
        const int node = c0 + iC;
        const size_t hbase = (size_t)node * DH;
        float hv0 = 0.f, hv1 = 0.f, hv2 = 0.f, hv3 = 0.f;
        if (last) {
            hv0 = h[hbase + lane];
            hv1 = h[hbase + 64 + lane];
            hv2 = h[hbase + 128 + lane];
            if (lane < 8) hv3 = h[hbase + 192 + lane];
        }

        f32x4 acc[13];
        #pragma unroll
        for (int nt = 0; nt < 13; nt++) {
            const short8 whv = *(const short8*)&sWH[nt*640 + lb];
            const short8 wlv = *(const short8*)&sWL[nt*640 + lb];
            f32x4 z = (f32x4){0.f,0.f,0.f,0.f};
            z = __builtin_amdgcn_mfma_f32_16x16x32_bf16(aC, whv, z, 0, 0, 0);
            z = __builtin_amdgcn_mfma_f32_16x16x32_bf16(aC, wlv, z, 0, 0, 0);
            acc[nt] = z;
        }
        // relu + per-row (per-edge) stats; row = t0 + aq*4 + r
        float sr[4] = {0.f,0.f,0.f,0.f}, s2r[4] = {0.f,0.f,0.f,0.f};
        #pragma unroll
        for (int nt = 0; nt < 13; nt++) {
            #pragma unroll
            for (int r = 0; r < 4; r++) {
                const float v = fmaxf(acc[nt][r], 0.f);
                acc[nt][r] = v;
                sr[r] += v; s2r[r] += v*v;
            }
        }
        #pragma unroll
        for (int off = 1; off < 16; off <<= 1) {
            #pragma unroll
            for (int r = 0; r < 4; r++) {
                sr[r]  += __shfl_xor(sr[r],  off, 64);
                s2r[r] += __shfl_xor(s2r[r], off, 64);
            }
        }
        #pragma unroll
        for (int r = 0; r < 4; r++) {
            const bool valid = (t0 + aq*4 + r) < dgC;
            const float mean = sr[r] * (1.0f/DH);
            const float var  = s2r[r] * (1.0f/DH) - mean*mean;
            const float rs   = rsqrtf(var + 1e-5f);
            const float rstd = valid ? rs : 0.f;
            musum += valid ? mean*rs : 0.f;
            #pragma unroll
            for (int nt = 0; nt < 13; nt++)
                colacc[nt] += rstd*acc[nt][r];
        }

        if (last) {
            // finish node: reduce over the 4 aq groups (rows partition)
            #pragma unroll
            for (int nt = 0; nt < 13; nt++) {
                colacc[nt] += __shfl_xor(colacc[nt], 16, 64);
                colacc[nt] += __shfl_xor(colacc[nt], 32, 64);
            }
            musum += __shfl_xor(musum, 16, 64);
            musum += __shfl_xor(musum, 32, 64);
            if (aq == 0) {
                #pragma unroll
                for (int nt = 0; nt < 13; nt++)
                    plane[wv][nt*16 + arow] = colacc[nt];
            }
            // wave-internal LDS producer/consumer: in-order, no barrier
            const float dgf = (float)dgC;
            h[hbase + lane]       = hv0 + g0*(plane[wv][lane]     - musum) + dgf*b0;
            h[hbase + 64 + lane]  = hv1 + g1*(plane[wv][64+lane]  - musum) + dgf*b1;
            h[hbase + 128 + lane] = hv2 + g2*(plane[wv][128+lane] - musum) + dgf*b2;
            if (lane < 8)
                h[hbase + 192 + lane] = hv3 + g3*(plane[wv][192+lane] - musum) + dgf*b3;
            if (iC == 15) break;
            #pragma unroll
            for (int nt = 0; nt < 13; nt++) colacc[nt] = 0.f;
            musum = 0.f;
            stC = stN;
            enC = __builtin_amdgcn_readlane(sv, iN + 1);
            iC = iN;
            t0 = 0;
        } else {
            t0 = tN;
        }
        aC = aN;
    }
}

// ---------------------------------------------------------------------------
// cvt (per half): h fp32 -> hb hi/lo [16384][224] rows + hbT hi/lo [32][224][512]
// ---------------------------------------------------------------------------
__global__ __launch_bounds__(256) void cvt_kernel(
    const float* __restrict__ h1, const float* __restrict__ h2, const int half,
    short* __restrict__ hbH1, short* __restrict__ hbL1,
    short* __restrict__ hbH2, short* __restrict__ hbL2,
    short* __restrict__ hTH1, short* __restrict__ hTL1,
    short* __restrict__ hTH2, short* __restrict__ hTL2)
{
    const int side = blockIdx.y;
    const float* h = side ? h2 : h1;
    short* hbH = side ? hbH2 : hbH1;
    short* hbL = side ? hbL2 : hbL1;
    short* hTH = side ? hTH2 : hTH1;
    short* hTL = side ? hTL2 : hTL1;

    const int nl0 = blockIdx.x * 64;          // local node
    const int bl = nl0 >> 9, m0 = nl0 & 511;
    const int ng0 = half*HBN + nl0;

    __shared__ short tH[64][226];
    __shared__ short tL[64][226];
    const int tid = threadIdx.x;
    for (int i = tid; i < 64*224; i += 256) {
        const int r = i / 224, c = i - r*224;
        const float v = (c < DH) ? h[(size_t)(ng0+r)*DH + c] : 0.f;
        const short hi = f2bf(v);
        const short lo = f2bf(v - bf2f(hi));
        tH[r][c] = hi; tL[r][c] = lo;
        hbH[(size_t)(nl0+r)*224 + c] = hi;
        hbL[(size_t)(nl0+r)*224 + c] = lo;
    }
    __syncthreads();
    for (int i = tid; i < 224*64; i += 256) {
        const int c = i >> 6, m = i & 63;
        const size_t o = ((size_t)bl*224 + c)*NN + m0 + m;
        hTH[o] = tH[m][c];
        hTL[o] = tL[m][c];
    }
}

// ---------------------------------------------------------------------------
// prep_w: W_down[400][200] -> WbTHI/LO[208][448] (transposed, padded, split)
// ---------------------------------------------------------------------------
__global__ __launch_bounds__(256) void prep_w_kernel(
    const float* __restrict__ W_down,
    short* __restrict__ WbTHI, short* __restrict__ WbTLO)
{
    const int idx = blockIdx.x*256 + threadIdx.x;
    if (idx >= 208*448) return;
    const int c = idx / 448, kk = idx - c*448;
    float v = 0.f;
    if (c < 200) {
        if (kk < 200) v = W_down[(size_t)kk*DH + c];
        else if (kk >= 224 && kk < 424) v = W_down[(size_t)(200 + kk - 224)*DH + c];
    }
    const short hi = f2bf(v);
    WbTHI[idx] = hi;
    WbTLO[idx] = f2bf(v - bf2f(hi));
}

// ---------------------------------------------------------------------------
// Fused attention v4: 16 Q-rows per block, 4 waves split 32 key-tiles;
// K/V streamed from global (L2); 3 barriers per block.
// XCD-aware block remap: dispatch ids == k (mod 8) land on XCD k (round-robin,
// m09); map them to batches 4k..4k+3 so each XCD's concurrent K/V working set
// is 4 x ~885KB ~= 3.5MB < 4MB L2 -> cross-block K/V reuse becomes L2 hits.
// ---------------------------------------------------------------------------
__global__ __launch_bounds__(256, 4) void attn_kernel(
    const short* __restrict__ QH, const short* __restrict__ QL,
    const short* __restrict__ KH, const short* __restrict__ KL,
    const short* __restrict__ VTH, const short* __restrict__ VTL,
    short* __restrict__ cb)
{
    const int id = blockIdx.x + (blockIdx.y << 5);   // gridDim.x == 32
    const int j  = id >> 3;
    const int b  = (id & 7)*4 + (j >> 5);            // half-local batch
    const int q0 = (j & 31) << 4;
    const short* Qh = QH + (size_t)b*NN*224;
    const short* Ql = QL + (size_t)b*NN*224;
    const short* Kh = KH + (size_t)b*NN*224;
    const short* Kl = KL + (size_t)b*NN*224;
    const short* Vh = VTH + (size_t)b*224*NN;
    const short* Vl = VTL + (size_t)b*224*NN;

    __shared__ short pb[16*520];              // 16.3 KB P bf16
    __shared__ float sm_[4][16];
    __shared__ float ss_[4][16];

    const int tid = threadIdx.x;
    const int wv = tid >> 6, lane = tid & 63;
    const int arow = lane & 15, aq = lane >> 4;

    const int qrow = q0 + arow;
    short8 qfh[7], qfl[7];
    #pragma unroll
    for (int k = 0; k < 7; k++) {
        qfh[k] = *(const short8*)&Qh[(size_t)qrow*224 + k*32 + aq*8];
        qfl[k] = *(const short8*)&Ql[(size_t)qrow*224 + k*32 + aq*8];
    }

    f32x4 acc[8];
    #pragma unroll
    for (int t = 0; t < 8; t++) acc[t] = (f32x4){0.f,0.f,0.f,0.f};

    #pragma unroll
    for (int t = 0; t < 8; t++) {
        const size_t kb = (size_t)((wv*8 + t)*16 + arow)*224;
        #pragma unroll
        for (int k = 0; k < 7; k++) {
            const short8 bh = *(const short8*)&Kh[kb + k*32 + aq*8];
            const short8 bl = *(const short8*)&Kl[kb + k*32 + aq*8];
            acc[t] = __builtin_amdgcn_mfma_f32_16x16x32_bf16(qfh[k], bh, acc[t], 0, 0, 0);
            acc[t] = __builtin_amdgcn_mfma_f32_16x16x32_bf16(qfh[k], bl, acc[t], 0, 0, 0);
            acc[t] = __builtin_amdgcn_mfma_f32_16x16x32_bf16(qfl[k], bh, acc[t], 0, 0, 0);
        }
    }

    float mr[4], sr[4], iv[4];
    #pragma unroll
    for (int r = 0; r < 4; r++) {
        float m = -1e30f;
        #pragma unroll
        for (int t = 0; t < 8; t++) {
            acc[t][r] *= T_SCALE;
            m = fmaxf(m, acc[t][r]);
        }
        m = fmaxf(m, __shfl_xor(m, 1, 64));
        m = fmaxf(m, __shfl_xor(m, 2, 64));
        m = fmaxf(m, __shfl_xor(m, 4, 64));
        m = fmaxf(m, __shfl_xor(m, 8, 64));
        mr[r] = m;
    }
    if (arow == 0) {
        #pragma unroll
        for (int r = 0; r < 4; r++) sm_[wv][aq*4+r] = mr[r];
    }
    __syncthreads();
    #pragma unroll
    for (int r = 0; r < 4; r++) {
        const int row = aq*4 + r;
        const float M = fmaxf(fmaxf(sm_[0][row], sm_[1][row]),
                              fmaxf(sm_[2][row], sm_[3][row]));
        float s = 0.f;
        #pragma unroll
        for (int t = 0; t < 8; t++) {
            const float e = __expf(acc[t][r] - M);
            acc[t][r] = e;
            s += e;
        }
        s += __shfl_xor(s, 1, 64);
        s += __shfl_xor(s, 2, 64);
        s += __shfl_xor(s, 4, 64);
        s += __shfl_xor(s, 8, 64);
        sr[r] = s;
    }
    if (arow == 0) {
        #pragma unroll
        for (int r = 0; r < 4; r++) ss_[wv][aq*4+r] = sr[r];
    }
    __syncthreads();
    #pragma unroll
    for (int r = 0; r < 4; r++) {
        const int row = aq*4 + r;
        iv[r] = 1.0f / (ss_[0][row] + ss_[1][row] + ss_[2][row] + ss_[3][row]);
    }

    #pragma unroll
    for (int t = 0; t < 8; t++) {
        const int col = (wv*8 + t)*16 + arow;
        #pragma unroll
        for (int r = 0; r < 4; r++)
            pb[(aq*4 + r)*520 + col] = f2bf(acc[t][r] * iv[r]);
    }
    __syncthreads();

    const int nbase = (wv == 0) ? 0 : 3*wv + 1;
    const int ncnt  = (wv == 0) ? 4 : 3;
    f32x4 pacc[4];
    #pragma unroll
    for (int t = 0; t < 4; t++) pacc[t] = (f32x4){0.f,0.f,0.f,0.f};

    for (int k0 = 0; k0 < NN; k0 += 32) {
        const short8 a = *(const short8*)&pb[arow*520 + k0 + aq*8];
        #pragma unroll
        for (int t = 0; t < 4; t++) {
            if (t < ncnt) {
                const size_t vb = (size_t)((nbase+t)*16 + arow)*NN + k0 + aq*8;
                const short8 bh = *(const short8*)&Vh[vb];
                const short8 bl = *(const short8*)&Vl[vb];
                pacc[t] = __builtin_amdgcn_mfma_f32_16x16x32_bf16(a, bh, pacc[t], 0, 0, 0);
                pacc[t] = __builtin_amdgcn_mfma_f32_16x16x32_bf16(a, bl, pacc[t], 0, 0, 0);
            }
        }
    }

    #pragma unroll
    for (int t = 0; t < 4; t++) {
        if (t < ncnt) {
            const int col = (nbase+t)*16 + arow;
            #pragma unroll
            for (int r = 0; r < 4; r++) {
                const int row = q0 + aq*4 + r;
                const short v = (col < DH) ? f2bf(pacc[t][r]) : (short)0;
                cb[((size_t)b*NN + row)*224 + col] = v;
            }
        }
    }
    if (wv == 3) {
        const int col = 208 + arow;
        #pragma unroll
        for (int r = 0; r < 4; r++) {
            const int row = q0 + aq*4 + r;
            cb[((size_t)b*NN + row)*224 + col] = 0;
        }
    }
}

// ---------------------------------------------------------------------------
// down (per half, MFMA, split-W): relu([hb|cb] @ W_down) + degree_table -> hsg
// ---------------------------------------------------------------------------
__global__ __launch_bounds__(256) void down_mfma(
    const short* __restrict__ hbH1, const short* __restrict__ hbH2,
    const short* __restrict__ cb1, const short* __restrict__ cb2,
    const int* __restrict__ deg1, const int* __restrict__ deg2,
    const short* __restrict__ WbTH, const short* __restrict__ WbTL,
    const float* __restrict__ degree_table,
    float* __restrict__ hsg1, float* __restrict__ hsg2, const int half)
{
    const int side = blockIdx.y;
    const short* X0 = side ? hbH2 : hbH1;
    const short* X1 = side ? cb2 : cb1;
    const int*   dgp = side ? deg2 : deg1;
    float* hsg = side ? hsg2 : hsg1;

    const int nl0 = blockIdx.x * 64;
    const int ng0 = half*HBN + nl0;
    const int b = ng0 >> 9;

    __shared__ short As[64*40];
    __shared__ short BsH[208*40];
    __shared__ short BsL[208*40];
    __shared__ float part[208];

    const int tid = threadIdx.x;
    const int wv = tid >> 6, lane = tid & 63;
    const int arow = lane & 15, aq = lane >> 4;

    if (tid < 208) part[tid] = 0.f;

    f32x4 acc[13];
    #pragma unroll
    for (int t = 0; t < 13; t++) acc[t] = (f32x4){0.f,0.f,0.f,0.f};

    const int sr = tid >> 2, sc = (tid & 3) * 8;

    for (int phase = 0; phase < 2; phase++) {
        const short* X = phase ? X1 : X0;
        for (int k0 = 0; k0 < 224; k0 += 32) {
            __syncthreads();
            *(short8*)&As[sr*40 + sc] =
                *(const short8*)&X[(size_t)(nl0+sr)*224 + k0 + sc];
            const int kkg = phase*224 + k0;
            #pragma unroll
            for (int pass = 0; pass < 4; pass++) {
                const int f = pass*256 + tid;
                if (f < 832) {
                    const int d = f >> 2, cc = (f & 3) * 8;
                    *(short8*)&BsH[d*40 + cc] = *(const short8*)&WbTH[(size_t)d*448 + kkg + cc];
                    *(short8*)&BsL[d*40 + cc] = *(const short8*)&WbTL[(size_t)d*448 + kkg + cc];
                }
            }
            __syncthreads();
            const short8 a = *(const short8*)&As[(16*wv + arow)*40 + aq*8];
            #pragma unroll
            for (int t = 0; t < 13; t++) {
                const short8 bh = *(const short8*)&BsH[(t*16 + arow)*40 + aq*8];
                const short8 bl = *(const short8*)&BsL[(t*16 + arow)*40 + aq*8];
                acc[t] = __builtin_amdgcn_mfma_f32_16x16x32_bf16(a, bh, acc[t], 0, 0, 0);
                acc[t] = __builtin_amdgcn_mfma_f32_16x16x32_bf16(a, bl, acc[t], 0, 0, 0);
            }
        }
    }
    __syncthreads();

    int dgc[4];
    #pragma unroll
    for (int r = 0; r < 4; r++) {
        int d = dgp[ng0 + 16*wv + aq*4 + r];
        dgc[r] = d > 199 ? 199 : d;
    }
    #pragma unroll
    for (int nt = 0; nt < 13; nt++) {
        const int col = nt*16 + arow;
        float s = 0.f;
        if (col < DH) {
            #pragma unroll
            for (int r = 0; r < 4; r++)
                s += fmaxf(acc[nt][r], 0.f) + degree_table[dgc[r]*DH + col];
        }
        s += __shfl_xor(s, 16, 64);
        s += __shfl_xor(s, 32, 64);
        if (lane < 16 && col < DH) atomicAdd(&part[col], s);
    }
    __syncthreads();
    if (tid < DH) unsafeAtomicAdd(&hsg[b*206 + tid], part[tid] * (1.0f/512.0f));
}

// ---------------------------------------------------------------------------
// Kernel 6: interaction mean over nodes -> hsg cols 200..205
// ---------------------------------------------------------------------------
__global__ __launch_bounds__(192) void inter_kernel(
    const float* __restrict__ i1, const float* __restrict__ i2,
    float* __restrict__ hsg1, float* __restrict__ hsg2)
{
    const int side = blockIdx.y;
    const float* it = side ? i2 : i1;
    float* hsg = side ? hsg2 : hsg1;
    const int b = blockIdx.x;
    __shared__ float red[192];
    const int tid = threadIdx.x;
    const int j = tid % 6, seg = tid / 6;
    float s = 0.0f;
    for (int n = seg*16; n < seg*16 + 16; n++)
        s += it[(size_t)b*NN*DI + n*DI + j];
    red[tid] = s;
    __syncthreads();
    if (tid < 6) {
        float tot = 0.0f;
        for (int sg2 = 0; sg2 < 32; sg2++) tot += red[sg2*6 + tid];
        hsg[b*206 + 200 + tid] = tot * (1.0f/512.0f);
    }
}

// ---------------------------------------------------------------------------
// Kernel 7: final MLP, one block per batch row
// ---------------------------------------------------------------------------
__global__ __launch_bounds__(256) void mlp_kernel(
    const float* __restrict__ hsg1, const float* __restrict__ hsg2,
    const float* __restrict__ W_f1, const float* __restrict__ b_f1,
    const float* __restrict__ W_f2, const float* __restrict__ b_f2,
    const float* __restrict__ W_f3, const float* __restrict__ b_f3,
    const float* __restrict__ W_f4, const float* __restrict__ b_f4,
    float* __restrict__ out)
{
    const int b = blockIdx.x;
    __shared__ float x[618];
    __shared__ float y1[400];
    __shared__ float y2[200];
    __shared__ float y3[100];
    __shared__ float red[256];
    const int tid = threadIdx.x;

    if (tid < 206) {
        const float a = hsg1[b*206 + tid], bb = hsg2[b*206 + tid];
        x[tid] = a; x[206 + tid] = bb; x[412 + tid] = a - bb;
    }
    __syncthreads();
    for (int c = tid; c < 400; c += 256) {
        float acc = b_f1[c];
        for (int k = 0; k < 618; k++) acc += x[k]*W_f1[(size_t)k*400 + c];
        y1[c] = fmaxf(acc, 0.0f);
    }
    __syncthreads();
    if (tid < 200) {
        float acc = b_f2[tid];
        for (int k = 0; k < 400; k++) acc += y1[k]*W_f2[k*200 + tid];
        y2[tid] = fmaxf(acc, 0.0f);
    }
    __syncthreads();
    if (tid < 100) {
        float acc = b_f3[tid];
        for (int k = 0; k < 200; k++) acc += y2[k]*W_f3[k*100 + tid];
        y3[tid] = fmaxf(acc, 0.0f);
    }
    __syncthreads();
    red[tid] = (tid < 100) ? y3[tid]*W_f4[tid] : 0.0f;
    __syncthreads();
    for (int s = 128; s > 0; s >>= 1) {
        if (tid < s) red[tid] += red[tid + s];
        __syncthreads();
    }
    if (tid == 0) out[b] = red[0] + b_f4[0];
}

// ---------------------------------------------------------------------------
extern "C" void kernel_launch(void* const* d_in, const int* in_sizes, int n_in,
                              void* d_out, int out_size, void* d_ws, size_t ws_size,
                              hipStream_t stream)
{
    const float* atom1  = (const float*)d_in[0];
    const float* atom2  = (const float*)d_in[1];
    const float* coords1= (const float*)d_in[2];
    const float* coords2= (const float*)d_in[3];
    const float* efeat1 = (const float*)d_in[4];
    const float* efeat2 = (const float*)d_in[5];
    const float* inter1 = (const float*)d_in[6];
    const float* inter2 = (const float*)d_in[7];
    const int*   esrc1  = (const int*)d_in[8];
    const int*   edst1  = (const int*)d_in[9];
    const int*   esrc2  = (const int*)d_in[10];
    const int*   edst2  = (const int*)d_in[11];
    const float* W_atom = (const float*)d_in[12];
    const float* W_edge = (const float*)d_in[13];
    const float* W_rbf  = (const float*)d_in[14];
    const float* b_rbf  = (const float*)d_in[15];
    const float* ln_g   = (const float*)d_in[16];
    const float* ln_b   = (const float*)d_in[17];
    const float* W_down = (const float*)d_in[18];
    const float* deg_tab= (const float*)d_in[19];
    const float* W_f1   = (const float*)d_in[20];
    const float* b_f1   = (const float*)d_in[21];
    const float* W_f2   = (const float*)d_in[22];
    const float* b_f2   = (const float*)d_in[23];
    const float* W_f3   = (const float*)d_in[24];
    const float* b_f3   = (const float*)d_in[25];
    const float* W_f4   = (const float*)d_in[26];
    const float* b_f4   = (const float*)d_in[27];
    float* out = (float*)d_out;

    // ---- workspace layout (~133 MB)
    float* ws = (float*)d_ws;
    const size_t HSZ = (size_t)BN*DH;              // per-side h floats
    float* h1  = ws;
    float* h2  = h1 + HSZ;
    // pool: max(feat 2*(EE+16)*32 shorts, bf16 pool 10*HB shorts)
    short* pool = (short*)(h2 + HSZ);
    const size_t FSZ = (size_t)(EE+16)*32;
    short* featH1 = pool;
    short* featH2 = featH1 + FSZ;
    const size_t HB = (size_t)32*NN*224;           // 3,670,016 shorts
    short* hbH1 = pool;           short* hbL1 = hbH1 + HB;
    short* hbH2 = hbL1 + HB;      short* hbL2 = hbH2 + HB;
    short* hTH1 = hbL2 + HB;      short* hTL1 = hTH1 + HB;
    short* hTH2 = hTL1 + HB;      short* hTL2 = hTH2 + HB;
    short* cb1  = hTL2 + HB;      short* cb2  = cb1 + HB;
    size_t pool_sz = 2*FSZ > 10*HB ? 2*FSZ : 10*HB;
    short* after = pool + pool_sz;
    short* WTH = after;                            // [208][32]
    short* WTL = WTH + 208*32;
    short* WbTH = WTL + 208*32;                    // [208][448]
    short* WbTL = WbTH + 208*448;
    float* hsg1 = (float*)(WbTL + 208*448);
    float* hsg2 = hsg1 + (size_t)BB*206;
    int* deg1 = (int*)(hsg2 + (size_t)BB*206);
    int* deg2 = deg1 + BN;
    int* start1 = deg2 + BN;                       // BN+1 entries
    int* start2 = start1 + (BN+1);
    int* cursor1 = start2 + (BN+1);
    int* cursor2 = cursor1 + BN;
    int* rank1 = cursor2 + BN;
    int* rank2 = rank1 + EE;

    hipMemsetAsync(deg1, 0, 2*(size_t)BN*sizeof(int), stream);
    hipMemsetAsync(hsg1, 0, 2*(size_t)BB*206*sizeof(float), stream);

    node_kernel<<<dim3(BN/4, 2), 256, 0, stream>>>(
        atom1, atom2, W_atom, ln_g, ln_b, h1, h2);

    hist_kernel<<<EE/256, 256, 0, stream>>>(edst1, edst2, deg1, deg2);
    scan_kernel<<<2, 1024, 0, stream>>>(deg1, deg2, start1, start2, cursor1, cursor2);
    scatter_kernel<<<EE/256, 256, 0, stream>>>(edst1, edst2, cursor1, cursor2,
                                               rank1, rank2);

    featgen_kernel<<<dim3(EE/256, 2), 256, 0, stream>>>(
        efeat1, efeat2, esrc1, esrc2, edst1, edst2, coords1, coords2,
        rank1, rank2, featH1, featH2);
    featpad_kernel<<<1, 256, 0, stream>>>(featH1, featH2);

    prep_wt_kernel<<<(208*32 + 255)/256, 256, 0, stream>>>(
        W_edge, W_rbf, b_rbf, WTH, WTL);

    gather_mfma<<<1024, 256, 0, stream>>>(
        featH1, featH2, start1, start2, WTH, WTL, ln_g, ln_b, h1, h2);

    prep_w_kernel<<<(208*448 + 255)/256, 256, 0, stream>>>(W_down, WbTH, WbTL);

    for (int half = 0; half < 2; half++) {
        cvt_kernel<<<dim3(HBN/64, 2), 256, 0, stream>>>(
            h1, h2, half, hbH1, hbL1, hbH2, hbL2, hTH1, hTL1, hTH2, hTL2);
        // dir0: c1 = softmax_rows(h1@h2^T) @ h2
        attn_kernel<<<dim3(NN/16, 32), 256, 0, stream>>>(
            hbH1, hbL1, hbH2, hbL2, hTH2, hTL2, cb1);
        // dir1: c2 = softmax_rows(h2@h1^T) @ h1
        attn_kernel<<<dim3(NN/16, 32), 256, 0, stream>>>(
            hbH2, hbL2, hbH1, hbL1, hTH1, hTL1, cb2);
        down_mfma<<<dim3(HBN/64, 2), 256, 0, stream>>>(
            hbH1, hbH2, cb1, cb2, deg1, deg2, WbTH, WbTL, deg_tab,
            hsg1, hsg2, half);
    }

    inter_kernel<<<dim3(BB, 2), 192, 0, stream>>>(inter1, inter2, hsg1, hsg2);

    mlp_kernel<<<BB, 256, 0, stream>>>(
        hsg1, hsg2, W_f1, b_f1, W_f2, b_f2, W_f3, b_f3, W_f4, b_f4, out);
}

// Round 3
// 1306.469 us; speedup vs baseline: 1.0438x; 1.0438x over previous
//
#include <hip/hip_runtime.h>
#include <cstddef>
#include <cstdint>

// Problem constants
#define BB   64
#define NN   512
#define BN   (BB*NN)          // 32768
#define HBN  16384            // nodes per half
#define EE   524288
#define DA   70
#define DE   14
#define DH   200
#define DI   6
#define T_SCALE 0.07071067811865475f   // sqrt(1/200)

typedef __attribute__((ext_vector_type(8))) short short8;
typedef __attribute__((ext_vector_type(4))) float f32x4;

__device__ __forceinline__ short f2bf(float x) {
    union { float f; unsigned u; } v; v.f = x;
    const unsigned r = v.u + 0x7FFFu + ((v.u >> 16) & 1u);   // RNE
    return (short)(r >> 16);
}
__device__ __forceinline__ float bf2f(short s) {
    union { unsigned u; float f; } v;
    v.u = ((unsigned)(unsigned short)s) << 16;
    return v.f;
}

// ---------------------------------------------------------------------------
// Kernel 1: per-node  h = layernorm(relu(atom @ W_atom))
// ---------------------------------------------------------------------------
__global__ __launch_bounds__(256) void node_kernel(
    const float* __restrict__ atom1, const float* __restrict__ atom2,
    const float* __restrict__ W_atom,
    const float* __restrict__ ln_g, const float* __restrict__ ln_b,
    float* __restrict__ h1, float* __restrict__ h2)
{
    const int side = blockIdx.y;
    const float* atom = side ? atom2 : atom1;
    float* h = side ? h2 : h1;
    const int node0 = blockIdx.x * 4;
    const int tid = threadIdx.x;

    __shared__ float arow[4][DA];
    __shared__ float vals[4][DH];

    for (int i = tid; i < 4*DA; i += 256) {
        const int n = i / DA, k = i % DA;
        arow[n][k] = atom[(size_t)(node0+n)*DA + k];
    }
    __syncthreads();

    if (tid < DH) {
        float a0 = 0.f, a1 = 0.f, a2 = 0.f, a3 = 0.f;
        #pragma unroll 7
        for (int k = 0; k < DA; k++) {
            const float w = W_atom[k*DH + tid];
            a0 += arow[0][k]*w; a1 += arow[1][k]*w;
            a2 += arow[2][k]*w; a3 += arow[3][k]*w;
        }
        vals[0][tid] = fmaxf(a0, 0.f);
        vals[1][tid] = fmaxf(a1, 0.f);
        vals[2][tid] = fmaxf(a2, 0.f);
        vals[3][tid] = fmaxf(a3, 0.f);
    }
    __syncthreads();

    const int wv = tid >> 6, lane = tid & 63;
    float v0 = vals[wv][lane];
    float v1 = vals[wv][64+lane];
    float v2 = vals[wv][128+lane];
    float v3 = (lane < 8) ? vals[wv][192+lane] : 0.0f;
    float s  = v0+v1+v2+v3;
    float s2 = v0*v0+v1*v1+v2*v2+v3*v3;
    #pragma unroll
    for (int off = 1; off < 64; off <<= 1) {
        s  += __shfl_xor(s,  off, 64);
        s2 += __shfl_xor(s2, off, 64);
    }
    const float mean = s * (1.0f/DH);
    const float var  = s2 * (1.0f/DH) - mean*mean;
    const float rstd = rsqrtf(var + 1e-5f);
    const size_t base = (size_t)(node0+wv)*DH;
    h[base + lane]       = ln_g[lane]     *(v0-mean)*rstd + ln_b[lane];
    h[base + 64 + lane]  = ln_g[64+lane]  *(v1-mean)*rstd + ln_b[64+lane];
    h[base + 128 + lane] = ln_g[128+lane] *(v2-mean)*rstd + ln_b[128+lane];
    if (lane < 8)
        h[base + 192 + lane] = ln_g[192+lane]*(v3-mean)*rstd + ln_b[192+lane];
}

// ---------------------------------------------------------------------------
// Counting sort by dst: hist -> scan(+sentinel) -> scatter (rank only)
// ---------------------------------------------------------------------------
__global__ __launch_bounds__(256) void hist_kernel(
    const int* __restrict__ edst1, const int* __restrict__ edst2,
    int* __restrict__ deg1, int* __restrict__ deg2)
{
    const int e = blockIdx.x*256 + threadIdx.x;
    atomicAdd(&deg1[edst1[e]], 1);
    atomicAdd(&deg2[edst2[e]], 1);
}

__global__ __launch_bounds__(1024) void scan_kernel(
    const int* __restrict__ deg1, const int* __restrict__ deg2,
    int* __restrict__ start1, int* __restrict__ start2,
    int* __restrict__ cursor1, int* __restrict__ cursor2)
{
    const int side = blockIdx.x;
    const int* deg   = side ? deg2 : deg1;
    int* start  = side ? start2 : start1;
    int* cursor = side ? cursor2 : cursor1;

    __shared__ int part[1024];
    const int t = threadIdx.x;
    const int base = t * 32;
    int local[32];
    int sum = 0;
    #pragma unroll
    for (int i = 0; i < 32; i++) { local[i] = deg[base+i]; sum += local[i]; }
    part[t] = sum;
    __syncthreads();
    for (int off = 1; off < 1024; off <<= 1) {
        int v = (t >= off) ? part[t-off] : 0;
        __syncthreads();
        part[t] += v;
        __syncthreads();
    }
    int run = part[t] - sum;   // exclusive
    #pragma unroll
    for (int i = 0; i < 32; i++) {
        start[base+i] = run;
        cursor[base+i] = run;
        run += local[i];
    }
    if (t == 1023) start[BN] = run;   // sentinel == EE
}

__global__ __launch_bounds__(256) void scatter_kernel(
    const int* __restrict__ edst1, const int* __restrict__ edst2,
    int* __restrict__ cursor1, int* __restrict__ cursor2,
    int* __restrict__ rank1, int* __restrict__ rank2)
{
    const int e = blockIdx.x*256 + threadIdx.x;
    {
        const int d = edst1[e];
        rank1[e] = atomicAdd(&cursor1[d], 1);
    }
    {
        const int d = edst2[e];
        rank2[e] = atomicAdd(&cursor2[d], 1);
    }
}

// ---------------------------------------------------------------------------
// featgen: per-edge feature row (rank-ordered) -> featH[rank][32] bf16
//   k 0..13 = ef, 14..29 = rbf, 30 = 1.0 (bias hook), 31 = 0
// ---------------------------------------------------------------------------
__global__ __launch_bounds__(256) void featgen_kernel(
    const float* __restrict__ efeat1, const float* __restrict__ efeat2,
    const int* __restrict__ esrc1, const int* __restrict__ esrc2,
    const int* __restrict__ edst1, const int* __restrict__ edst2,
    const float* __restrict__ coords1, const float* __restrict__ coords2,
    const int* __restrict__ rank1, const int* __restrict__ rank2,
    short* __restrict__ featH1, short* __restrict__ featH2)
{
    const int side = blockIdx.y;
    const float* ef     = side ? efeat2  : efeat1;
    const int*   esrc   = side ? esrc2   : esrc1;
    const int*   edst   = side ? edst2   : edst1;
    const float* coords = side ? coords2 : coords1;
    const int*   rank   = side ? rank2   : rank1;
    short* featH = side ? featH2 : featH1;

    const int e = blockIdx.x*256 + threadIdx.x;
    const int src = esrc[e], dst = edst[e];

    short f[32];
    #pragma unroll
    for (int k = 0; k < 14; k++) f[k] = f2bf(ef[(size_t)e*DE + k]);

    const float dx = coords[src*3+0] - coords[dst*3+0];
    const float dy = coords[src*3+1] - coords[dst*3+1];
    const float dz = coords[src*3+2] - coords[dst*3+2];
    const float dist = sqrtf(dx*dx + dy*dy + dz*dz + 1e-12f);
    #pragma unroll
    for (int k = 0; k < 16; k++) {
        const float t = 3.2f*dist - 1.0666666667f*(float)k;
        f[14+k] = f2bf(__expf(-t*t));
    }
    f[30] = f2bf(1.0f);
    f[31] = 0;

    short* out = featH + (size_t)rank[e]*32;
    #pragma unroll
    for (int q = 0; q < 4; q++)
        *(short8*)&out[q*8] = *(short8*)&f[q*8];
}

// ---------------------------------------------------------------------------
// featpad: zero the 16-row pad past EE so tail tiles read finite zeros
// ---------------------------------------------------------------------------
__global__ __launch_bounds__(256) void featpad_kernel(
    short* __restrict__ featH1, short* __restrict__ featH2)
{
    const int i = threadIdx.x;   // 16*32 = 512 shorts... use 256 threads x2
    featH1[(size_t)EE*32 + i] = 0;
    featH1[(size_t)EE*32 + 256 + i] = 0;
    featH2[(size_t)EE*32 + i] = 0;
    featH2[(size_t)EE*32 + 256 + i] = 0;
}

// ---------------------------------------------------------------------------
// prep_wt: build WT[208][32] hi/lo for the edge projection.
// ---------------------------------------------------------------------------
__global__ __launch_bounds__(256) void prep_wt_kernel(
    const float* __restrict__ W_edge, const float* __restrict__ W_rbf,
    const float* __restrict__ b_rbf,
    short* __restrict__ WTH, short* __restrict__ WTL)
{
    const int idx = blockIdx.x*256 + threadIdx.x;
    if (idx >= 208*32) return;
    const int c = idx >> 5, k = idx & 31;
    float v = 0.f;
    if (c < 100) {
        if (k < 14) v = W_edge[k*100 + c];
    } else if (c < 200) {
        const int cc = c - 100;
        if (k >= 14 && k < 30) v = W_rbf[(k-14)*100 + cc];
        else if (k == 30) v = b_rbf[cc];
    }
    const short hi = f2bf(v);
    WTH[idx] = hi;
    WTL[idx] = f2bf(v - bf2f(hi));
}

// ---------------------------------------------------------------------------
// gather_mfma v5: one wave = 4 consecutive nodes, STATIC structure (v4's
// while-loop chunk walker collapsed to 64 VGPR + scratch spill -> 1.2 GB
// HBM traffic; this version is a `#pragma unroll 1` node loop with a single
// body so regalloc reuses one node's registers). W staged once per block in
// LDS with stride-40 rows (bank = 4*((5*arow+aq)%8), 8 words/bank balanced —
// verified by round-2 counters: 0.25 conflict-cy/read vs 2.7 for stride-32).
// Per node: h RMW loads hoisted to node start, feat prefetched 1 tile ahead
// (overshoot reads next node's rows or the zeroed pad — discarded), 5
// start[] values fetched once per wave and served via readlane.
// ---------------------------------------------------------------------------
__global__ __launch_bounds__(256, 3) void gather_mfma(
    const short* __restrict__ featH1, const short* __restrict__ featH2,
    const int* __restrict__ start1, const int* __restrict__ start2,
    const short* __restrict__ WTH, const short* __restrict__ WTL,
    const float* __restrict__ ln_g, const float* __restrict__ ln_b,
    float* __restrict__ h1, float* __restrict__ h2)
{
    __shared__ short sWH[208*40];    // 16.6 KB, stride-40 (80B) rows
    __shared__ short sWL[208*40];    // 16.6 KB
    __shared__ float plane[4][216];

    const int tid = threadIdx.x;
    const int wv = tid >> 6, lane = tid & 63;
    const int arow = lane & 15, aq = lane >> 4;

    // stage W once per block (832 short8 per array)
    for (int f = tid; f < 832; f += 256) {
        const int d = f >> 2, cc = (f & 3) * 8;
        *(short8*)&sWH[d*40 + cc] = *(const short8*)&WTH[f*8];
        *(short8*)&sWL[d*40 + cc] = *(const short8*)&WTL[f*8];
    }
    __syncthreads();

    const int side = blockIdx.y;
    const short* feat = side ? featH2 : featH1;
    const int*  start = side ? start2 : start1;
    float* h = side ? h2 : h1;

    const int c0 = blockIdx.x*16 + wv*4;     // wave's first node (of 4)

    // hoist ln params (lane-mapped)
    const float g0 = ln_g[lane],      bb0 = ln_b[lane];
    const float g1 = ln_g[64+lane],   bb1 = ln_b[64+lane];
    const float g2 = ln_g[128+lane],  bb2 = ln_b[128+lane];
    const float g3 = (lane < 8) ? ln_g[192+lane] : 0.f;
    const float bb3 = (lane < 8) ? ln_b[192+lane] : 0.f;

    // 5 start values for the 4 nodes, one load, then readlane
    const int sidx = (lane < 5) ? lane : 4;
    const int sv = start[c0 + sidx];

    const int lb = arow*40 + aq*8;           // LDS element offset in a W tile

    #pragma unroll 1
    for (int ni = 0; ni < 4; ni++) {
        const int st = __builtin_amdgcn_readlane(sv, ni);
        const int en = __builtin_amdgcn_readlane(sv, ni + 1);
        const int dg = en - st;
        const int node = c0 + ni;
        const size_t hbase = (size_t)node * DH;

        // hoist h RMW loads (consumed at node end, hidden under tiles)
        const float hv0 = h[hbase + lane];
        const float hv1 = h[hbase + 64 + lane];
        const float hv2 = h[hbase + 128 + lane];
        const float hv3 = (lane < 8) ? h[hbase + 192 + lane] : 0.f;

        float colacc[13];
        #pragma unroll
        for (int nt = 0; nt < 13; nt++) colacc[nt] = 0.f;
        float musum = 0.f;

        short8 aC = *(const short8*)&feat[(size_t)(st + arow)*32 + aq*8];

        for (int t0 = 0; t0 < dg; t0 += 16) {
            // prefetch next tile; overshoot lands in next node's rows or the
            // zeroed 16-row pad (start[BN]=EE sentinel) — discarded if unused
            const short8 aN = *(const short8*)&feat[(size_t)(st + t0 + 16 + arow)*32 + aq*8];

            f32x4 acc[13];
            #pragma unroll
            for (int nt = 0; nt < 13; nt++) {
                const short8 whv = *(const short8*)&sWH[nt*640 + lb];
                const short8 wlv = *(const short8*)&sWL[nt*640 + lb];
                f32x4 z = (f32x4){0.f,0.f,0.f,0.f};
                z = __builtin_amdgcn_mfma_f32_16x16x32_bf16(aC, whv, z, 0, 0, 0);
                z = __builtin_amdgcn_mfma_f32_16x16x32_bf16(aC, wlv, z, 0, 0, 0);
                acc[nt] = z;
            }
            // relu + per-row (per-edge) stats; row = t0 + aq*4 + r
            float sr[4] = {0.f,0.f,0.f,0.f}, s2r[4] = {0.f,0.f,0.f,0.f};
            #pragma unroll
            for (int nt = 0; nt < 13; nt++) {
                #pragma unroll
                for (int r = 0; r < 4; r++) {
                    const float v = fmaxf(acc[nt][r], 0.f);
                    acc[nt][r] = v;
                    sr[r] += v; s2r[r] += v*v;
                }
            }
            #pragma unroll
            for (int off = 1; off < 16; off <<= 1) {
                #pragma unroll
                for (int r = 0; r < 4; r++) {
                    sr[r]  += __shfl_xor(sr[r],  off, 64);
                    s2r[r] += __shfl_xor(s2r[r], off, 64);
                }
            }
            #pragma unroll
            for (int r = 0; r < 4; r++) {
                const bool valid = (t0 + aq*4 + r) < dg;
                const float mean = sr[r] * (1.0f/DH);
                const float var  = s2r[r] * (1.0f/DH) - mean*mean;
                const float rs   = rsqrtf(var + 1e-5f);
                const float rstd = valid ? rs : 0.f;
                musum += valid ? mean*rs : 0.f;
                #pragma unroll
                for (int nt = 0; nt < 13; nt++)
                    colacc[nt] += rstd*acc[nt][r];
            }
            aC = aN;
        }

        // reduce over the 4 aq groups (rows partition)
        #pragma unroll
        for (int nt = 0; nt < 13; nt++) {
            colacc[nt] += __shfl_xor(colacc[nt], 16, 64);
            colacc[nt] += __shfl_xor(colacc[nt], 32, 64);
        }
        musum += __shfl_xor(musum, 16, 64);
        musum += __shfl_xor(musum, 32, 64);

        if (aq == 0) {
            #pragma unroll
            for (int nt = 0; nt < 13; nt++)
                plane[wv][nt*16 + arow] = colacc[nt];
        }
        // wave-internal LDS producer/consumer: DS pipe is in-order per wave —
        // no barrier (and the next node's writes issue after these reads)

        const float dgf = (float)dg;
        h[hbase + lane]       = hv0 + g0*(plane[wv][lane]     - musum) + dgf*bb0;
        h[hbase + 64 + lane]  = hv1 + g1*(plane[wv][64+lane]  - musum) + dgf*bb1;
        h[hbase + 128 + lane] = hv2 + g2*(plane[wv][128+lane] - musum) + dgf*bb2;
        if (lane < 8)
            h[hbase + 192 + lane] = hv3 + g3*(plane[wv][192+lane] - musum) + dgf*bb3;
    }
}

// ---------------------------------------------------------------------------
// cvt (per half): h fp32 -> hb hi/lo [16384][224] rows + hbT hi/lo [32][224][512]
// ---------------------------------------------------------------------------
__global__ __launch_bounds__(256) void cvt_kernel(
    const float* __restrict__ h1, const float* __restrict__ h2, const int half,
    short* __restrict__ hbH1, short* __restrict__ hbL1,
    short* __restrict__ hbH2, short* __restrict__ hbL2,
    short* __restrict__ hTH1, short* __restrict__ hTL1,
    short* __restrict__ hTH2, short* __restrict__ hTL2)
{
    const int side = blockIdx.y;
    const float* h = side ? h2 : h1;
    short* hbH = side ? hbH2 : hbH1;
    short* hbL = side ? hbL2 : hbL1;
    short* hTH = side ? hTH2 : hTH1;
    short* hTL = side ? hTL2 : hTL1;

    const int nl0 = blockIdx.x * 64;          // local node
    const int bl = nl0 >> 9, m0 = nl0 & 511;
    const int ng0 = half*HBN + nl0;

    __shared__ short tH[64][226];
    __shared__ short tL[64][226];
    const int tid = threadIdx.x;
    for (int i = tid; i < 64*224; i += 256) {
        const int r = i / 224, c = i - r*224;
        const float v = (c < DH) ? h[(size_t)(ng0+r)*DH + c] : 0.f;
        const short hi = f2bf(v);
        const short lo = f2bf(v - bf2f(hi));
        tH[r][c] = hi; tL[r][c] = lo;
        hbH[(size_t)(nl0+r)*224 + c] = hi;
        hbL[(size_t)(nl0+r)*224 + c] = lo;
    }
    __syncthreads();
    for (int i = tid; i < 224*64; i += 256) {
        const int c = i >> 6, m = i & 63;
        const size_t o = ((size_t)bl*224 + c)*NN + m0 + m;
        hTH[o] = tH[m][c];
        hTL[o] = tL[m][c];
    }
}

// ---------------------------------------------------------------------------
// prep_w: W_down[400][200] -> WbTHI/LO[208][448] (transposed, padded, split)
// ---------------------------------------------------------------------------
__global__ __launch_bounds__(256) void prep_w_kernel(
    const float* __restrict__ W_down,
    short* __restrict__ WbTHI, short* __restrict__ WbTLO)
{
    const int idx = blockIdx.x*256 + threadIdx.x;
    if (idx >= 208*448) return;
    const int c = idx / 448, kk = idx - c*448;
    float v = 0.f;
    if (c < 200) {
        if (kk < 200) v = W_down[(size_t)kk*DH + c];
        else if (kk >= 224 && kk < 424) v = W_down[(size_t)(200 + kk - 224)*DH + c];
    }
    const short hi = f2bf(v);
    WbTHI[idx] = hi;
    WbTLO[idx] = f2bf(v - bf2f(hi));
}

// ---------------------------------------------------------------------------
// Fused attention v4: 16 Q-rows per block, 4 waves split 32 key-tiles;
// K/V streamed from global (L2); 3 barriers per block.
// XCD-aware block remap: dispatch ids == k (mod 8) land on XCD k (round-robin,
// m09); map them to batches 4k..4k+3 so each XCD's concurrent K/V working set
// is 4 x ~885KB ~= 3.5MB < 4MB L2 -> cross-block K/V reuse becomes L2 hits.
// ---------------------------------------------------------------------------
__global__ __launch_bounds__(256, 4) void attn_kernel(
    const short* __restrict__ QH, const short* __restrict__ QL,
    const short* __restrict__ KH, const short* __restrict__ KL,
    const short* __restrict__ VTH, const short* __restrict__ VTL,
    short* __restrict__ cb)
{
    const int id = blockIdx.x + (blockIdx.y << 5);   // gridDim.x == 32
    const int j  = id >> 3;
    const int b  = (id & 7)*4 + (j >> 5);            // half-local batch
    const int q0 = (j & 31) << 4;
    const short* Qh = QH + (size_t)b*NN*224;
    const short* Ql = QL + (size_t)b*NN*224;
    const short* Kh = KH + (size_t)b*NN*224;
    const short* Kl = KL + (size_t)b*NN*224;
    const short* Vh = VTH + (size_t)b*224*NN;
    const short* Vl = VTL + (size_t)b*224*NN;

    __shared__ short pb[16*520];              // 16.3 KB P bf16
    __shared__ float sm_[4][16];
    __shared__ float ss_[4][16];

    const int tid = threadIdx.x;
    const int wv = tid >> 6, lane = tid & 63;
    const int arow = lane & 15, aq = lane >> 4;

    const int qrow = q0 + arow;
    short8 qfh[7], qfl[7];
    #pragma unroll
    for (int k = 0; k < 7; k++) {
        qfh[k] = *(const short8*)&Qh[(size_t)qrow*224 + k*32 + aq*8];
        qfl[k] = *(const short8*)&Ql[(size_t)qrow*224 + k*32 + aq*8];
    }

    f32x4 acc[8];
    #pragma unroll
    for (int t = 0; t < 8; t++) acc[t] = (f32x4){0.f,0.f,0.f,0.f};

    #pragma unroll
    for (int t = 0; t < 8; t++) {
        const size_t kb = (size_t)((wv*8 + t)*16 + arow)*224;
        #pragma unroll
        for (int k = 0; k < 7; k++) {
            const short8 bh = *(const short8*)&Kh[kb + k*32 + aq*8];
            const short8 bl = *(const short8*)&Kl[kb + k*32 + aq*8];
            acc[t] = __builtin_amdgcn_mfma_f32_16x16x32_bf16(qfh[k], bh, acc[t], 0, 0, 0);
            acc[t] = __builtin_amdgcn_mfma_f32_16x16x32_bf16(qfh[k], bl, acc[t], 0, 0, 0);
            acc[t] = __builtin_amdgcn_mfma_f32_16x16x32_bf16(qfl[k], bh, acc[t], 0, 0, 0);
        }
    }

    float mr[4], sr[4], iv[4];
    #pragma unroll
    for (int r = 0; r < 4; r++) {
        float m = -1e30f;
        #pragma unroll
        for (int t = 0; t < 8; t++) {
            acc[t][r] *= T_SCALE;
            m = fmaxf(m, acc[t][r]);
        }
        m = fmaxf(m, __shfl_xor(m, 1, 64));
        m = fmaxf(m, __shfl_xor(m, 2, 64));
        m = fmaxf(m, __shfl_xor(m, 4, 64));
        m = fmaxf(m, __shfl_xor(m, 8, 64));
        mr[r] = m;
    }
    if (arow == 0) {
        #pragma unroll
        for (int r = 0; r < 4; r++) sm_[wv][aq*4+r] = mr[r];
    }
    __syncthreads();
    #pragma unroll
    for (int r = 0; r < 4; r++) {
        const int row = aq*4 + r;
        const float M = fmaxf(fmaxf(sm_[0][row], sm_[1][row]),
                              fmaxf(sm_[2][row], sm_[3][row]));
        float s = 0.f;
        #pragma unroll
        for (int t = 0; t < 8; t++) {
            const float e = __expf(acc[t][r] - M);
            acc[t][r] = e;
            s += e;
        }
        s += __shfl_xor(s, 1, 64);
        s += __shfl_xor(s, 2, 64);
        s += __shfl_xor(s, 4, 64);
        s += __shfl_xor(s, 8, 64);
        sr[r] = s;
    }
    if (arow == 0) {
        #pragma unroll
        for (int r = 0; r < 4; r++) ss_[wv][aq*4+r] = sr[r];
    }
    __syncthreads();
    #pragma unroll
    for (int r = 0; r < 4; r++) {
        const int row = aq*4 + r;
        iv[r] = 1.0f / (ss_[0][row] + ss_[1][row] + ss_[2][row] + ss_[3][row]);
    }

    #pragma unroll
    for (int t = 0; t < 8; t++) {
        const int col = (wv*8 + t)*16 + arow;
        #pragma unroll
        for (int r = 0; r < 4; r++)
            pb[(aq*4 + r)*520 + col] = f2bf(acc[t][r] * iv[r]);
    }
    __syncthreads();

    const int nbase = (wv == 0) ? 0 : 3*wv + 1;
    const int ncnt  = (wv == 0) ? 4 : 3;
    f32x4 pacc[4];
    #pragma unroll
    for (int t = 0; t < 4; t++) pacc[t] = (f32x4){0.f,0.f,0.f,0.f};

    for (int k0 = 0; k0 < NN; k0 += 32) {
        const short8 a = *(const short8*)&pb[arow*520 + k0 + aq*8];
        #pragma unroll
        for (int t = 0; t < 4; t++) {
            if (t < ncnt) {
                const size_t vb = (size_t)((nbase+t)*16 + arow)*NN + k0 + aq*8;
                const short8 bh = *(const short8*)&Vh[vb];
                const short8 bl = *(const short8*)&Vl[vb];
                pacc[t] = __builtin_amdgcn_mfma_f32_16x16x32_bf16(a, bh, pacc[t], 0, 0, 0);
                pacc[t] = __builtin_amdgcn_mfma_f32_16x16x32_bf16(a, bl, pacc[t], 0, 0, 0);
            }
        }
    }

    #pragma unroll
    for (int t = 0; t < 4; t++) {
        if (t < ncnt) {
            const int col = (nbase+t)*16 + arow;
            #pragma unroll
            for (int r = 0; r < 4; r++) {
                const int row = q0 + aq*4 + r;
                const short v = (col < DH) ? f2bf(pacc[t][r]) : (short)0;
                cb[((size_t)b*NN + row)*224 + col] = v;
            }
        }
    }
    if (wv == 3) {
        const int col = 208 + arow;
        #pragma unroll
        for (int r = 0; r < 4; r++) {
            const int row = q0 + aq*4 + r;
            cb[((size_t)b*NN + row)*224 + col] = 0;
        }
    }
}

// ---------------------------------------------------------------------------
// down (per half, MFMA, split-W): relu([hb|cb] @ W_down) + degree_table -> hsg
// ---------------------------------------------------------------------------
__global__ __launch_bounds__(256) void down_mfma(
    const short* __restrict__ hbH1, const short* __restrict__ hbH2,
    const short* __restrict__ cb1, const short* __restrict__ cb2,
    const int* __restrict__ deg1, const int* __restrict__ deg2,
    const short* __restrict__ WbTH, const short* __restrict__ WbTL,
    const float* __restrict__ degree_table,
    float* __restrict__ hsg1, float* __restrict__ hsg2, const int half)
{
    const int side = blockIdx.y;
    const short* X0 = side ? hbH2 : hbH1;
    const short* X1 = side ? cb2 : cb1;
    const int*   dgp = side ? deg2 : deg1;
    float* hsg = side ? hsg2 : hsg1;

    const int nl0 = blockIdx.x * 64;
    const int ng0 = half*HBN + nl0;
    const int b = ng0 >> 9;

    __shared__ short As[64*40];
    __shared__ short BsH[208*40];
    __shared__ short BsL[208*40];
    __shared__ float part[208];

    const int tid = threadIdx.x;
    const int wv = tid >> 6, lane = tid & 63;
    const int arow = lane & 15, aq = lane >> 4;

    if (tid < 208) part[tid] = 0.f;

    f32x4 acc[13];
    #pragma unroll
    for (int t = 0; t < 13; t++) acc[t] = (f32x4){0.f,0.f,0.f,0.f};

    const int sr = tid >> 2, sc = (tid & 3) * 8;

    for (int phase = 0; phase < 2; phase++) {
        const short* X = phase ? X1 : X0;
        for (int k0 = 0; k0 < 224; k0 += 32) {
            __syncthreads();
            *(short8*)&As[sr*40 + sc] =
                *(const short8*)&X[(size_t)(nl0+sr)*224 + k0 + sc];
            const int kkg = phase*224 + k0;
            #pragma unroll
            for (int pass = 0; pass < 4; pass++) {
                const int f = pass*256 + tid;
                if (f < 832) {
                    const int d = f >> 2, cc = (f & 3) * 8;
                    *(short8*)&BsH[d*40 + cc] = *(const short8*)&WbTH[(size_t)d*448 + kkg + cc];
                    *(short8*)&BsL[d*40 + cc] = *(const short8*)&WbTL[(size_t)d*448 + kkg + cc];
                }
            }
            __syncthreads();
            const short8 a = *(const short8*)&As[(16*wv + arow)*40 + aq*8];
            #pragma unroll
            for (int t = 0; t < 13; t++) {
                const short8 bh = *(const short8*)&BsH[(t*16 + arow)*40 + aq*8];
                const short8 bl = *(const short8*)&BsL[(t*16 + arow)*40 + aq*8];
                acc[t] = __builtin_amdgcn_mfma_f32_16x16x32_bf16(a, bh, acc[t], 0, 0, 0);
                acc[t] = __builtin_amdgcn_mfma_f32_16x16x32_bf16(a, bl, acc[t], 0, 0, 0);
            }
        }
    }
    __syncthreads();

    int dgc[4];
    #pragma unroll
    for (int r = 0; r < 4; r++) {
        int d = dgp[ng0 + 16*wv + aq*4 + r];
        dgc[r] = d > 199 ? 199 : d;
    }
    #pragma unroll
    for (int nt = 0; nt < 13; nt++) {
        const int col = nt*16 + arow;
        float s = 0.f;
        if (col < DH) {
            #pragma unroll
            for (int r = 0; r < 4; r++)
                s += fmaxf(acc[nt][r], 0.f) + degree_table[dgc[r]*DH + col];
        }
        s += __shfl_xor(s, 16, 64);
        s += __shfl_xor(s, 32, 64);
        if (lane < 16 && col < DH) atomicAdd(&part[col], s);
    }
    __syncthreads();
    if (tid < DH) unsafeAtomicAdd(&hsg[b*206 + tid], part[tid] * (1.0f/512.0f));
}

// ---------------------------------------------------------------------------
// Kernel 6: interaction mean over nodes -> hsg cols 200..205
// ---------------------------------------------------------------------------
__global__ __launch_bounds__(192) void inter_kernel(
    const float* __restrict__ i1, const float* __restrict__ i2,
    float* __restrict__ hsg1, float* __restrict__ hsg2)
{
    const int side = blockIdx.y;
    const float* it = side ? i2 : i1;
    float* hsg = side ? hsg2 : hsg1;
    const int b = blockIdx.x;
    __shared__ float red[192];
    const int tid = threadIdx.x;
    const int j = tid % 6, seg = tid / 6;
    float s = 0.0f;
    for (int n = seg*16; n < seg*16 + 16; n++)
        s += it[(size_t)b*NN*DI + n*DI + j];
    red[tid] = s;
    __syncthreads();
    if (tid < 6) {
        float tot = 0.0f;
        for (int sg2 = 0; sg2 < 32; sg2++) tot += red[sg2*6 + tid];
        hsg[b*206 + 200 + tid] = tot * (1.0f/512.0f);
    }
}

// ---------------------------------------------------------------------------
// Kernel 7: final MLP, one block per batch row
// ---------------------------------------------------------------------------
__global__ __launch_bounds__(256) void mlp_kernel(
    const float* __restrict__ hsg1, const float* __restrict__ hsg2,
    const float* __restrict__ W_f1, const float* __restrict__ b_f1,
    const float* __restrict__ W_f2, const float* __restrict__ b_f2,
    const float* __restrict__ W_f3, const float* __restrict__ b_f3,
    const float* __restrict__ W_f4, const float* __restrict__ b_f4,
    float* __restrict__ out)
{
    const int b = blockIdx.x;
    __shared__ float x[618];
    __shared__ float y1[400];
    __shared__ float y2[200];
    __shared__ float y3[100];
    __shared__ float red[256];
    const int tid = threadIdx.x;

    if (tid < 206) {
        const float a = hsg1[b*206 + tid], bb = hsg2[b*206 + tid];
        x[tid] = a; x[206 + tid] = bb; x[412 + tid] = a - bb;
    }
    __syncthreads();
    for (int c = tid; c < 400; c += 256) {
        float acc = b_f1[c];
        for (int k = 0; k < 618; k++) acc += x[k]*W_f1[(size_t)k*400 + c];
        y1[c] = fmaxf(acc, 0.0f);
    }
    __syncthreads();
    if (tid < 200) {
        float acc = b_f2[tid];
        for (int k = 0; k < 400; k++) acc += y1[k]*W_f2[k*200 + tid];
        y2[tid] = fmaxf(acc, 0.0f);
    }
    __syncthreads();
    if (tid < 100) {
        float acc = b_f3[tid];
        for (int k = 0; k < 200; k++) acc += y2[k]*W_f3[k*100 + tid];
        y3[tid] = fmaxf(acc, 0.0f);
    }
    __syncthreads();
    red[tid] = (tid < 100) ? y3[tid]*W_f4[tid] : 0.0f;
    __syncthreads();
    for (int s = 128; s > 0; s >>= 1) {
        if (tid < s) red[tid] += red[tid + s];
        __syncthreads();
    }
    if (tid == 0) out[b] = red[0] + b_f4[0];
}

// ---------------------------------------------------------------------------
extern "C" void kernel_launch(void* const* d_in, const int* in_sizes, int n_in,
                              void* d_out, int out_size, void* d_ws, size_t ws_size,
                              hipStream_t stream)
{
    const float* atom1  = (const float*)d_in[0];
    const float* atom2  = (const float*)d_in[1];
    const float* coords1= (const float*)d_in[2];
    const float* coords2= (const float*)d_in[3];
    const float* efeat1 = (const float*)d_in[4];
    const float* efeat2 = (const float*)d_in[5];
    const float* inter1 = (const float*)d_in[6];
    const float* inter2 = (const float*)d_in[7];
    const int*   esrc1  = (const int*)d_in[8];
    const int*   edst1  = (const int*)d_in[9];
    const int*   esrc2  = (const int*)d_in[10];
    const int*   edst2  = (const int*)d_in[11];
    const float* W_atom = (const float*)d_in[12];
    const float* W_edge = (const float*)d_in[13];
    const float* W_rbf  = (const float*)d_in[14];
    const float* b_rbf  = (const float*)d_in[15];
    const float* ln_g   = (const float*)d_in[16];
    const float* ln_b   = (const float*)d_in[17];
    const float* W_down = (const float*)d_in[18];
    const float* deg_tab= (const float*)d_in[19];
    const float* W_f1   = (const float*)d_in[20];
    const float* b_f1   = (const float*)d_in[21];
    const float* W_f2   = (const float*)d_in[22];
    const float* b_f2   = (const float*)d_in[23];
    const float* W_f3   = (const float*)d_in[24];
    const float* b_f3   = (const float*)d_in[25];
    const float* W_f4   = (const float*)d_in[26];
    const float* b_f4   = (const float*)d_in[27];
    float* out = (float*)d_out;

    // ---- workspace layout (~133 MB)
    float* ws = (float*)d_ws;
    const size_t HSZ = (size_t)BN*DH;              // per-side h floats
    float* h1  = ws;
    float* h2  = h1 + HSZ;
    // pool: max(feat 2*(EE+16)*32 shorts, bf16 pool 10*HB shorts)
    short* pool = (short*)(h2 + HSZ);
    const size_t FSZ = (size_t)(EE+16)*32;
    short* featH1 = pool;
    short* featH2 = featH1 + FSZ;
    const size_t HB = (size_t)32*NN*224;           // 3,670,016 shorts
    short* hbH1 = pool;           short* hbL1 = hbH1 + HB;
    short* hbH2 = hbL1 + HB;      short* hbL2 = hbH2 + HB;
    short* hTH1 = hbL2 + HB;      short* hTL1 = hTH1 + HB;
    short* hTH2 = hTL1 + HB;      short* hTL2 = hTH2 + HB;
    short* cb1  = hTL2 + HB;      short* cb2  = cb1 + HB;
    size_t pool_sz = 2*FSZ > 10*HB ? 2*FSZ : 10*HB;
    short* after = pool + pool_sz;
    short* WTH = after;                            // [208][32]
    short* WTL = WTH + 208*32;
    short* WbTH = WTL + 208*32;                    // [208][448]
    short* WbTL = WbTH + 208*448;
    float* hsg1 = (float*)(WbTL + 208*448);
    float* hsg2 = hsg1 + (size_t)BB*206;
    int* deg1 = (int*)(hsg2 + (size_t)BB*206);
    int* deg2 = deg1 + BN;
    int* start1 = deg2 + BN;                       // BN+1 entries
    int* start2 = start1 + (BN+1);
    int* cursor1 = start2 + (BN+1);
    int* cursor2 = cursor1 + BN;
    int* rank1 = cursor2 + BN;
    int* rank2 = rank1 + EE;

    hipMemsetAsync(deg1, 0, 2*(size_t)BN*sizeof(int), stream);
    hipMemsetAsync(hsg1, 0, 2*(size_t)BB*206*sizeof(float), stream);

    node_kernel<<<dim3(BN/4, 2), 256, 0, stream>>>(
        atom1, atom2, W_atom, ln_g, ln_b, h1, h2);

    hist_kernel<<<EE/256, 256, 0, stream>>>(edst1, edst2, deg1, deg2);
    scan_kernel<<<2, 1024, 0, stream>>>(deg1, deg2, start1, start2, cursor1, cursor2);
    scatter_kernel<<<EE/256, 256, 0, stream>>>(edst1, edst2, cursor1, cursor2,
                                               rank1, rank2);

    featgen_kernel<<<dim3(EE/256, 2), 256, 0, stream>>>(
        efeat1, efeat2, esrc1, esrc2, edst1, edst2, coords1, coords2,
        rank1, rank2, featH1, featH2);
    featpad_kernel<<<1, 256, 0, stream>>>(featH1, featH2);

    prep_wt_kernel<<<(208*32 + 255)/256, 256, 0, stream>>>(
        W_edge, W_rbf, b_rbf, WTH, WTL);

    gather_mfma<<<dim3(BN/16, 2), 256, 0, stream>>>(
        featH1, featH2, start1, start2, WTH, WTL, ln_g, ln_b, h1, h2);

    prep_w_kernel<<<(208*448 + 255)/256, 256, 0, stream>>>(W_down, WbTH, WbTL);

    for (int half = 0; half < 2; half++) {
        cvt_kernel<<<dim3(HBN/64, 2), 256, 0, stream>>>(
            h1, h2, half, hbH1, hbL1, hbH2, hbL2, hTH1, hTL1, hTH2, hTL2);
        // dir0: c1 = softmax_rows(h1@h2^T) @ h2
        attn_kernel<<<dim3(NN/16, 32), 256, 0, stream>>>(
            hbH1, hbL1, hbH2, hbL2, hTH2, hTL2, cb1);
        // dir1: c2 = softmax_rows(h2@h1^T) @ h1
        attn_kernel<<<dim3(NN/16, 32), 256, 0, stream>>>(
            hbH2, hbL2, hbH1, hbL1, hTH1, hTL1, cb2);
        down_mfma<<<dim3(HBN/64, 2), 256, 0, stream>>>(
            hbH1, hbH2, cb1, cb2, deg1, deg2, WbTH, WbTL, deg_tab,
            hsg1, hsg2, half);
    }

    inter_kernel<<<dim3(BB, 2), 192, 0, stream>>>(inter1, inter2, hsg1, hsg2);

    mlp_kernel<<<BB, 256, 0, stream>>>(
        hsg1, hsg2, W_f1, b_f1, W_f2, b_f2, W_f3, b_f3, W_f4, b_f4, out);
}

// Round 4
// 1115.911 us; speedup vs baseline: 1.2221x; 1.1708x over previous
//
#include <hip/hip_runtime.h>
#include <cstddef>
#include <cstdint>

// Problem constants
#define BB   64
#define NN   512
#define BN   (BB*NN)          // 32768
#define HBN  16384            // nodes per half
#define EE   524288
#define DA   70
#define DE   14
#define DH   200
#define DI   6
#define T_SCALE 0.07071067811865475f   // sqrt(1/200)

typedef __attribute__((ext_vector_type(8))) short short8;
typedef __attribute__((ext_vector_type(4))) float f32x4;

__device__ __forceinline__ short f2bf(float x) {
    union { float f; unsigned u; } v; v.f = x;
    const unsigned r = v.u + 0x7FFFu + ((v.u >> 16) & 1u);   // RNE
    return (short)(r >> 16);
}
__device__ __forceinline__ float bf2f(short s) {
    union { unsigned u; float f; } v;
    v.u = ((unsigned)(unsigned short)s) << 16;
    return v.f;
}

// ---------------------------------------------------------------------------
// Kernel 1: per-node  h = layernorm(relu(atom @ W_atom))
// ---------------------------------------------------------------------------
__global__ __launch_bounds__(256) void node_kernel(
    const float* __restrict__ atom1, const float* __restrict__ atom2,
    const float* __restrict__ W_atom,
    const float* __restrict__ ln_g, const float* __restrict__ ln_b,
    float* __restrict__ h1, float* __restrict__ h2)
{
    const int side = blockIdx.y;
    const float* atom = side ? atom2 : atom1;
    float* h = side ? h2 : h1;
    const int node0 = blockIdx.x * 4;
    const int tid = threadIdx.x;

    __shared__ float arow[4][DA];
    __shared__ float vals[4][DH];

    for (int i = tid; i < 4*DA; i += 256) {
        const int n = i / DA, k = i % DA;
        arow[n][k] = atom[(size_t)(node0+n)*DA + k];
    }
    __syncthreads();

    if (tid < DH) {
        float a0 = 0.f, a1 = 0.f, a2 = 0.f, a3 = 0.f;
        #pragma unroll 7
        for (int k = 0; k < DA; k++) {
            const float w = W_atom[k*DH + tid];
            a0 += arow[0][k]*w; a1 += arow[1][k]*w;
            a2 += arow[2][k]*w; a3 += arow[3][k]*w;
        }
        vals[0][tid] = fmaxf(a0, 0.f);
        vals[1][tid] = fmaxf(a1, 0.f);
        vals[2][tid] = fmaxf(a2, 0.f);
        vals[3][tid] = fmaxf(a3, 0.f);
    }
    __syncthreads();

    const int wv = tid >> 6, lane = tid & 63;
    float v0 = vals[wv][lane];
    float v1 = vals[wv][64+lane];
    float v2 = vals[wv][128+lane];
    float v3 = (lane < 8) ? vals[wv][192+lane] : 0.0f;
    float s  = v0+v1+v2+v3;
    float s2 = v0*v0+v1*v1+v2*v2+v3*v3;
    #pragma unroll
    for (int off = 1; off < 64; off <<= 1) {
        s  += __shfl_xor(s,  off, 64);
        s2 += __shfl_xor(s2, off, 64);
    }
    const float mean = s * (1.0f/DH);
    const float var  = s2 * (1.0f/DH) - mean*mean;
    const float rstd = rsqrtf(var + 1e-5f);
    const size_t base = (size_t)(node0+wv)*DH;
    h[base + lane]       = ln_g[lane]     *(v0-mean)*rstd + ln_b[lane];
    h[base + 64 + lane]  = ln_g[64+lane]  *(v1-mean)*rstd + ln_b[64+lane];
    h[base + 128 + lane] = ln_g[128+lane] *(v2-mean)*rstd + ln_b[128+lane];
    if (lane < 8)
        h[base + 192 + lane] = ln_g[192+lane]*(v3-mean)*rstd + ln_b[192+lane];
}

// ---------------------------------------------------------------------------
// Counting sort by dst: hist -> scan(+sentinel) -> scatter (rank only)
// ---------------------------------------------------------------------------
__global__ __launch_bounds__(256) void hist_kernel(
    const int* __restrict__ edst1, const int* __restrict__ edst2,
    int* __restrict__ deg1, int* __restrict__ deg2)
{
    const int e = blockIdx.x*256 + threadIdx.x;
    atomicAdd(&deg1[edst1[e]], 1);
    atomicAdd(&deg2[edst2[e]], 1);
}

__global__ __launch_bounds__(1024) void scan_kernel(
    const int* __restrict__ deg1, const int* __restrict__ deg2,
    int* __restrict__ start1, int* __restrict__ start2,
    int* __restrict__ cursor1, int* __restrict__ cursor2)
{
    const int side = blockIdx.x;
    const int* deg   = side ? deg2 : deg1;
    int* start  = side ? start2 : start1;
    int* cursor = side ? cursor2 : cursor1;

    __shared__ int part[1024];
    const int t = threadIdx.x;
    const int base = t * 32;
    int local[32];
    int sum = 0;
    #pragma unroll
    for (int i = 0; i < 32; i++) { local[i] = deg[base+i]; sum += local[i]; }
    part[t] = sum;
    __syncthreads();
    for (int off = 1; off < 1024; off <<= 1) {
        int v = (t >= off) ? part[t-off] : 0;
        __syncthreads();
        part[t] += v;
        __syncthreads();
    }
    int run = part[t] - sum;   // exclusive
    #pragma unroll
    for (int i = 0; i < 32; i++) {
        start[base+i] = run;
        cursor[base+i] = run;
        run += local[i];
    }
    if (t == 1023) start[BN] = run;   // sentinel == EE
}

__global__ __launch_bounds__(256) void scatter_kernel(
    const int* __restrict__ edst1, const int* __restrict__ edst2,
    int* __restrict__ cursor1, int* __restrict__ cursor2,
    int* __restrict__ rank1, int* __restrict__ rank2)
{
    const int e = blockIdx.x*256 + threadIdx.x;
    {
        const int d = edst1[e];
        rank1[e] = atomicAdd(&cursor1[d], 1);
    }
    {
        const int d = edst2[e];
        rank2[e] = atomicAdd(&cursor2[d], 1);
    }
}

// ---------------------------------------------------------------------------
// featgen: per-edge feature row (rank-ordered) -> featH[rank][32] bf16
//   k 0..13 = ef, 14..29 = rbf, 30 = 1.0 (bias hook), 31 = 0
// ---------------------------------------------------------------------------
__global__ __launch_bounds__(256) void featgen_kernel(
    const float* __restrict__ efeat1, const float* __restrict__ efeat2,
    const int* __restrict__ esrc1, const int* __restrict__ esrc2,
    const int* __restrict__ edst1, const int* __restrict__ edst2,
    const float* __restrict__ coords1, const float* __restrict__ coords2,
    const int* __restrict__ rank1, const int* __restrict__ rank2,
    short* __restrict__ featH1, short* __restrict__ featH2)
{
    const int side = blockIdx.y;
    const float* ef     = side ? efeat2  : efeat1;
    const int*   esrc   = side ? esrc2   : esrc1;
    const int*   edst   = side ? edst2   : edst1;
    const float* coords = side ? coords2 : coords1;
    const int*   rank   = side ? rank2   : rank1;
    short* featH = side ? featH2 : featH1;

    const int e = blockIdx.x*256 + threadIdx.x;
    const int src = esrc[e], dst = edst[e];

    short f[32];
    #pragma unroll
    for (int k = 0; k < 14; k++) f[k] = f2bf(ef[(size_t)e*DE + k]);

    const float dx = coords[src*3+0] - coords[dst*3+0];
    const float dy = coords[src*3+1] - coords[dst*3+1];
    const float dz = coords[src*3+2] - coords[dst*3+2];
    const float dist = sqrtf(dx*dx + dy*dy + dz*dz + 1e-12f);
    #pragma unroll
    for (int k = 0; k < 16; k++) {
        const float t = 3.2f*dist - 1.0666666667f*(float)k;
        f[14+k] = f2bf(__expf(-t*t));
    }
    f[30] = f2bf(1.0f);
    f[31] = 0;

    short* out = featH + (size_t)rank[e]*32;
    #pragma unroll
    for (int q = 0; q < 4; q++)
        *(short8*)&out[q*8] = *(short8*)&f[q*8];
}

// ---------------------------------------------------------------------------
// featpad: zero the 16-row pad past EE so tail tiles read finite zeros
// ---------------------------------------------------------------------------
__global__ __launch_bounds__(256) void featpad_kernel(
    short* __restrict__ featH1, short* __restrict__ featH2)
{
    const int i = threadIdx.x;   // 16*32 = 512 shorts... use 256 threads x2
    featH1[(size_t)EE*32 + i] = 0;
    featH1[(size_t)EE*32 + 256 + i] = 0;
    featH2[(size_t)EE*32 + i] = 0;
    featH2[(size_t)EE*32 + 256 + i] = 0;
}

// ---------------------------------------------------------------------------
// prep_wt: build WT[208][32] hi/lo for the edge projection.
// ---------------------------------------------------------------------------
__global__ __launch_bounds__(256) void prep_wt_kernel(
    const float* __restrict__ W_edge, const float* __restrict__ W_rbf,
    const float* __restrict__ b_rbf,
    short* __restrict__ WTH, short* __restrict__ WTL)
{
    const int idx = blockIdx.x*256 + threadIdx.x;
    if (idx >= 208*32) return;
    const int c = idx >> 5, k = idx & 31;
    float v = 0.f;
    if (c < 100) {
        if (k < 14) v = W_edge[k*100 + c];
    } else if (c < 200) {
        const int cc = c - 100;
        if (k >= 14 && k < 30) v = W_rbf[(k-14)*100 + cc];
        else if (k == 30) v = b_rbf[cc];
    }
    const short hi = f2bf(v);
    WTH[idx] = hi;
    WTL[idx] = f2bf(v - bf2f(hi));
}

// ---------------------------------------------------------------------------
// gather_mfma v6: v5 structure with the VGPR cap fixed. Evidence across
// rounds: __launch_bounds__(256,N) caps arch-VGPRs at ~256/N on gfx950
// ((256,4)->64, (256,3)->84, (256,2)->112-fit). v5's live state (~110 regs:
// acc[13]=52 + colacc=13 + aC/aN=16 + hoisted h/ln) under the 84-cap spilled
// the accumulator per tile -> 900 MB scratch traffic, 336 us. (256,2) caps
// at ~128 >= 110 -> no spill; occupancy is then LDS-limited at 4 blocks/CU
// (36.9 KB), 16 waves/CU with VGPR<=128.
// One wave = 4 consecutive nodes (#pragma unroll 1 loop, static body);
// W staged once per block in LDS stride-40 rows; feat prefetched 1 tile
// ahead; h RMW loads hoisted; 5 start[] values via one load + readlane.
// ---------------------------------------------------------------------------
__global__ __launch_bounds__(256, 2) void gather_mfma(
    const short* __restrict__ featH1, const short* __restrict__ featH2,
    const int* __restrict__ start1, const int* __restrict__ start2,
    const short* __restrict__ WTH, const short* __restrict__ WTL,
    const float* __restrict__ ln_g, const float* __restrict__ ln_b,
    float* __restrict__ h1, float* __restrict__ h2)
{
    __shared__ short sWH[208*40];    // 16.6 KB, stride-40 (80B) rows
    __shared__ short sWL[208*40];    // 16.6 KB
    __shared__ float plane[4][216];

    const int tid = threadIdx.x;
    const int wv = tid >> 6, lane = tid & 63;
    const int arow = lane & 15, aq = lane >> 4;

    // stage W once per block (832 short8 per array)
    for (int f = tid; f < 832; f += 256) {
        const int d = f >> 2, cc = (f & 3) * 8;
        *(short8*)&sWH[d*40 + cc] = *(const short8*)&WTH[f*8];
        *(short8*)&sWL[d*40 + cc] = *(const short8*)&WTL[f*8];
    }
    __syncthreads();

    const int side = blockIdx.y;
    const short* feat = side ? featH2 : featH1;
    const int*  start = side ? start2 : start1;
    float* h = side ? h2 : h1;

    const int c0 = blockIdx.x*16 + wv*4;     // wave's first node (of 4)

    // hoist ln params (lane-mapped)
    const float g0 = ln_g[lane],      bb0 = ln_b[lane];
    const float g1 = ln_g[64+lane],   bb1 = ln_b[64+lane];
    const float g2 = ln_g[128+lane],  bb2 = ln_b[128+lane];
    const float g3 = (lane < 8) ? ln_g[192+lane] : 0.f;
    const float bb3 = (lane < 8) ? ln_b[192+lane] : 0.f;

    // 5 start values for the 4 nodes, one load, then readlane
    const int sidx = (lane < 5) ? lane : 4;
    const int sv = start[c0 + sidx];

    const int lb = arow*40 + aq*8;           // LDS element offset in a W tile

    #pragma unroll 1
    for (int ni = 0; ni < 4; ni++) {
        const int st = __builtin_amdgcn_readlane(sv, ni);
        const int en = __builtin_amdgcn_readlane(sv, ni + 1);
        const int dg = en - st;
        const int node = c0 + ni;
        const size_t hbase = (size_t)node * DH;

        // hoist h RMW loads (consumed at node end, hidden under tiles)
        const float hv0 = h[hbase + lane];
        const float hv1 = h[hbase + 64 + lane];
        const float hv2 = h[hbase + 128 + lane];
        const float hv3 = (lane < 8) ? h[hbase + 192 + lane] : 0.f;

        float colacc[13];
        #pragma unroll
        for (int nt = 0; nt < 13; nt++) colacc[nt] = 0.f;
        float musum = 0.f;

        short8 aC = *(const short8*)&feat[(size_t)(st + arow)*32 + aq*8];

        for (int t0 = 0; t0 < dg; t0 += 16) {
            // prefetch next tile; overshoot lands in next node's rows or the
            // zeroed 16-row pad (start[BN]=EE sentinel) — discarded if unused
            const short8 aN = *(const short8*)&feat[(size_t)(st + t0 + 16 + arow)*32 + aq*8];

            f32x4 acc[13];
            #pragma unroll
            for (int nt = 0; nt < 13; nt++) {
                const short8 whv = *(const short8*)&sWH[nt*640 + lb];
                const short8 wlv = *(const short8*)&sWL[nt*640 + lb];
                f32x4 z = (f32x4){0.f,0.f,0.f,0.f};
                z = __builtin_amdgcn_mfma_f32_16x16x32_bf16(aC, whv, z, 0, 0, 0);
                z = __builtin_amdgcn_mfma_f32_16x16x32_bf16(aC, wlv, z, 0, 0, 0);
                acc[nt] = z;
            }
            // relu + per-row (per-edge) stats; row = t0 + aq*4 + r
            float sr[4] = {0.f,0.f,0.f,0.f}, s2r[4] = {0.f,0.f,0.f,0.f};
            #pragma unroll
            for (int nt = 0; nt < 13; nt++) {
                #pragma unroll
                for (int r = 0; r < 4; r++) {
                    const float v = fmaxf(acc[nt][r], 0.f);
                    acc[nt][r] = v;
                    sr[r] += v; s2r[r] += v*v;
                }
            }
            #pragma unroll
            for (int off = 1; off < 16; off <<= 1) {
                #pragma unroll
                for (int r = 0; r < 4; r++) {
                    sr[r]  += __shfl_xor(sr[r],  off, 64);
                    s2r[r] += __shfl_xor(s2r[r], off, 64);
                }
            }
            #pragma unroll
            for (int r = 0; r < 4; r++) {
                const bool valid = (t0 + aq*4 + r) < dg;
                const float mean = sr[r] * (1.0f/DH);
                const float var  = s2r[r] * (1.0f/DH) - mean*mean;
                const float rs   = rsqrtf(var + 1e-5f);
                const float rstd = valid ? rs : 0.f;
                musum += valid ? mean*rs : 0.f;
                #pragma unroll
                for (int nt = 0; nt < 13; nt++)
                    colacc[nt] += rstd*acc[nt][r];
            }
            aC = aN;
        }

        // reduce over the 4 aq groups (rows partition)
        #pragma unroll
        for (int nt = 0; nt < 13; nt++) {
            colacc[nt] += __shfl_xor(colacc[nt], 16, 64);
            colacc[nt] += __shfl_xor(colacc[nt], 32, 64);
        }
        musum += __shfl_xor(musum, 16, 64);
        musum += __shfl_xor(musum, 32, 64);

        if (aq == 0) {
            #pragma unroll
            for (int nt = 0; nt < 13; nt++)
                plane[wv][nt*16 + arow] = colacc[nt];
        }
        // wave-internal LDS producer/consumer: DS pipe is in-order per wave —
        // no barrier (and the next node's writes issue after these reads)

        const float dgf = (float)dg;
        h[hbase + lane]       = hv0 + g0*(plane[wv][lane]     - musum) + dgf*bb0;
        h[hbase + 64 + lane]  = hv1 + g1*(plane[wv][64+lane]  - musum) + dgf*bb1;
        h[hbase + 128 + lane] = hv2 + g2*(plane[wv][128+lane] - musum) + dgf*bb2;
        if (lane < 8)
            h[hbase + 192 + lane] = hv3 + g3*(plane[wv][192+lane] - musum) + dgf*bb3;
    }
}

// ---------------------------------------------------------------------------
// cvt (per half): h fp32 -> hb hi/lo [16384][224] rows + hbT hi/lo [32][224][512]
// ---------------------------------------------------------------------------
__global__ __launch_bounds__(256) void cvt_kernel(
    const float* __restrict__ h1, const float* __restrict__ h2, const int half,
    short* __restrict__ hbH1, short* __restrict__ hbL1,
    short* __restrict__ hbH2, short* __restrict__ hbL2,
    short* __restrict__ hTH1, short* __restrict__ hTL1,
    short* __restrict__ hTH2, short* __restrict__ hTL2)
{
    const int side = blockIdx.y;
    const float* h = side ? h2 : h1;
    short* hbH = side ? hbH2 : hbH1;
    short* hbL = side ? hbL2 : hbL1;
    short* hTH = side ? hTH2 : hTH1;
    short* hTL = side ? hTL2 : hTL1;

    const int nl0 = blockIdx.x * 64;          // local node
    const int bl = nl0 >> 9, m0 = nl0 & 511;
    const int ng0 = half*HBN + nl0;

    __shared__ short tH[64][226];
    __shared__ short tL[64][226];
    const int tid = threadIdx.x;
    for (int i = tid; i < 64*224; i += 256) {
        const int r = i / 224, c = i - r*224;
        const float v = (c < DH) ? h[(size_t)(ng0+r)*DH + c] : 0.f;
        const short hi = f2bf(v);
        const short lo = f2bf(v - bf2f(hi));
        tH[r][c] = hi; tL[r][c] = lo;
        hbH[(size_t)(nl0+r)*224 + c] = hi;
        hbL[(size_t)(nl0+r)*224 + c] = lo;
    }
    __syncthreads();
    for (int i = tid; i < 224*64; i += 256) {
        const int c = i >> 6, m = i & 63;
        const size_t o = ((size_t)bl*224 + c)*NN + m0 + m;
        hTH[o] = tH[m][c];
        hTL[o] = tL[m][c];
    }
}

// ---------------------------------------------------------------------------
// prep_w: W_down[400][200] -> WbTHI/LO[208][448] (transposed, padded, split)
// ---------------------------------------------------------------------------
__global__ __launch_bounds__(256) void prep_w_kernel(
    const float* __restrict__ W_down,
    short* __restrict__ WbTHI, short* __restrict__ WbTLO)
{
    const int idx = blockIdx.x*256 + threadIdx.x;
    if (idx >= 208*448) return;
    const int c = idx / 448, kk = idx - c*448;
    float v = 0.f;
    if (c < 200) {
        if (kk < 200) v = W_down[(size_t)kk*DH + c];
        else if (kk >= 224 && kk < 424) v = W_down[(size_t)(200 + kk - 224)*DH + c];
    }
    const short hi = f2bf(v);
    WbTHI[idx] = hi;
    WbTLO[idx] = f2bf(v - bf2f(hi));
}

// ---------------------------------------------------------------------------
// Fused attention v4: 16 Q-rows per block, 4 waves split 32 key-tiles;
// K/V streamed from global (L2); 3 barriers per block.
// XCD-aware block remap: dispatch ids == k (mod 8) land on XCD k (round-robin,
// m09); map them to batches 4k..4k+3 so each XCD's concurrent K/V working set
// is 4 x ~885KB ~= 3.5MB < 4MB L2 -> cross-block K/V reuse becomes L2 hits.
// ---------------------------------------------------------------------------
__global__ __launch_bounds__(256, 4) void attn_kernel(
    const short* __restrict__ QH, const short* __restrict__ QL,
    const short* __restrict__ KH, const short* __restrict__ KL,
    const short* __restrict__ VTH, const short* __restrict__ VTL,
    short* __restrict__ cb)
{
    const int id = blockIdx.x + (blockIdx.y << 5);   // gridDim.x == 32
    const int j  = id >> 3;
    const int b  = (id & 7)*4 + (j >> 5);            // half-local batch
    const int q0 = (j & 31) << 4;
    const short* Qh = QH + (size_t)b*NN*224;
    const short* Ql = QL + (size_t)b*NN*224;
    const short* Kh = KH + (size_t)b*NN*224;
    const short* Kl = KL + (size_t)b*NN*224;
    const short* Vh = VTH + (size_t)b*224*NN;
    const short* Vl = VTL + (size_t)b*224*NN;

    __shared__ short pb[16*520];              // 16.3 KB P bf16
    __shared__ float sm_[4][16];
    __shared__ float ss_[4][16];

    const int tid = threadIdx.x;
    const int wv = tid >> 6, lane = tid & 63;
    const int arow = lane & 15, aq = lane >> 4;

    const int qrow = q0 + arow;
    short8 qfh[7], qfl[7];
    #pragma unroll
    for (int k = 0; k < 7; k++) {
        qfh[k] = *(const short8*)&Qh[(size_t)qrow*224 + k*32 + aq*8];
        qfl[k] = *(const short8*)&Ql[(size_t)qrow*224 + k*32 + aq*8];
    }

    f32x4 acc[8];
    #pragma unroll
    for (int t = 0; t < 8; t++) acc[t] = (f32x4){0.f,0.f,0.f,0.f};

    #pragma unroll
    for (int t = 0; t < 8; t++) {
        const size_t kb = (size_t)((wv*8 + t)*16 + arow)*224;
        #pragma unroll
        for (int k = 0; k < 7; k++) {
            const short8 bh = *(const short8*)&Kh[kb + k*32 + aq*8];
            const short8 bl = *(const short8*)&Kl[kb + k*32 + aq*8];
            acc[t] = __builtin_amdgcn_mfma_f32_16x16x32_bf16(qfh[k], bh, acc[t], 0, 0, 0);
            acc[t] = __builtin_amdgcn_mfma_f32_16x16x32_bf16(qfh[k], bl, acc[t], 0, 0, 0);
            acc[t] = __builtin_amdgcn_mfma_f32_16x16x32_bf16(qfl[k], bh, acc[t], 0, 0, 0);
        }
    }

    float mr[4], sr[4], iv[4];
    #pragma unroll
    for (int r = 0; r < 4; r++) {
        float m = -1e30f;
        #pragma unroll
        for (int t = 0; t < 8; t++) {
            acc[t][r] *= T_SCALE;
            m = fmaxf(m, acc[t][r]);
        }
        m = fmaxf(m, __shfl_xor(m, 1, 64));
        m = fmaxf(m, __shfl_xor(m, 2, 64));
        m = fmaxf(m, __shfl_xor(m, 4, 64));
        m = fmaxf(m, __shfl_xor(m, 8, 64));
        mr[r] = m;
    }
    if (arow == 0) {
        #pragma unroll
        for (int r = 0; r < 4; r++) sm_[wv][aq*4+r] = mr[r];
    }
    __syncthreads();
    #pragma unroll
    for (int r = 0; r < 4; r++) {
        const int row = aq*4 + r;
        const float M = fmaxf(fmaxf(sm_[0][row], sm_[1][row]),
                              fmaxf(sm_[2][row], sm_[3][row]));
        float s = 0.f;
        #pragma unroll
        for (int t = 0; t < 8; t++) {
            const float e = __expf(acc[t][r] - M);
            acc[t][r] = e;
            s += e;
        }
        s += __shfl_xor(s, 1, 64);
        s += __shfl_xor(s, 2, 64);
        s += __shfl_xor(s, 4, 64);
        s += __shfl_xor(s, 8, 64);
        sr[r] = s;
    }
    if (arow == 0) {
        #pragma unroll
        for (int r = 0; r < 4; r++) ss_[wv][aq*4+r] = sr[r];
    }
    __syncthreads();
    #pragma unroll
    for (int r = 0; r < 4; r++) {
        const int row = aq*4 + r;
        iv[r] = 1.0f / (ss_[0][row] + ss_[1][row] + ss_[2][row] + ss_[3][row]);
    }

    #pragma unroll
    for (int t = 0; t < 8; t++) {
        const int col = (wv*8 + t)*16 + arow;
        #pragma unroll
        for (int r = 0; r < 4; r++)
            pb[(aq*4 + r)*520 + col] = f2bf(acc[t][r] * iv[r]);
    }
    __syncthreads();

    const int nbase = (wv == 0) ? 0 : 3*wv + 1;
    const int ncnt  = (wv == 0) ? 4 : 3;
    f32x4 pacc[4];
    #pragma unroll
    for (int t = 0; t < 4; t++) pacc[t] = (f32x4){0.f,0.f,0.f,0.f};

    for (int k0 = 0; k0 < NN; k0 += 32) {
        const short8 a = *(const short8*)&pb[arow*520 + k0 + aq*8];
        #pragma unroll
        for (int t = 0; t < 4; t++) {
            if (t < ncnt) {
                const size_t vb = (size_t)((nbase+t)*16 + arow)*NN + k0 + aq*8;
                const short8 bh = *(const short8*)&Vh[vb];
                const short8 bl = *(const short8*)&Vl[vb];
                pacc[t] = __builtin_amdgcn_mfma_f32_16x16x32_bf16(a, bh, pacc[t], 0, 0, 0);
                pacc[t] = __builtin_amdgcn_mfma_f32_16x16x32_bf16(a, bl, pacc[t], 0, 0, 0);
            }
        }
    }

    #pragma unroll
    for (int t = 0; t < 4; t++) {
        if (t < ncnt) {
            const int col = (nbase+t)*16 + arow;
            #pragma unroll
            for (int r = 0; r < 4; r++) {
                const int row = q0 + aq*4 + r;
                const short v = (col < DH) ? f2bf(pacc[t][r]) : (short)0;
                cb[((size_t)b*NN + row)*224 + col] = v;
            }
        }
    }
    if (wv == 3) {
        const int col = 208 + arow;
        #pragma unroll
        for (int r = 0; r < 4; r++) {
            const int row = q0 + aq*4 + r;
            cb[((size_t)b*NN + row)*224 + col] = 0;
        }
    }
}

// ---------------------------------------------------------------------------
// down (per half, MFMA, split-W): relu([hb|cb] @ W_down) + degree_table -> hsg
// ---------------------------------------------------------------------------
__global__ __launch_bounds__(256) void down_mfma(
    const short* __restrict__ hbH1, const short* __restrict__ hbH2,
    const short* __restrict__ cb1, const short* __restrict__ cb2,
    const int* __restrict__ deg1, const int* __restrict__ deg2,
    const short* __restrict__ WbTH, const short* __restrict__ WbTL,
    const float* __restrict__ degree_table,
    float* __restrict__ hsg1, float* __restrict__ hsg2, const int half)
{
    const int side = blockIdx.y;
    const short* X0 = side ? hbH2 : hbH1;
    const short* X1 = side ? cb2 : cb1;
    const int*   dgp = side ? deg2 : deg1;
    float* hsg = side ? hsg2 : hsg1;

    const int nl0 = blockIdx.x * 64;
    const int ng0 = half*HBN + nl0;
    const int b = ng0 >> 9;

    __shared__ short As[64*40];
    __shared__ short BsH[208*40];
    __shared__ short BsL[208*40];
    __shared__ float part[208];

    const int tid = threadIdx.x;
    const int wv = tid >> 6, lane = tid & 63;
    const int arow = lane & 15, aq = lane >> 4;

    if (tid < 208) part[tid] = 0.f;

    f32x4 acc[13];
    #pragma unroll
    for (int t = 0; t < 13; t++) acc[t] = (f32x4){0.f,0.f,0.f,0.f};

    const int sr = tid >> 2, sc = (tid & 3) * 8;

    for (int phase = 0; phase < 2; phase++) {
        const short* X = phase ? X1 : X0;
        for (int k0 = 0; k0 < 224; k0 += 32) {
            __syncthreads();
            *(short8*)&As[sr*40 + sc] =
                *(const short8*)&X[(size_t)(nl0+sr)*224 + k0 + sc];
            const int kkg = phase*224 + k0;
            #pragma unroll
            for (int pass = 0; pass < 4; pass++) {
                const int f = pass*256 + tid;
                if (f < 832) {
                    const int d = f >> 2, cc = (f & 3) * 8;
                    *(short8*)&BsH[d*40 + cc] = *(const short8*)&WbTH[(size_t)d*448 + kkg + cc];
                    *(short8*)&BsL[d*40 + cc] = *(const short8*)&WbTL[(size_t)d*448 + kkg + cc];
                }
            }
            __syncthreads();
            const short8 a = *(const short8*)&As[(16*wv + arow)*40 + aq*8];
            #pragma unroll
            for (int t = 0; t < 13; t++) {
                const short8 bh = *(const short8*)&BsH[(t*16 + arow)*40 + aq*8];
                const short8 bl = *(const short8*)&BsL[(t*16 + arow)*40 + aq*8];
                acc[t] = __builtin_amdgcn_mfma_f32_16x16x32_bf16(a, bh, acc[t], 0, 0, 0);
                acc[t] = __builtin_amdgcn_mfma_f32_16x16x32_bf16(a, bl, acc[t], 0, 0, 0);
            }
        }
    }
    __syncthreads();

    int dgc[4];
    #pragma unroll
    for (int r = 0; r < 4; r++) {
        int d = dgp[ng0 + 16*wv + aq*4 + r];
        dgc[r] = d > 199 ? 199 : d;
    }
    #pragma unroll
    for (int nt = 0; nt < 13; nt++) {
        const int col = nt*16 + arow;
        float s = 0.f;
        if (col < DH) {
            #pragma unroll
            for (int r = 0; r < 4; r++)
                s += fmaxf(acc[nt][r], 0.f) + degree_table[dgc[r]*DH + col];
        }
        s += __shfl_xor(s, 16, 64);
        s += __shfl_xor(s, 32, 64);
        if (lane < 16 && col < DH) atomicAdd(&part[col], s);
    }
    __syncthreads();
    if (tid < DH) unsafeAtomicAdd(&hsg[b*206 + tid], part[tid] * (1.0f/512.0f));
}

// ---------------------------------------------------------------------------
// Kernel 6: interaction mean over nodes -> hsg cols 200..205
// ---------------------------------------------------------------------------
__global__ __launch_bounds__(192) void inter_kernel(
    const float* __restrict__ i1, const float* __restrict__ i2,
    float* __restrict__ hsg1, float* __restrict__ hsg2)
{
    const int side = blockIdx.y;
    const float* it = side ? i2 : i1;
    float* hsg = side ? hsg2 : hsg1;
    const int b = blockIdx.x;
    __shared__ float red[192];
    const int tid = threadIdx.x;
    const int j = tid % 6, seg = tid / 6;
    float s = 0.0f;
    for (int n = seg*16; n < seg*16 + 16; n++)
        s += it[(size_t)b*NN*DI + n*DI + j];
    red[tid] = s;
    __syncthreads();
    if (tid < 6) {
        float tot = 0.0f;
        for (int sg2 = 0; sg2 < 32; sg2++) tot += red[sg2*6 + tid];
        hsg[b*206 + 200 + tid] = tot * (1.0f/512.0f);
    }
}

// ---------------------------------------------------------------------------
// Kernel 7: final MLP, one block per batch row
// ---------------------------------------------------------------------------
__global__ __launch_bounds__(256) void mlp_kernel(
    const float* __restrict__ hsg1, const float* __restrict__ hsg2,
    const float* __restrict__ W_f1, const float* __restrict__ b_f1,
    const float* __restrict__ W_f2, const float* __restrict__ b_f2,
    const float* __restrict__ W_f3, const float* __restrict__ b_f3,
    const float* __restrict__ W_f4, const float* __restrict__ b_f4,
    float* __restrict__ out)
{
    const int b = blockIdx.x;
    __shared__ float x[618];
    __shared__ float y1[400];
    __shared__ float y2[200];
    __shared__ float y3[100];
    __shared__ float red[256];
    const int tid = threadIdx.x;

    if (tid < 206) {
        const float a = hsg1[b*206 + tid], bb = hsg2[b*206 + tid];
        x[tid] = a; x[206 + tid] = bb; x[412 + tid] = a - bb;
    }
    __syncthreads();
    for (int c = tid; c < 400; c += 256) {
        float acc = b_f1[c];
        for (int k = 0; k < 618; k++) acc += x[k]*W_f1[(size_t)k*400 + c];
        y1[c] = fmaxf(acc, 0.0f);
    }
    __syncthreads();
    if (tid < 200) {
        float acc = b_f2[tid];
        for (int k = 0; k < 400; k++) acc += y1[k]*W_f2[k*200 + tid];
        y2[tid] = fmaxf(acc, 0.0f);
    }
    __syncthreads();
    if (tid < 100) {
        float acc = b_f3[tid];
        for (int k = 0; k < 200; k++) acc += y2[k]*W_f3[k*100 + tid];
        y3[tid] = fmaxf(acc, 0.0f);
    }
    __syncthreads();
    red[tid] = (tid < 100) ? y3[tid]*W_f4[tid] : 0.0f;
    __syncthreads();
    for (int s = 128; s > 0; s >>= 1) {
        if (tid < s) red[tid] += red[tid + s];
        __syncthreads();
    }
    if (tid == 0) out[b] = red[0] + b_f4[0];
}

// ---------------------------------------------------------------------------
extern "C" void kernel_launch(void* const* d_in, const int* in_sizes, int n_in,
                              void* d_out, int out_size, void* d_ws, size_t ws_size,
                              hipStream_t stream)
{
    const float* atom1  = (const float*)d_in[0];
    const float* atom2  = (const float*)d_in[1];
    const float* coords1= (const float*)d_in[2];
    const float* coords2= (const float*)d_in[3];
    const float* efeat1 = (const float*)d_in[4];
    const float* efeat2 = (const float*)d_in[5];
    const float* inter1 = (const float*)d_in[6];
    const float* inter2 = (const float*)d_in[7];
    const int*   esrc1  = (const int*)d_in[8];
    const int*   edst1  = (const int*)d_in[9];
    const int*   esrc2  = (const int*)d_in[10];
    const int*   edst2  = (const int*)d_in[11];
    const float* W_atom = (const float*)d_in[12];
    const float* W_edge = (const float*)d_in[13];
    const float* W_rbf  = (const float*)d_in[14];
    const float* b_rbf  = (const float*)d_in[15];
    const float* ln_g   = (const float*)d_in[16];
    const float* ln_b   = (const float*)d_in[17];
    const float* W_down = (const float*)d_in[18];
    const float* deg_tab= (const float*)d_in[19];
    const float* W_f1   = (const float*)d_in[20];
    const float* b_f1   = (const float*)d_in[21];
    const float* W_f2   = (const float*)d_in[22];
    const float* b_f2   = (const float*)d_in[23];
    const float* W_f3   = (const float*)d_in[24];
    const float* b_f3   = (const float*)d_in[25];
    const float* W_f4   = (const float*)d_in[26];
    const float* b_f4   = (const float*)d_in[27];
    float* out = (float*)d_out;

    // ---- workspace layout (~133 MB)
    float* ws = (float*)d_ws;
    const size_t HSZ = (size_t)BN*DH;              // per-side h floats
    float* h1  = ws;
    float* h2  = h1 + HSZ;
    // pool: max(feat 2*(EE+16)*32 shorts, bf16 pool 10*HB shorts)
    short* pool = (short*)(h2 + HSZ);
    const size_t FSZ = (size_t)(EE+16)*32;
    short* featH1 = pool;
    short* featH2 = featH1 + FSZ;
    const size_t HB = (size_t)32*NN*224;           // 3,670,016 shorts
    short* hbH1 = pool;           short* hbL1 = hbH1 + HB;
    short* hbH2 = hbL1 + HB;      short* hbL2 = hbH2 + HB;
    short* hTH1 = hbL2 + HB;      short* hTL1 = hTH1 + HB;
    short* hTH2 = hTL1 + HB;      short* hTL2 = hTH2 + HB;
    short* cb1  = hTL2 + HB;      short* cb2  = cb1 + HB;
    size_t pool_sz = 2*FSZ > 10*HB ? 2*FSZ : 10*HB;
    short* after = pool + pool_sz;
    short* WTH = after;                            // [208][32]
    short* WTL = WTH + 208*32;
    short* WbTH = WTL + 208*32;                    // [208][448]
    short* WbTL = WbTH + 208*448;
    float* hsg1 = (float*)(WbTL + 208*448);
    float* hsg2 = hsg1 + (size_t)BB*206;
    int* deg1 = (int*)(hsg2 + (size_t)BB*206);
    int* deg2 = deg1 + BN;
    int* start1 = deg2 + BN;                       // BN+1 entries
    int* start2 = start1 + (BN+1);
    int* cursor1 = start2 + (BN+1);
    int* cursor2 = cursor1 + BN;
    int* rank1 = cursor2 + BN;
    int* rank2 = rank1 + EE;

    hipMemsetAsync(deg1, 0, 2*(size_t)BN*sizeof(int), stream);
    hipMemsetAsync(hsg1, 0, 2*(size_t)BB*206*sizeof(float), stream);

    node_kernel<<<dim3(BN/4, 2), 256, 0, stream>>>(
        atom1, atom2, W_atom, ln_g, ln_b, h1, h2);

    hist_kernel<<<EE/256, 256, 0, stream>>>(edst1, edst2, deg1, deg2);
    scan_kernel<<<2, 1024, 0, stream>>>(deg1, deg2, start1, start2, cursor1, cursor2);
    scatter_kernel<<<EE/256, 256, 0, stream>>>(edst1, edst2, cursor1, cursor2,
                                               rank1, rank2);

    featgen_kernel<<<dim3(EE/256, 2), 256, 0, stream>>>(
        efeat1, efeat2, esrc1, esrc2, edst1, edst2, coords1, coords2,
        rank1, rank2, featH1, featH2);
    featpad_kernel<<<1, 256, 0, stream>>>(featH1, featH2);

    prep_wt_kernel<<<(208*32 + 255)/256, 256, 0, stream>>>(
        W_edge, W_rbf, b_rbf, WTH, WTL);

    gather_mfma<<<dim3(BN/16, 2), 256, 0, stream>>>(
        featH1, featH2, start1, start2, WTH, WTL, ln_g, ln_b, h1, h2);

    prep_w_kernel<<<(208*448 + 255)/256, 256, 0, stream>>>(W_down, WbTH, WbTL);

    for (int half = 0; half < 2; half++) {
        cvt_kernel<<<dim3(HBN/64, 2), 256, 0, stream>>>(
            h1, h2, half, hbH1, hbL1, hbH2, hbL2, hTH1, hTL1, hTH2, hTL2);
        // dir0: c1 = softmax_rows(h1@h2^T) @ h2
        attn_kernel<<<dim3(NN/16, 32), 256, 0, stream>>>(
            hbH1, hbL1, hbH2, hbL2, hTH2, hTL2, cb1);
        // dir1: c2 = softmax_rows(h2@h1^T) @ h1
        attn_kernel<<<dim3(NN/16, 32), 256, 0, stream>>>(
            hbH2, hbL2, hbH1, hbL1, hTH1, hTL1, cb2);
        down_mfma<<<dim3(HBN/64, 2), 256, 0, stream>>>(
            hbH1, hbH2, cb1, cb2, deg1, deg2, WbTH, WbTL, deg_tab,
            hsg1, hsg2, half);
    }

    inter_kernel<<<dim3(BB, 2), 192, 0, stream>>>(inter1, inter2, hsg1, hsg2);

    mlp_kernel<<<BB, 256, 0, stream>>>(
        hsg1, hsg2, W_f1, b_f1, W_f2, b_f2, W_f3, b_f3, W_f4, b_f4, out);
}

// Round 5
// 1106.176 us; speedup vs baseline: 1.2328x; 1.0088x over previous
//
#include <hip/hip_runtime.h>
#include <cstddef>
#include <cstdint>

// Problem constants
#define BB   64
#define NN   512
#define BN   (BB*NN)          // 32768
#define HBN  16384            // nodes per half
#define EE   524288
#define DA   70
#define DE   14
#define DH   200
#define DI   6
#define T_SCALE 0.07071067811865475f   // sqrt(1/200)

typedef __attribute__((ext_vector_type(8))) short short8;
typedef __attribute__((ext_vector_type(4))) float f32x4;

__device__ __forceinline__ short f2bf(float x) {
    union { float f; unsigned u; } v; v.f = x;
    const unsigned r = v.u + 0x7FFFu + ((v.u >> 16) & 1u);   // RNE
    return (short)(r >> 16);
}
__device__ __forceinline__ float bf2f(short s) {
    union { unsigned u; float f; } v;
    v.u = ((unsigned)(unsigned short)s) << 16;
    return v.f;
}

// 16-lane (row) sum via DPP — pure VALU, no DS pipe, no address VGPRs.
// Steps: quad_perm(1,0,3,2)=xor1, quad_perm(2,3,0,1)=xor2,
// row_half_mirror(i^7)=cross-quad, row_mirror(i^15)=cross-8group.
__device__ __forceinline__ float dpp16_sum(float x) {
    union { float f; int i; } a, b;
    a.f = x;
    b.i = __builtin_amdgcn_update_dpp(0, a.i, 0xB1, 0xF, 0xF, false); a.f += b.f;
    b.i = __builtin_amdgcn_update_dpp(0, a.i, 0x4E, 0xF, 0xF, false); a.f += b.f;
    b.i = __builtin_amdgcn_update_dpp(0, a.i, 0x141, 0xF, 0xF, false); a.f += b.f;
    b.i = __builtin_amdgcn_update_dpp(0, a.i, 0x140, 0xF, 0xF, false); a.f += b.f;
    return a.f;
}

// ---------------------------------------------------------------------------
// Kernel 1: per-node  h = layernorm(relu(atom @ W_atom))
// ---------------------------------------------------------------------------
__global__ __launch_bounds__(256) void node_kernel(
    const float* __restrict__ atom1, const float* __restrict__ atom2,
    const float* __restrict__ W_atom,
    const float* __restrict__ ln_g, const float* __restrict__ ln_b,
    float* __restrict__ h1, float* __restrict__ h2)
{
    const int side = blockIdx.y;
    const float* atom = side ? atom2 : atom1;
    float* h = side ? h2 : h1;
    const int node0 = blockIdx.x * 4;
    const int tid = threadIdx.x;

    __shared__ float arow[4][DA];
    __shared__ float vals[4][DH];

    for (int i = tid; i < 4*DA; i += 256) {
        const int n = i / DA, k = i % DA;
        arow[n][k] = atom[(size_t)(node0+n)*DA + k];
    }
    __syncthreads();

    if (tid < DH) {
        float a0 = 0.f, a1 = 0.f, a2 = 0.f, a3 = 0.f;
        #pragma unroll 7
        for (int k = 0; k < DA; k++) {
            const float w = W_atom[k*DH + tid];
            a0 += arow[0][k]*w; a1 += arow[1][k]*w;
            a2 += arow[2][k]*w; a3 += arow[3][k]*w;
        }
        vals[0][tid] = fmaxf(a0, 0.f);
        vals[1][tid] = fmaxf(a1, 0.f);
        vals[2][tid] = fmaxf(a2, 0.f);
        vals[3][tid] = fmaxf(a3, 0.f);
    }
    __syncthreads();

    const int wv = tid >> 6, lane = tid & 63;
    float v0 = vals[wv][lane];
    float v1 = vals[wv][64+lane];
    float v2 = vals[wv][128+lane];
    float v3 = (lane < 8) ? vals[wv][192+lane] : 0.0f;
    float s  = v0+v1+v2+v3;
    float s2 = v0*v0+v1*v1+v2*v2+v3*v3;
    #pragma unroll
    for (int off = 1; off < 64; off <<= 1) {
        s  += __shfl_xor(s,  off, 64);
        s2 += __shfl_xor(s2, off, 64);
    }
    const float mean = s * (1.0f/DH);
    const float var  = s2 * (1.0f/DH) - mean*mean;
    const float rstd = rsqrtf(var + 1e-5f);
    const size_t base = (size_t)(node0+wv)*DH;
    h[base + lane]       = ln_g[lane]     *(v0-mean)*rstd + ln_b[lane];
    h[base + 64 + lane]  = ln_g[64+lane]  *(v1-mean)*rstd + ln_b[64+lane];
    h[base + 128 + lane] = ln_g[128+lane] *(v2-mean)*rstd + ln_b[128+lane];
    if (lane < 8)
        h[base + 192 + lane] = ln_g[192+lane]*(v3-mean)*rstd + ln_b[192+lane];
}

// ---------------------------------------------------------------------------
// Counting sort by dst: hist -> scan(+sentinel) -> scatter (rank only)
// ---------------------------------------------------------------------------
__global__ __launch_bounds__(256) void hist_kernel(
    const int* __restrict__ edst1, const int* __restrict__ edst2,
    int* __restrict__ deg1, int* __restrict__ deg2)
{
    const int e = blockIdx.x*256 + threadIdx.x;
    atomicAdd(&deg1[edst1[e]], 1);
    atomicAdd(&deg2[edst2[e]], 1);
}

__global__ __launch_bounds__(1024) void scan_kernel(
    const int* __restrict__ deg1, const int* __restrict__ deg2,
    int* __restrict__ start1, int* __restrict__ start2,
    int* __restrict__ cursor1, int* __restrict__ cursor2)
{
    const int side = blockIdx.x;
    const int* deg   = side ? deg2 : deg1;
    int* start  = side ? start2 : start1;
    int* cursor = side ? cursor2 : cursor1;

    __shared__ int part[1024];
    const int t = threadIdx.x;
    const int base = t * 32;
    int local[32];
    int sum = 0;
    #pragma unroll
    for (int i = 0; i < 32; i++) { local[i] = deg[base+i]; sum += local[i]; }
    part[t] = sum;
    __syncthreads();
    for (int off = 1; off < 1024; off <<= 1) {
        int v = (t >= off) ? part[t-off] : 0;
        __syncthreads();
        part[t] += v;
        __syncthreads();
    }
    int run = part[t] - sum;   // exclusive
    #pragma unroll
    for (int i = 0; i < 32; i++) {
        start[base+i] = run;
        cursor[base+i] = run;
        run += local[i];
    }
    if (t == 1023) start[BN] = run;   // sentinel == EE
}

__global__ __launch_bounds__(256) void scatter_kernel(
    const int* __restrict__ edst1, const int* __restrict__ edst2,
    int* __restrict__ cursor1, int* __restrict__ cursor2,
    int* __restrict__ rank1, int* __restrict__ rank2)
{
    const int e = blockIdx.x*256 + threadIdx.x;
    {
        const int d = edst1[e];
        rank1[e] = atomicAdd(&cursor1[d], 1);
    }
    {
        const int d = edst2[e];
        rank2[e] = atomicAdd(&cursor2[d], 1);
    }
}

// ---------------------------------------------------------------------------
// featgen: per-edge feature row (rank-ordered) -> featH[rank][32] bf16
//   k 0..13 = ef, 14..29 = rbf, 30 = 1.0 (bias hook), 31 = 0
// ---------------------------------------------------------------------------
__global__ __launch_bounds__(256) void featgen_kernel(
    const float* __restrict__ efeat1, const float* __restrict__ efeat2,
    const int* __restrict__ esrc1, const int* __restrict__ esrc2,
    const int* __restrict__ edst1, const int* __restrict__ edst2,
    const float* __restrict__ coords1, const float* __restrict__ coords2,
    const int* __restrict__ rank1, const int* __restrict__ rank2,
    short* __restrict__ featH1, short* __restrict__ featH2)
{
    const int side = blockIdx.y;
    const float* ef     = side ? efeat2  : efeat1;
    const int*   esrc   = side ? esrc2   : esrc1;
    const int*   edst   = side ? edst2   : edst1;
    const float* coords = side ? coords2 : coords1;
    const int*   rank   = side ? rank2   : rank1;
    short* featH = side ? featH2 : featH1;

    const int e = blockIdx.x*256 + threadIdx.x;
    const int src = esrc[e], dst = edst[e];

    short f[32];
    #pragma unroll
    for (int k = 0; k < 14; k++) f[k] = f2bf(ef[(size_t)e*DE + k]);

    const float dx = coords[src*3+0] - coords[dst*3+0];
    const float dy = coords[src*3+1] - coords[dst*3+1];
    const float dz = coords[src*3+2] - coords[dst*3+2];
    const float dist = sqrtf(dx*dx + dy*dy + dz*dz + 1e-12f);
    #pragma unroll
    for (int k = 0; k < 16; k++) {
        const float t = 3.2f*dist - 1.0666666667f*(float)k;
        f[14+k] = f2bf(__expf(-t*t));
    }
    f[30] = f2bf(1.0f);
    f[31] = 0;

    short* out = featH + (size_t)rank[e]*32;
    #pragma unroll
    for (int q = 0; q < 4; q++)
        *(short8*)&out[q*8] = *(short8*)&f[q*8];
}

// ---------------------------------------------------------------------------
// featpad: zero the 16-row pad past EE so tail tiles read finite zeros
// ---------------------------------------------------------------------------
__global__ __launch_bounds__(256) void featpad_kernel(
    short* __restrict__ featH1, short* __restrict__ featH2)
{
    const int i = threadIdx.x;   // 16*32 = 512 shorts... use 256 threads x2
    featH1[(size_t)EE*32 + i] = 0;
    featH1[(size_t)EE*32 + 256 + i] = 0;
    featH2[(size_t)EE*32 + i] = 0;
    featH2[(size_t)EE*32 + 256 + i] = 0;
}

// ---------------------------------------------------------------------------
// prep_wt: build WT[208][32] hi/lo for the edge projection.
// ---------------------------------------------------------------------------
__global__ __launch_bounds__(256) void prep_wt_kernel(
    const float* __restrict__ W_edge, const float* __restrict__ W_rbf,
    const float* __restrict__ b_rbf,
    short* __restrict__ WTH, short* __restrict__ WTL)
{
    const int idx = blockIdx.x*256 + threadIdx.x;
    if (idx >= 208*32) return;
    const int c = idx >> 5, k = idx & 31;
    float v = 0.f;
    if (c < 100) {
        if (k < 14) v = W_edge[k*100 + c];
    } else if (c < 200) {
        const int cc = c - 100;
        if (k >= 14 && k < 30) v = W_rbf[(k-14)*100 + cc];
        else if (k == 30) v = b_rbf[cc];
    }
    const short hi = f2bf(v);
    WTH[idx] = hi;
    WTL[idx] = f2bf(v - bf2f(hi));
}

// ---------------------------------------------------------------------------
// gather_mfma v7: v6 + DPP-based 16-lane stat reduction (replaces 8 chains
// of 4 dependent ds_swizzle shuffles per tile with pure-VALU dpp adds — no
// DS pipe, no address VGPRs, ~4x shorter reduce latency). Structure
// otherwise identical to v6 (141 us, no spill, VGPR 120 @ (256,2) cap 128).
// ---------------------------------------------------------------------------
__global__ __launch_bounds__(256, 2) void gather_mfma(
    const short* __restrict__ featH1, const short* __restrict__ featH2,
    const int* __restrict__ start1, const int* __restrict__ start2,
    const short* __restrict__ WTH, const short* __restrict__ WTL,
    const float* __restrict__ ln_g, const float* __restrict__ ln_b,
    float* __restrict__ h1, float* __restrict__ h2)
{
    __shared__ short sWH[208*40];    // 16.6 KB, stride-40 (80B) rows
    __shared__ short sWL[208*40];    // 16.6 KB
    __shared__ float plane[4][216];

    const int tid = threadIdx.x;
    const int wv = tid >> 6, lane = tid & 63;
    const int arow = lane & 15, aq = lane >> 4;

    // stage W once per block (832 short8 per array)
    for (int f = tid; f < 832; f += 256) {
        const int d = f >> 2, cc = (f & 3) * 8;
        *(short8*)&sWH[d*40 + cc] = *(const short8*)&WTH[f*8];
        *(short8*)&sWL[d*40 + cc] = *(const short8*)&WTL[f*8];
    }
    __syncthreads();

    const int side = blockIdx.y;
    const short* feat = side ? featH2 : featH1;
    const int*  start = side ? start2 : start1;
    float* h = side ? h2 : h1;

    const int c0 = blockIdx.x*16 + wv*4;     // wave's first node (of 4)

    // hoist ln params (lane-mapped)
    const float g0 = ln_g[lane],      bb0 = ln_b[lane];
    const float g1 = ln_g[64+lane],   bb1 = ln_b[64+lane];
    const float g2 = ln_g[128+lane],  bb2 = ln_b[128+lane];
    const float g3 = (lane < 8) ? ln_g[192+lane] : 0.f;
    const float bb3 = (lane < 8) ? ln_b[192+lane] : 0.f;

    // 5 start values for the 4 nodes, one load, then readlane
    const int sidx = (lane < 5) ? lane : 4;
    const int sv = start[c0 + sidx];

    const int lb = arow*40 + aq*8;           // LDS element offset in a W tile

    #pragma unroll 1
    for (int ni = 0; ni < 4; ni++) {
        const int st = __builtin_amdgcn_readlane(sv, ni);
        const int en = __builtin_amdgcn_readlane(sv, ni + 1);
        const int dg = en - st;
        const int node = c0 + ni;
        const size_t hbase = (size_t)node * DH;

        // hoist h RMW loads (consumed at node end, hidden under tiles)
        const float hv0 = h[hbase + lane];
        const float hv1 = h[hbase + 64 + lane];
        const float hv2 = h[hbase + 128 + lane];
        const float hv3 = (lane < 8) ? h[hbase + 192 + lane] : 0.f;

        float colacc[13];
        #pragma unroll
        for (int nt = 0; nt < 13; nt++) colacc[nt] = 0.f;
        float musum = 0.f;

        short8 aC = *(const short8*)&feat[(size_t)(st + arow)*32 + aq*8];

        for (int t0 = 0; t0 < dg; t0 += 16) {
            // prefetch next tile; overshoot lands in next node's rows or the
            // zeroed 16-row pad (start[BN]=EE sentinel) — discarded if unused
            const short8 aN = *(const short8*)&feat[(size_t)(st + t0 + 16 + arow)*32 + aq*8];

            f32x4 acc[13];
            #pragma unroll
            for (int nt = 0; nt < 13; nt++) {
                const short8 whv = *(const short8*)&sWH[nt*640 + lb];
                const short8 wlv = *(const short8*)&sWL[nt*640 + lb];
                f32x4 z = (f32x4){0.f,0.f,0.f,0.f};
                z = __builtin_amdgcn_mfma_f32_16x16x32_bf16(aC, whv, z, 0, 0, 0);
                z = __builtin_amdgcn_mfma_f32_16x16x32_bf16(aC, wlv, z, 0, 0, 0);
                acc[nt] = z;
            }
            // relu + per-row (per-edge) stats; row = t0 + aq*4 + r
            float sr[4] = {0.f,0.f,0.f,0.f}, s2r[4] = {0.f,0.f,0.f,0.f};
            #pragma unroll
            for (int nt = 0; nt < 13; nt++) {
                #pragma unroll
                for (int r = 0; r < 4; r++) {
                    const float v = fmaxf(acc[nt][r], 0.f);
                    acc[nt][r] = v;
                    sr[r] += v; s2r[r] += v*v;
                }
            }
            // 16-lane sum across arow via DPP (VALU-only)
            #pragma unroll
            for (int r = 0; r < 4; r++) {
                sr[r]  = dpp16_sum(sr[r]);
                s2r[r] = dpp16_sum(s2r[r]);
            }
            #pragma unroll
            for (int r = 0; r < 4; r++) {
                const bool valid = (t0 + aq*4 + r) < dg;
                const float mean = sr[r] * (1.0f/DH);
                const float var  = s2r[r] * (1.0f/DH) - mean*mean;
                const float rs   = rsqrtf(var + 1e-5f);
                const float rstd = valid ? rs : 0.f;
                musum += valid ? mean*rs : 0.f;
                #pragma unroll
                for (int nt = 0; nt < 13; nt++)
                    colacc[nt] += rstd*acc[nt][r];
            }
            aC = aN;
        }

        // reduce over the 4 aq groups (rows partition)
        #pragma unroll
        for (int nt = 0; nt < 13; nt++) {
            colacc[nt] += __shfl_xor(colacc[nt], 16, 64);
            colacc[nt] += __shfl_xor(colacc[nt], 32, 64);
        }
        musum += __shfl_xor(musum, 16, 64);
        musum += __shfl_xor(musum, 32, 64);

        if (aq == 0) {
            #pragma unroll
            for (int nt = 0; nt < 13; nt++)
                plane[wv][nt*16 + arow] = colacc[nt];
        }
        // wave-internal LDS producer/consumer: DS pipe is in-order per wave —
        // no barrier (and the next node's writes issue after these reads)

        const float dgf = (float)dg;
        h[hbase + lane]       = hv0 + g0*(plane[wv][lane]     - musum) + dgf*bb0;
        h[hbase + 64 + lane]  = hv1 + g1*(plane[wv][64+lane]  - musum) + dgf*bb1;
        h[hbase + 128 + lane] = hv2 + g2*(plane[wv][128+lane] - musum) + dgf*bb2;
        if (lane < 8)
            h[hbase + 192 + lane] = hv3 + g3*(plane[wv][192+lane] - musum) + dgf*bb3;
    }
}

// ---------------------------------------------------------------------------
// cvt (per half): h fp32 -> hb hi/lo [16384][224] rows + hbT hi/lo [32][224][512]
// ---------------------------------------------------------------------------
__global__ __launch_bounds__(256) void cvt_kernel(
    const float* __restrict__ h1, const float* __restrict__ h2, const int half,
    short* __restrict__ hbH1, short* __restrict__ hbL1,
    short* __restrict__ hbH2, short* __restrict__ hbL2,
    short* __restrict__ hTH1, short* __restrict__ hTL1,
    short* __restrict__ hTH2, short* __restrict__ hTL2)
{
    const int side = blockIdx.y;
    const float* h = side ? h2 : h1;
    short* hbH = side ? hbH2 : hbH1;
    short* hbL = side ? hbL2 : hbL1;
    short* hTH = side ? hTH2 : hTH1;
    short* hTL = side ? hTL2 : hTL1;

    const int nl0 = blockIdx.x * 64;          // local node
    const int bl = nl0 >> 9, m0 = nl0 & 511;
    const int ng0 = half*HBN + nl0;

    __shared__ short tH[64][226];
    __shared__ short tL[64][226];
    const int tid = threadIdx.x;
    for (int i = tid; i < 64*224; i += 256) {
        const int r = i / 224, c = i - r*224;
        const float v = (c < DH) ? h[(size_t)(ng0+r)*DH + c] : 0.f;
        const short hi = f2bf(v);
        const short lo = f2bf(v - bf2f(hi));
        tH[r][c] = hi; tL[r][c] = lo;
        hbH[(size_t)(nl0+r)*224 + c] = hi;
        hbL[(size_t)(nl0+r)*224 + c] = lo;
    }
    __syncthreads();
    for (int i = tid; i < 224*64; i += 256) {
        const int c = i >> 6, m = i & 63;
        const size_t o = ((size_t)bl*224 + c)*NN + m0 + m;
        hTH[o] = tH[m][c];
        hTL[o] = tL[m][c];
    }
}

// ---------------------------------------------------------------------------
// prep_w: W_down[400][200] -> WbTHI/LO[208][448] (transposed, padded, split)
// ---------------------------------------------------------------------------
__global__ __launch_bounds__(256) void prep_w_kernel(
    const float* __restrict__ W_down,
    short* __restrict__ WbTHI, short* __restrict__ WbTLO)
{
    const int idx = blockIdx.x*256 + threadIdx.x;
    if (idx >= 208*448) return;
    const int c = idx / 448, kk = idx - c*448;
    float v = 0.f;
    if (c < 200) {
        if (kk < 200) v = W_down[(size_t)kk*DH + c];
        else if (kk >= 224 && kk < 424) v = W_down[(size_t)(200 + kk - 224)*DH + c];
    }
    const short hi = f2bf(v);
    WbTHI[idx] = hi;
    WbTLO[idx] = f2bf(v - bf2f(hi));
}

// ---------------------------------------------------------------------------
// Fused attention v5: 16 Q-rows per block, 4 waves split 32 key-tiles.
// KEY CHANGE vs v4: the 56-VGPR Q-fragment array is gone. Q (same 16 rows
// for all 4 waves) is staged ONCE per block into LDS (padded stride 232 ->
// balanced banks), and the QK loop is interchanged to k-outer/t-inner so
// only one (qh,ql) pair is live (8 VGPRs). v4 declared (256,4) = empirical
// VGPR cap 64 with ~105 live -> scratch spill (same mechanism as gather r2).
// Peak live now ~60; (256,3) caps at 85 -> headroom for K prefetch.
// Numerics bit-identical: per acc[t], k still ascends with hh/hl/lh order.
// LDS 32KB -> 5 blocks/CU.
// ---------------------------------------------------------------------------
__global__ __launch_bounds__(256, 3) void attn_kernel(
    const short* __restrict__ QH, const short* __restrict__ QL,
    const short* __restrict__ KH, const short* __restrict__ KL,
    const short* __restrict__ VTH, const short* __restrict__ VTL,
    short* __restrict__ cb)
{
    const int id = blockIdx.x + (blockIdx.y << 5);   // gridDim.x == 32
    const int j  = id >> 3;
    const int b  = (id & 7)*4 + (j >> 5);            // half-local batch
    const int q0 = (j & 31) << 4;
    const short* Qh = QH + (size_t)b*NN*224;
    const short* Ql = QL + (size_t)b*NN*224;
    const short* Kh = KH + (size_t)b*NN*224;
    const short* Kl = KL + (size_t)b*NN*224;
    const short* Vh = VTH + (size_t)b*224*NN;
    const short* Vl = VTL + (size_t)b*224*NN;

    __shared__ short sQh[16*232];             // 7.4 KB, stride-232 rows
    __shared__ short sQl[16*232];             // 7.4 KB
    __shared__ short pb[16*520];              // 16.3 KB P bf16
    __shared__ float sm_[4][16];
    __shared__ float ss_[4][16];

    const int tid = threadIdx.x;
    const int wv = tid >> 6, lane = tid & 63;
    const int arow = lane & 15, aq = lane >> 4;

    // stage Q (16 rows x 224, hi/lo) cooperatively — was loaded 4x per block
    for (int i = tid; i < 448; i += 256) {
        const int r = i / 28, c = (i - r*28) * 8;
        *(short8*)&sQh[r*232 + c] = *(const short8*)&Qh[(size_t)(q0 + r)*224 + c];
        *(short8*)&sQl[r*232 + c] = *(const short8*)&Ql[(size_t)(q0 + r)*224 + c];
    }
    __syncthreads();

    f32x4 acc[8];
    #pragma unroll
    for (int t = 0; t < 8; t++) acc[t] = (f32x4){0.f,0.f,0.f,0.f};

    const int qb = arow*232 + aq*8;
    #pragma unroll 1
    for (int k = 0; k < 7; k++) {
        const short8 qh = *(const short8*)&sQh[qb + k*32];
        const short8 ql = *(const short8*)&sQl[qb + k*32];
        #pragma unroll
        for (int t = 0; t < 8; t++) {
            const size_t kb = (size_t)((wv*8 + t)*16 + arow)*224 + k*32 + aq*8;
            const short8 bh = *(const short8*)&Kh[kb];
            const short8 bl = *(const short8*)&Kl[kb];
            acc[t] = __builtin_amdgcn_mfma_f32_16x16x32_bf16(qh, bh, acc[t], 0, 0, 0);
            acc[t] = __builtin_amdgcn_mfma_f32_16x16x32_bf16(qh, bl, acc[t], 0, 0, 0);
            acc[t] = __builtin_amdgcn_mfma_f32_16x16x32_bf16(ql, bh, acc[t], 0, 0, 0);
        }
    }

    float mr[4], sr[4], iv[4];
    #pragma unroll
    for (int r = 0; r < 4; r++) {
        float m = -1e30f;
        #pragma unroll
        for (int t = 0; t < 8; t++) {
            acc[t][r] *= T_SCALE;
            m = fmaxf(m, acc[t][r]);
        }
        m = fmaxf(m, __shfl_xor(m, 1, 64));
        m = fmaxf(m, __shfl_xor(m, 2, 64));
        m = fmaxf(m, __shfl_xor(m, 4, 64));
        m = fmaxf(m, __shfl_xor(m, 8, 64));
        mr[r] = m;
    }
    if (arow == 0) {
        #pragma unroll
        for (int r = 0; r < 4; r++) sm_[wv][aq*4+r] = mr[r];
    }
    __syncthreads();
    #pragma unroll
    for (int r = 0; r < 4; r++) {
        const int row = aq*4 + r;
        const float M = fmaxf(fmaxf(sm_[0][row], sm_[1][row]),
                              fmaxf(sm_[2][row], sm_[3][row]));
        float s = 0.f;
        #pragma unroll
        for (int t = 0; t < 8; t++) {
            const float e = __expf(acc[t][r] - M);
            acc[t][r] = e;
            s += e;
        }
        s += __shfl_xor(s, 1, 64);
        s += __shfl_xor(s, 2, 64);
        s += __shfl_xor(s, 4, 64);
        s += __shfl_xor(s, 8, 64);
        sr[r] = s;
    }
    if (arow == 0) {
        #pragma unroll
        for (int r = 0; r < 4; r++) ss_[wv][aq*4+r] = sr[r];
    }
    __syncthreads();
    #pragma unroll
    for (int r = 0; r < 4; r++) {
        const int row = aq*4 + r;
        iv[r] = 1.0f / (ss_[0][row] + ss_[1][row] + ss_[2][row] + ss_[3][row]);
    }

    #pragma unroll
    for (int t = 0; t < 8; t++) {
        const int col = (wv*8 + t)*16 + arow;
        #pragma unroll
        for (int r = 0; r < 4; r++)
            pb[(aq*4 + r)*520 + col] = f2bf(acc[t][r] * iv[r]);
    }
    __syncthreads();

    const int nbase = (wv == 0) ? 0 : 3*wv + 1;
    const int ncnt  = (wv == 0) ? 4 : 3;
    f32x4 pacc[4];
    #pragma unroll
    for (int t = 0; t < 4; t++) pacc[t] = (f32x4){0.f,0.f,0.f,0.f};

    for (int k0 = 0; k0 < NN; k0 += 32) {
        const short8 a = *(const short8*)&pb[arow*520 + k0 + aq*8];
        #pragma unroll
        for (int t = 0; t < 4; t++) {
            if (t < ncnt) {
                const size_t vb = (size_t)((nbase+t)*16 + arow)*NN + k0 + aq*8;
                const short8 bh = *(const short8*)&Vh[vb];
                const short8 bl = *(const short8*)&Vl[vb];
                pacc[t] = __builtin_amdgcn_mfma_f32_16x16x32_bf16(a, bh, pacc[t], 0, 0, 0);
                pacc[t] = __builtin_amdgcn_mfma_f32_16x16x32_bf16(a, bl, pacc[t], 0, 0, 0);
            }
        }
    }

    #pragma unroll
    for (int t = 0; t < 4; t++) {
        if (t < ncnt) {
            const int col = (nbase+t)*16 + arow;
            #pragma unroll
            for (int r = 0; r < 4; r++) {
                const int row = q0 + aq*4 + r;
                const short v = (col < DH) ? f2bf(pacc[t][r]) : (short)0;
                cb[((size_t)b*NN + row)*224 + col] = v;
            }
        }
    }
    if (wv == 3) {
        const int col = 208 + arow;
        #pragma unroll
        for (int r = 0; r < 4; r++) {
            const int row = q0 + aq*4 + r;
            cb[((size_t)b*NN + row)*224 + col] = 0;
        }
    }
}

// ---------------------------------------------------------------------------
// down (per half, MFMA, split-W): relu([hb|cb] @ W_down) + degree_table -> hsg
// ---------------------------------------------------------------------------
__global__ __launch_bounds__(256) void down_mfma(
    const short* __restrict__ hbH1, const short* __restrict__ hbH2,
    const short* __restrict__ cb1, const short* __restrict__ cb2,
    const int* __restrict__ deg1, const int* __restrict__ deg2,
    const short* __restrict__ WbTH, const short* __restrict__ WbTL,
    const float* __restrict__ degree_table,
    float* __restrict__ hsg1, float* __restrict__ hsg2, const int half)
{
    const int side = blockIdx.y;
    const short* X0 = side ? hbH2 : hbH1;
    const short* X1 = side ? cb2 : cb1;
    const int*   dgp = side ? deg2 : deg1;
    float* hsg = side ? hsg2 : hsg1;

    const int nl0 = blockIdx.x * 64;
    const int ng0 = half*HBN + nl0;
    const int b = ng0 >> 9;

    __shared__ short As[64*40];
    __shared__ short BsH[208*40];
    __shared__ short BsL[208*40];
    __shared__ float part[208];

    const int tid = threadIdx.x;
    const int wv = tid >> 6, lane = tid & 63;
    const int arow = lane & 15, aq = lane >> 4;

    if (tid < 208) part[tid] = 0.f;

    f32x4 acc[13];
    #pragma unroll
    for (int t = 0; t < 13; t++) acc[t] = (f32x4){0.f,0.f,0.f,0.f};

    const int sr = tid >> 2, sc = (tid & 3) * 8;

    for (int phase = 0; phase < 2; phase++) {
        const short* X = phase ? X1 : X0;
        for (int k0 = 0; k0 < 224; k0 += 32) {
            __syncthreads();
            *(short8*)&As[sr*40 + sc] =
                *(const short8*)&X[(size_t)(nl0+sr)*224 + k0 + sc];
            const int kkg = phase*224 + k0;
            #pragma unroll
            for (int pass = 0; pass < 4; pass++) {
                const int f = pass*256 + tid;
                if (f < 832) {
                    const int d = f >> 2, cc = (f & 3) * 8;
                    *(short8*)&BsH[d*40 + cc] = *(const short8*)&WbTH[(size_t)d*448 + kkg + cc];
                    *(short8*)&BsL[d*40 + cc] = *(const short8*)&WbTL[(size_t)d*448 + kkg + cc];
                }
            }
            __syncthreads();
            const short8 a = *(const short8*)&As[(16*wv + arow)*40 + aq*8];
            #pragma unroll
            for (int t = 0; t < 13; t++) {
                const short8 bh = *(const short8*)&BsH[(t*16 + arow)*40 + aq*8];
                const short8 bl = *(const short8*)&BsL[(t*16 + arow)*40 + aq*8];
                acc[t] = __builtin_amdgcn_mfma_f32_16x16x32_bf16(a, bh, acc[t], 0, 0, 0);
                acc[t] = __builtin_amdgcn_mfma_f32_16x16x32_bf16(a, bl, acc[t], 0, 0, 0);
            }
        }
    }
    __syncthreads();

    int dgc[4];
    #pragma unroll
    for (int r = 0; r < 4; r++) {
        int d = dgp[ng0 + 16*wv + aq*4 + r];
        dgc[r] = d > 199 ? 199 : d;
    }
    #pragma unroll
    for (int nt = 0; nt < 13; nt++) {
        const int col = nt*16 + arow;
        float s = 0.f;
        if (col < DH) {
            #pragma unroll
            for (int r = 0; r < 4; r++)
                s += fmaxf(acc[nt][r], 0.f) + degree_table[dgc[r]*DH + col];
        }
        s += __shfl_xor(s, 16, 64);
        s += __shfl_xor(s, 32, 64);
        if (lane < 16 && col < DH) atomicAdd(&part[col], s);
    }
    __syncthreads();
    if (tid < DH) unsafeAtomicAdd(&hsg[b*206 + tid], part[tid] * (1.0f/512.0f));
}

// ---------------------------------------------------------------------------
// Kernel 6: interaction mean over nodes -> hsg cols 200..205
// ---------------------------------------------------------------------------
__global__ __launch_bounds__(192) void inter_kernel(
    const float* __restrict__ i1, const float* __restrict__ i2,
    float* __restrict__ hsg1, float* __restrict__ hsg2)
{
    const int side = blockIdx.y;
    const float* it = side ? i2 : i1;
    float* hsg = side ? hsg2 : hsg1;
    const int b = blockIdx.x;
    __shared__ float red[192];
    const int tid = threadIdx.x;
    const int j = tid % 6, seg = tid / 6;
    float s = 0.0f;
    for (int n = seg*16; n < seg*16 + 16; n++)
        s += it[(size_t)b*NN*DI + n*DI + j];
    red[tid] = s;
    __syncthreads();
    if (tid < 6) {
        float tot = 0.0f;
        for (int sg2 = 0; sg2 < 32; sg2++) tot += red[sg2*6 + tid];
        hsg[b*206 + 200 + tid] = tot * (1.0f/512.0f);
    }
}

// ---------------------------------------------------------------------------
// Kernel 7: final MLP, one block per batch row
// ---------------------------------------------------------------------------
__global__ __launch_bounds__(256) void mlp_kernel(
    const float* __restrict__ hsg1, const float* __restrict__ hsg2,
    const float* __restrict__ W_f1, const float* __restrict__ b_f1,
    const float* __restrict__ W_f2, const float* __restrict__ b_f2,
    const float* __restrict__ W_f3, const float* __restrict__ b_f3,
    const float* __restrict__ W_f4, const float* __restrict__ b_f4,
    float* __restrict__ out)
{
    const int b = blockIdx.x;
    __shared__ float x[618];
    __shared__ float y1[400];
    __shared__ float y2[200];
    __shared__ float y3[100];
    __shared__ float red[256];
    const int tid = threadIdx.x;

    if (tid < 206) {
        const float a = hsg1[b*206 + tid], bb = hsg2[b*206 + tid];
        x[tid] = a; x[206 + tid] = bb; x[412 + tid] = a - bb;
    }
    __syncthreads();
    for (int c = tid; c < 400; c += 256) {
        float acc = b_f1[c];
        for (int k = 0; k < 618; k++) acc += x[k]*W_f1[(size_t)k*400 + c];
        y1[c] = fmaxf(acc, 0.0f);
    }
    __syncthreads();
    if (tid < 200) {
        float acc = b_f2[tid];
        for (int k = 0; k < 400; k++) acc += y1[k]*W_f2[k*200 + tid];
        y2[tid] = fmaxf(acc, 0.0f);
    }
    __syncthreads();
    if (tid < 100) {
        float acc = b_f3[tid];
        for (int k = 0; k < 200; k++) acc += y2[k]*W_f3[k*100 + tid];
        y3[tid] = fmaxf(acc, 0.0f);
    }
    __syncthreads();
    red[tid] = (tid < 100) ? y3[tid]*W_f4[tid] : 0.0f;
    __syncthreads();
    for (int s = 128; s > 0; s >>= 1) {
        if (tid < s) red[tid] += red[tid + s];
        __syncthreads();
    }
    if (tid == 0) out[b] = red[0] + b_f4[0];
}

// ---------------------------------------------------------------------------
extern "C" void kernel_launch(void* const* d_in, const int* in_sizes, int n_in,
                              void* d_out, int out_size, void* d_ws, size_t ws_size,
                              hipStream_t stream)
{
    const float* atom1  = (const float*)d_in[0];
    const float* atom2  = (const float*)d_in[1];
    const float* coords1= (const float*)d_in[2];
    const float* coords2= (const float*)d_in[3];
    const float* efeat1 = (const float*)d_in[4];
    const float* efeat2 = (const float*)d_in[5];
    const float* inter1 = (const float*)d_in[6];
    const float* inter2 = (const float*)d_in[7];
    const int*   esrc1  = (const int*)d_in[8];
    const int*   edst1  = (const int*)d_in[9];
    const int*   esrc2  = (const int*)d_in[10];
    const int*   edst2  = (const int*)d_in[11];
    const float* W_atom = (const float*)d_in[12];
    const float* W_edge = (const float*)d_in[13];
    const float* W_rbf  = (const float*)d_in[14];
    const float* b_rbf  = (const float*)d_in[15];
    const float* ln_g   = (const float*)d_in[16];
    const float* ln_b   = (const float*)d_in[17];
    const float* W_down = (const float*)d_in[18];
    const float* deg_tab= (const float*)d_in[19];
    const float* W_f1   = (const float*)d_in[20];
    const float* b_f1   = (const float*)d_in[21];
    const float* W_f2   = (const float*)d_in[22];
    const float* b_f2   = (const float*)d_in[23];
    const float* W_f3   = (const float*)d_in[24];
    const float* b_f3   = (const float*)d_in[25];
    const float* W_f4   = (const float*)d_in[26];
    const float* b_f4   = (const float*)d_in[27];
    float* out = (float*)d_out;

    // ---- workspace layout (~133 MB)
    float* ws = (float*)d_ws;
    const size_t HSZ = (size_t)BN*DH;              // per-side h floats
    float* h1  = ws;
    float* h2  = h1 + HSZ;
    // pool: max(feat 2*(EE+16)*32 shorts, bf16 pool 10*HB shorts)
    short* pool = (short*)(h2 + HSZ);
    const size_t FSZ = (size_t)(EE+16)*32;
    short* featH1 = pool;
    short* featH2 = featH1 + FSZ;
    const size_t HB = (size_t)32*NN*224;           // 3,670,016 shorts
    short* hbH1 = pool;           short* hbL1 = hbH1 + HB;
    short* hbH2 = hbL1 + HB;      short* hbL2 = hbH2 + HB;
    short* hTH1 = hbL2 + HB;      short* hTL1 = hTH1 + HB;
    short* hTH2 = hTL1 + HB;      short* hTL2 = hTH2 + HB;
    short* cb1  = hTL2 + HB;      short* cb2  = cb1 + HB;
    size_t pool_sz = 2*FSZ > 10*HB ? 2*FSZ : 10*HB;
    short* after = pool + pool_sz;
    short* WTH = after;                            // [208][32]
    short* WTL = WTH + 208*32;
    short* WbTH = WTL + 208*32;                    // [208][448]
    short* WbTL = WbTH + 208*448;
    float* hsg1 = (float*)(WbTL + 208*448);
    float* hsg2 = hsg1 + (size_t)BB*206;
    int* deg1 = (int*)(hsg2 + (size_t)BB*206);
    int* deg2 = deg1 + BN;
    int* start1 = deg2 + BN;                       // BN+1 entries
    int* start2 = start1 + (BN+1);
    int* cursor1 = start2 + (BN+1);
    int* cursor2 = cursor1 + BN;
    int* rank1 = cursor2 + BN;
    int* rank2 = rank1 + EE;

    hipMemsetAsync(deg1, 0, 2*(size_t)BN*sizeof(int), stream);
    hipMemsetAsync(hsg1, 0, 2*(size_t)BB*206*sizeof(float), stream);

    node_kernel<<<dim3(BN/4, 2), 256, 0, stream>>>(
        atom1, atom2, W_atom, ln_g, ln_b, h1, h2);

    hist_kernel<<<EE/256, 256, 0, stream>>>(edst1, edst2, deg1, deg2);
    scan_kernel<<<2, 1024, 0, stream>>>(deg1, deg2, start1, start2, cursor1, cursor2);
    scatter_kernel<<<EE/256, 256, 0, stream>>>(edst1, edst2, cursor1, cursor2,
                                               rank1, rank2);

    featgen_kernel<<<dim3(EE/256, 2), 256, 0, stream>>>(
        efeat1, efeat2, esrc1, esrc2, edst1, edst2, coords1, coords2,
        rank1, rank2, featH1, featH2);
    featpad_kernel<<<1, 256, 0, stream>>>(featH1, featH2);

    prep_wt_kernel<<<(208*32 + 255)/256, 256, 0, stream>>>(
        W_edge, W_rbf, b_rbf, WTH, WTL);

    gather_mfma<<<dim3(BN/16, 2), 256, 0, stream>>>(
        featH1, featH2, start1, start2, WTH, WTL, ln_g, ln_b, h1, h2);

    prep_w_kernel<<<(208*448 + 255)/256, 256, 0, stream>>>(W_down, WbTH, WbTL);

    for (int half = 0; half < 2; half++) {
        cvt_kernel<<<dim3(HBN/64, 2), 256, 0, stream>>>(
            h1, h2, half, hbH1, hbL1, hbH2, hbL2, hTH1, hTL1, hTH2, hTL2);
        // dir0: c1 = softmax_rows(h1@h2^T) @ h2
        attn_kernel<<<dim3(NN/16, 32), 256, 0, stream>>>(
            hbH1, hbL1, hbH2, hbL2, hTH2, hTL2, cb1);
        // dir1: c2 = softmax_rows(h2@h1^T) @ h1
        attn_kernel<<<dim3(NN/16, 32), 256, 0, stream>>>(
            hbH2, hbL2, hbH1, hbL1, hTH1, hTL1, cb2);
        down_mfma<<<dim3(HBN/64, 2), 256, 0, stream>>>(
            hbH1, hbH2, cb1, cb2, deg1, deg2, WbTH, WbTL, deg_tab,
            hsg1, hsg2, half);
    }

    inter_kernel<<<dim3(BB, 2), 192, 0, stream>>>(inter1, inter2, hsg1, hsg2);

    mlp_kernel<<<BB, 256, 0, stream>>>(
        hsg1, hsg2, W_f1, b_f1, W_f2, b_f2, W_f3, b_f3, W_f4, b_f4, out);
}

// Round 6
// 976.279 us; speedup vs baseline: 1.3969x; 1.1331x over previous
//
#include <hip/hip_runtime.h>
#include <cstddef>
#include <cstdint>

// Problem constants
#define BB   64
#define NN   512
#define BN   (BB*NN)          // 32768
#define HBN  16384            // nodes per half
#define EE   524288
#define DA   70
#define DE   14
#define DH   200
#define DI   6
#define T_SCALE 0.07071067811865475f   // sqrt(1/200)

typedef __attribute__((ext_vector_type(8))) short short8;
typedef __attribute__((ext_vector_type(4))) float f32x4;

__device__ __forceinline__ short f2bf(float x) {
    union { float f; unsigned u; } v; v.f = x;
    const unsigned r = v.u + 0x7FFFu + ((v.u >> 16) & 1u);   // RNE
    return (short)(r >> 16);
}
__device__ __forceinline__ float bf2f(short s) {
    union { unsigned u; float f; } v;
    v.u = ((unsigned)(unsigned short)s) << 16;
    return v.f;
}

// 16-lane (row) sum via DPP — pure VALU, no DS pipe, no address VGPRs.
__device__ __forceinline__ float dpp16_sum(float x) {
    union { float f; int i; } a, b;
    a.f = x;
    b.i = __builtin_amdgcn_update_dpp(0, a.i, 0xB1, 0xF, 0xF, false); a.f += b.f;
    b.i = __builtin_amdgcn_update_dpp(0, a.i, 0x4E, 0xF, 0xF, false); a.f += b.f;
    b.i = __builtin_amdgcn_update_dpp(0, a.i, 0x141, 0xF, 0xF, false); a.f += b.f;
    b.i = __builtin_amdgcn_update_dpp(0, a.i, 0x140, 0xF, 0xF, false); a.f += b.f;
    return a.f;
}

// ---------------------------------------------------------------------------
// Kernel 1: per-node  h = layernorm(relu(atom @ W_atom))
// ---------------------------------------------------------------------------
__global__ __launch_bounds__(256) void node_kernel(
    const float* __restrict__ atom1, const float* __restrict__ atom2,
    const float* __restrict__ W_atom,
    const float* __restrict__ ln_g, const float* __restrict__ ln_b,
    float* __restrict__ h1, float* __restrict__ h2)
{
    const int side = blockIdx.y;
    const float* atom = side ? atom2 : atom1;
    float* h = side ? h2 : h1;
    const int node0 = blockIdx.x * 4;
    const int tid = threadIdx.x;

    __shared__ float arow[4][DA];
    __shared__ float vals[4][DH];

    for (int i = tid; i < 4*DA; i += 256) {
        const int n = i / DA, k = i % DA;
        arow[n][k] = atom[(size_t)(node0+n)*DA + k];
    }
    __syncthreads();

    if (tid < DH) {
        float a0 = 0.f, a1 = 0.f, a2 = 0.f, a3 = 0.f;
        #pragma unroll 7
        for (int k = 0; k < DA; k++) {
            const float w = W_atom[k*DH + tid];
            a0 += arow[0][k]*w; a1 += arow[1][k]*w;
            a2 += arow[2][k]*w; a3 += arow[3][k]*w;
        }
        vals[0][tid] = fmaxf(a0, 0.f);
        vals[1][tid] = fmaxf(a1, 0.f);
        vals[2][tid] = fmaxf(a2, 0.f);
        vals[3][tid] = fmaxf(a3, 0.f);
    }
    __syncthreads();

    const int wv = tid >> 6, lane = tid & 63;
    float v0 = vals[wv][lane];
    float v1 = vals[wv][64+lane];
    float v2 = vals[wv][128+lane];
    float v3 = (lane < 8) ? vals[wv][192+lane] : 0.0f;
    float s  = v0+v1+v2+v3;
    float s2 = v0*v0+v1*v1+v2*v2+v3*v3;
    #pragma unroll
    for (int off = 1; off < 64; off <<= 1) {
        s  += __shfl_xor(s,  off, 64);
        s2 += __shfl_xor(s2, off, 64);
    }
    const float mean = s * (1.0f/DH);
    const float var  = s2 * (1.0f/DH) - mean*mean;
    const float rstd = rsqrtf(var + 1e-5f);
    const size_t base = (size_t)(node0+wv)*DH;
    h[base + lane]       = ln_g[lane]     *(v0-mean)*rstd + ln_b[lane];
    h[base + 64 + lane]  = ln_g[64+lane]  *(v1-mean)*rstd + ln_b[64+lane];
    h[base + 128 + lane] = ln_g[128+lane] *(v2-mean)*rstd + ln_b[128+lane];
    if (lane < 8)
        h[base + 192 + lane] = ln_g[192+lane]*(v3-mean)*rstd + ln_b[192+lane];
}

// ---------------------------------------------------------------------------
// Counting sort by dst: hist -> scan(+sentinel) -> scatter (rank only)
// ---------------------------------------------------------------------------
__global__ __launch_bounds__(256) void hist_kernel(
    const int* __restrict__ edst1, const int* __restrict__ edst2,
    int* __restrict__ deg1, int* __restrict__ deg2)
{
    const int e = blockIdx.x*256 + threadIdx.x;
    atomicAdd(&deg1[edst1[e]], 1);
    atomicAdd(&deg2[edst2[e]], 1);
}

__global__ __launch_bounds__(1024) void scan_kernel(
    const int* __restrict__ deg1, const int* __restrict__ deg2,
    int* __restrict__ start1, int* __restrict__ start2,
    int* __restrict__ cursor1, int* __restrict__ cursor2)
{
    const int side = blockIdx.x;
    const int* deg   = side ? deg2 : deg1;
    int* start  = side ? start2 : start1;
    int* cursor = side ? cursor2 : cursor1;

    __shared__ int part[1024];
    const int t = threadIdx.x;
    const int base = t * 32;
    int local[32];
    int sum = 0;
    #pragma unroll
    for (int i = 0; i < 32; i++) { local[i] = deg[base+i]; sum += local[i]; }
    part[t] = sum;
    __syncthreads();
    for (int off = 1; off < 1024; off <<= 1) {
        int v = (t >= off) ? part[t-off] : 0;
        __syncthreads();
        part[t] += v;
        __syncthreads();
    }
    int run = part[t] - sum;   // exclusive
    #pragma unroll
    for (int i = 0; i < 32; i++) {
        start[base+i] = run;
        cursor[base+i] = run;
        run += local[i];
    }
    if (t == 1023) start[BN] = run;   // sentinel == EE
}

__global__ __launch_bounds__(256) void scatter_kernel(
    const int* __restrict__ edst1, const int* __restrict__ edst2,
    int* __restrict__ cursor1, int* __restrict__ cursor2,
    int* __restrict__ rank1, int* __restrict__ rank2)
{
    const int e = blockIdx.x*256 + threadIdx.x;
    {
        const int d = edst1[e];
        rank1[e] = atomicAdd(&cursor1[d], 1);
    }
    {
        const int d = edst2[e];
        rank2[e] = atomicAdd(&cursor2[d], 1);
    }
}

// ---------------------------------------------------------------------------
// featgen: per-edge feature row (rank-ordered) -> featH[rank][32] bf16
//   k 0..13 = ef, 14..29 = rbf, 30 = 1.0 (bias hook), 31 = 0
// ---------------------------------------------------------------------------
__global__ __launch_bounds__(256) void featgen_kernel(
    const float* __restrict__ efeat1, const float* __restrict__ efeat2,
    const int* __restrict__ esrc1, const int* __restrict__ esrc2,
    const int* __restrict__ edst1, const int* __restrict__ edst2,
    const float* __restrict__ coords1, const float* __restrict__ coords2,
    const int* __restrict__ rank1, const int* __restrict__ rank2,
    short* __restrict__ featH1, short* __restrict__ featH2)
{
    const int side = blockIdx.y;
    const float* ef     = side ? efeat2  : efeat1;
    const int*   esrc   = side ? esrc2   : esrc1;
    const int*   edst   = side ? edst2   : edst1;
    const float* coords = side ? coords2 : coords1;
    const int*   rank   = side ? rank2   : rank1;
    short* featH = side ? featH2 : featH1;

    const int e = blockIdx.x*256 + threadIdx.x;
    const int src = esrc[e], dst = edst[e];

    short f[32];
    #pragma unroll
    for (int k = 0; k < 14; k++) f[k] = f2bf(ef[(size_t)e*DE + k]);

    const float dx = coords[src*3+0] - coords[dst*3+0];
    const float dy = coords[src*3+1] - coords[dst*3+1];
    const float dz = coords[src*3+2] - coords[dst*3+2];
    const float dist = sqrtf(dx*dx + dy*dy + dz*dz + 1e-12f);
    #pragma unroll
    for (int k = 0; k < 16; k++) {
        const float t = 3.2f*dist - 1.0666666667f*(float)k;
        f[14+k] = f2bf(__expf(-t*t));
    }
    f[30] = f2bf(1.0f);
    f[31] = 0;

    short* out = featH + (size_t)rank[e]*32;
    #pragma unroll
    for (int q = 0; q < 4; q++)
        *(short8*)&out[q*8] = *(short8*)&f[q*8];
}

// ---------------------------------------------------------------------------
// featpad: zero the 16-row pad past EE so tail tiles read finite zeros
// ---------------------------------------------------------------------------
__global__ __launch_bounds__(256) void featpad_kernel(
    short* __restrict__ featH1, short* __restrict__ featH2)
{
    const int i = threadIdx.x;   // 16*32 = 512 shorts... use 256 threads x2
    featH1[(size_t)EE*32 + i] = 0;
    featH1[(size_t)EE*32 + 256 + i] = 0;
    featH2[(size_t)EE*32 + i] = 0;
    featH2[(size_t)EE*32 + 256 + i] = 0;
}

// ---------------------------------------------------------------------------
// prep_wt: build WT[208][32] hi/lo for the edge projection.
// ---------------------------------------------------------------------------
__global__ __launch_bounds__(256) void prep_wt_kernel(
    const float* __restrict__ W_edge, const float* __restrict__ W_rbf,
    const float* __restrict__ b_rbf,
    short* __restrict__ WTH, short* __restrict__ WTL)
{
    const int idx = blockIdx.x*256 + threadIdx.x;
    if (idx >= 208*32) return;
    const int c = idx >> 5, k = idx & 31;
    float v = 0.f;
    if (c < 100) {
        if (k < 14) v = W_edge[k*100 + c];
    } else if (c < 200) {
        const int cc = c - 100;
        if (k >= 14 && k < 30) v = W_rbf[(k-14)*100 + cc];
        else if (k == 30) v = b_rbf[cc];
    }
    const short hi = f2bf(v);
    WTH[idx] = hi;
    WTL[idx] = f2bf(v - bf2f(hi));
}

// ---------------------------------------------------------------------------
// gather_mfma v7 (unchanged from round 5): 132 us, VALU-dominated (53%),
// VALU:MFMA = 4.3:1 matches static op count — structural floor for this
// formulation. VGPR 112 @ (256,2) cap 128, no spill.
// ---------------------------------------------------------------------------
__global__ __launch_bounds__(256, 2) void gather_mfma(
    const short* __restrict__ featH1, const short* __restrict__ featH2,
    const int* __restrict__ start1, const int* __restrict__ start2,
    const short* __restrict__ WTH, const short* __restrict__ WTL,
    const float* __restrict__ ln_g, const float* __restrict__ ln_b,
    float* __restrict__ h1, float* __restrict__ h2)
{
    __shared__ short sWH[208*40];    // 16.6 KB, stride-40 (80B) rows
    __shared__ short sWL[208*40];    // 16.6 KB
    __shared__ float plane[4][216];

    const int tid = threadIdx.x;
    const int wv = tid >> 6, lane = tid & 63;
    const int arow = lane & 15, aq = lane >> 4;

    // stage W once per block (832 short8 per array)
    for (int f = tid; f < 832; f += 256) {
        const int d = f >> 2, cc = (f & 3) * 8;
        *(short8*)&sWH[d*40 + cc] = *(const short8*)&WTH[f*8];
        *(short8*)&sWL[d*40 + cc] = *(const short8*)&WTL[f*8];
    }
    __syncthreads();

    const int side = blockIdx.y;
    const short* feat = side ? featH2 : featH1;
    const int*  start = side ? start2 : start1;
    float* h = side ? h2 : h1;

    const int c0 = blockIdx.x*16 + wv*4;     // wave's first node (of 4)

    // hoist ln params (lane-mapped)
    const float g0 = ln_g[lane],      bb0 = ln_b[lane];
    const float g1 = ln_g[64+lane],   bb1 = ln_b[64+lane];
    const float g2 = ln_g[128+lane],  bb2 = ln_b[128+lane];
    const float g3 = (lane < 8) ? ln_g[192+lane] : 0.f;
    const float bb3 = (lane < 8) ? ln_b[192+lane] : 0.f;

    // 5 start values for the 4 nodes, one load, then readlane
    const int sidx = (lane < 5) ? lane : 4;
    const int sv = start[c0 + sidx];

    const int lb = arow*40 + aq*8;           // LDS element offset in a W tile

    #pragma unroll 1
    for (int ni = 0; ni < 4; ni++) {
        const int st = __builtin_amdgcn_readlane(sv, ni);
        const int en = __builtin_amdgcn_readlane(sv, ni + 1);
        const int dg = en - st;
        const int node = c0 + ni;
        const size_t hbase = (size_t)node * DH;

        // hoist h RMW loads (consumed at node end, hidden under tiles)
        const float hv0 = h[hbase + lane];
        const float hv1 = h[hbase + 64 + lane];
        const float hv2 = h[hbase + 128 + lane];
        const float hv3 = (lane < 8) ? h[hbase + 192 + lane] : 0.f;

        float colacc[13];
        #pragma unroll
        for (int nt = 0; nt < 13; nt++) colacc[nt] = 0.f;
        float musum = 0.f;

        short8 aC = *(const short8*)&feat[(size_t)(st + arow)*32 + aq*8];

        for (int t0 = 0; t0 < dg; t0 += 16) {
            // prefetch next tile; overshoot lands in next node's rows or the
            // zeroed 16-row pad (start[BN]=EE sentinel) — discarded if unused
            const short8 aN = *(const short8*)&feat[(size_t)(st + t0 + 16 + arow)*32 + aq*8];

            f32x4 acc[13];
            #pragma unroll
            for (int nt = 0; nt < 13; nt++) {
                const short8 whv = *(const short8*)&sWH[nt*640 + lb];
                const short8 wlv = *(const short8*)&sWL[nt*640 + lb];
                f32x4 z = (f32x4){0.f,0.f,0.f,0.f};
                z = __builtin_amdgcn_mfma_f32_16x16x32_bf16(aC, whv, z, 0, 0, 0);
                z = __builtin_amdgcn_mfma_f32_16x16x32_bf16(aC, wlv, z, 0, 0, 0);
                acc[nt] = z;
            }
            // relu + per-row (per-edge) stats; row = t0 + aq*4 + r
            float sr[4] = {0.f,0.f,0.f,0.f}, s2r[4] = {0.f,0.f,0.f,0.f};
            #pragma unroll
            for (int nt = 0; nt < 13; nt++) {
                #pragma unroll
                for (int r = 0; r < 4; r++) {
                    const float v = fmaxf(acc[nt][r], 0.f);
                    acc[nt][r] = v;
                    sr[r] += v; s2r[r] += v*v;
                }
            }
            // 16-lane sum across arow via DPP (VALU-only)
            #pragma unroll
            for (int r = 0; r < 4; r++) {
                sr[r]  = dpp16_sum(sr[r]);
                s2r[r] = dpp16_sum(s2r[r]);
            }
            #pragma unroll
            for (int r = 0; r < 4; r++) {
                const bool valid = (t0 + aq*4 + r) < dg;
                const float mean = sr[r] * (1.0f/DH);
                const float var  = s2r[r] * (1.0f/DH) - mean*mean;
                const float rs   = rsqrtf(var + 1e-5f);
                const float rstd = valid ? rs : 0.f;
                musum += valid ? mean*rs : 0.f;
                #pragma unroll
                for (int nt = 0; nt < 13; nt++)
                    colacc[nt] += rstd*acc[nt][r];
            }
            aC = aN;
        }

        // reduce over the 4 aq groups (rows partition)
        #pragma unroll
        for (int nt = 0; nt < 13; nt++) {
            colacc[nt] += __shfl_xor(colacc[nt], 16, 64);
            colacc[nt] += __shfl_xor(colacc[nt], 32, 64);
        }
        musum += __shfl_xor(musum, 16, 64);
        musum += __shfl_xor(musum, 32, 64);

        if (aq == 0) {
            #pragma unroll
            for (int nt = 0; nt < 13; nt++)
                plane[wv][nt*16 + arow] = colacc[nt];
        }
        // wave-internal LDS producer/consumer: DS pipe is in-order per wave —
        // no barrier (and the next node's writes issue after these reads)

        const float dgf = (float)dg;
        h[hbase + lane]       = hv0 + g0*(plane[wv][lane]     - musum) + dgf*bb0;
        h[hbase + 64 + lane]  = hv1 + g1*(plane[wv][64+lane]  - musum) + dgf*bb1;
        h[hbase + 128 + lane] = hv2 + g2*(plane[wv][128+lane] - musum) + dgf*bb2;
        if (lane < 8)
            h[hbase + 192 + lane] = hv3 + g3*(plane[wv][192+lane] - musum) + dgf*bb3;
    }
}

// ---------------------------------------------------------------------------
// cvt (per half): h fp32 -> hb hi/lo [16384][224] rows + hbT hi/lo [32][224][512]
// ---------------------------------------------------------------------------
__global__ __launch_bounds__(256) void cvt_kernel(
    const float* __restrict__ h1, const float* __restrict__ h2, const int half,
    short* __restrict__ hbH1, short* __restrict__ hbL1,
    short* __restrict__ hbH2, short* __restrict__ hbL2,
    short* __restrict__ hTH1, short* __restrict__ hTL1,
    short* __restrict__ hTH2, short* __restrict__ hTL2)
{
    const int side = blockIdx.y;
    const float* h = side ? h2 : h1;
    short* hbH = side ? hbH2 : hbH1;
    short* hbL = side ? hbL2 : hbL1;
    short* hTH = side ? hTH2 : hTH1;
    short* hTL = side ? hTL2 : hTL1;

    const int nl0 = blockIdx.x * 64;          // local node
    const int bl = nl0 >> 9, m0 = nl0 & 511;
    const int ng0 = half*HBN + nl0;

    __shared__ short tH[64][226];
    __shared__ short tL[64][226];
    const int tid = threadIdx.x;
    for (int i = tid; i < 64*224; i += 256) {
        const int r = i / 224, c = i - r*224;
        const float v = (c < DH) ? h[(size_t)(ng0+r)*DH + c] : 0.f;
        const short hi = f2bf(v);
        const short lo = f2bf(v - bf2f(hi));
        tH[r][c] = hi; tL[r][c] = lo;
        hbH[(size_t)(nl0+r)*224 + c] = hi;
        hbL[(size_t)(nl0+r)*224 + c] = lo;
    }
    __syncthreads();
    for (int i = tid; i < 224*64; i += 256) {
        const int c = i >> 6, m = i & 63;
        const size_t o = ((size_t)bl*224 + c)*NN + m0 + m;
        hTH[o] = tH[m][c];
        hTL[o] = tL[m][c];
    }
}

// ---------------------------------------------------------------------------
// prep_w: W_down[400][200] -> WbTHI/LO[208][448] (transposed, padded, split)
// ---------------------------------------------------------------------------
__global__ __launch_bounds__(256) void prep_w_kernel(
    const float* __restrict__ W_down,
    short* __restrict__ WbTHI, short* __restrict__ WbTLO)
{
    const int idx = blockIdx.x*256 + threadIdx.x;
    if (idx >= 208*448) return;
    const int c = idx / 448, kk = idx - c*448;
    float v = 0.f;
    if (c < 200) {
        if (kk < 200) v = W_down[(size_t)kk*DH + c];
        else if (kk >= 224 && kk < 424) v = W_down[(size_t)(200 + kk - 224)*DH + c];
    }
    const short hi = f2bf(v);
    WbTHI[idx] = hi;
    WbTLO[idx] = f2bf(v - bf2f(hi));
}

// ---------------------------------------------------------------------------
// Fused attention v6: 32 Q-rows per block, 512 threads / 8 waves (each wave:
// 4 key-tiles x 2 q-row-groups). attn is streaming-bound: each block reads
// the full K+V hi/lo (~918 KB) for its batch; doubling the Q-tile halves the
// per-dispatch K/V stream (940 -> ~490 MB). pb ALIASES sQ (dead after the
// barrier preceding pb writes) -> 34 KB LDS. (512,2) -> VGPR cap 128, peak
// live ~100 (acc[2][4]=32 + q-frags 16 + K frags 8 + addr). Bit-identical
// numerics: per acc, k ascends, hh/hl/lh order; PV hi-then-lo, k0 ascending.
// XCD remap: ids==k (mod 8) -> XCD k -> batches 4k..4k+3 (64 resident blocks
// per XCD = its 4 batches x 16 q-blocks).
// ---------------------------------------------------------------------------
__global__ __launch_bounds__(512, 2) void attn_kernel(
    const short* __restrict__ QH, const short* __restrict__ QL,
    const short* __restrict__ KH, const short* __restrict__ KL,
    const short* __restrict__ VTH, const short* __restrict__ VTL,
    short* __restrict__ cb)
{
    const int id = blockIdx.x + (blockIdx.y << 4);   // gridDim.x == 16
    const int j  = id >> 3;
    const int b  = (id & 7)*4 + (j >> 4);            // half-local batch
    const int q0 = (j & 15) << 5;                    // 32 q-rows
    const short* Qh = QH + (size_t)b*NN*224;
    const short* Ql = QL + (size_t)b*NN*224;
    const short* Kh = KH + (size_t)b*NN*224;
    const short* Kl = KL + (size_t)b*NN*224;
    const short* Vh = VTH + (size_t)b*224*NN;
    const short* Vl = VTL + (size_t)b*224*NN;

    __shared__ short smem[32*520];            // 33.3 KB: pb, aliases sQ
    short* sQh = smem;                        // [32][232] = 7424 shorts
    short* sQl = smem + 7424;                 // [32][232]
    short* pb  = smem;                        // [32][520]
    __shared__ float sm_[8][32];
    __shared__ float ss_[8][32];

    const int tid = threadIdx.x;
    const int wv = tid >> 6, lane = tid & 63;
    const int arow = lane & 15, aq = lane >> 4;

    // stage Q (32 rows x 224, hi/lo) cooperatively
    for (int i = tid; i < 896; i += 512) {
        const int r = i / 28, c = (i - r*28) * 8;
        *(short8*)&sQh[r*232 + c] = *(const short8*)&Qh[(size_t)(q0 + r)*224 + c];
        *(short8*)&sQl[r*232 + c] = *(const short8*)&Ql[(size_t)(q0 + r)*224 + c];
    }
    __syncthreads();

    f32x4 acc[2][4];
    #pragma unroll
    for (int g = 0; g < 2; g++)
        #pragma unroll
        for (int t = 0; t < 4; t++) acc[g][t] = (f32x4){0.f,0.f,0.f,0.f};

    const int qb = arow*232 + aq*8;
    #pragma unroll 1
    for (int k = 0; k < 7; k++) {
        const short8 qh0 = *(const short8*)&sQh[qb + k*32];
        const short8 ql0 = *(const short8*)&sQl[qb + k*32];
        const short8 qh1 = *(const short8*)&sQh[qb + 16*232 + k*32];
        const short8 ql1 = *(const short8*)&sQl[qb + 16*232 + k*32];
        #pragma unroll
        for (int t = 0; t < 4; t++) {
            const size_t kb = (size_t)((wv*4 + t)*16 + arow)*224 + k*32 + aq*8;
            const short8 bh = *(const short8*)&Kh[kb];
            const short8 bl = *(const short8*)&Kl[kb];
            acc[0][t] = __builtin_amdgcn_mfma_f32_16x16x32_bf16(qh0, bh, acc[0][t], 0, 0, 0);
            acc[0][t] = __builtin_amdgcn_mfma_f32_16x16x32_bf16(qh0, bl, acc[0][t], 0, 0, 0);
            acc[0][t] = __builtin_amdgcn_mfma_f32_16x16x32_bf16(ql0, bh, acc[0][t], 0, 0, 0);
            acc[1][t] = __builtin_amdgcn_mfma_f32_16x16x32_bf16(qh1, bh, acc[1][t], 0, 0, 0);
            acc[1][t] = __builtin_amdgcn_mfma_f32_16x16x32_bf16(qh1, bl, acc[1][t], 0, 0, 0);
            acc[1][t] = __builtin_amdgcn_mfma_f32_16x16x32_bf16(ql1, bh, acc[1][t], 0, 0, 0);
        }
    }

    float iv[2][4];
    #pragma unroll
    for (int g = 0; g < 2; g++) {
        #pragma unroll
        for (int r = 0; r < 4; r++) {
            float m = -1e30f;
            #pragma unroll
            for (int t = 0; t < 4; t++) {
                acc[g][t][r] *= T_SCALE;
                m = fmaxf(m, acc[g][t][r]);
            }
            m = fmaxf(m, __shfl_xor(m, 1, 64));
            m = fmaxf(m, __shfl_xor(m, 2, 64));
            m = fmaxf(m, __shfl_xor(m, 4, 64));
            m = fmaxf(m, __shfl_xor(m, 8, 64));
            if (arow == 0) sm_[wv][g*16 + aq*4 + r] = m;
        }
    }
    __syncthreads();
    #pragma unroll
    for (int g = 0; g < 2; g++) {
        #pragma unroll
        for (int r = 0; r < 4; r++) {
            const int row = g*16 + aq*4 + r;
            float M = sm_[0][row];
            #pragma unroll
            for (int w = 1; w < 8; w++) M = fmaxf(M, sm_[w][row]);
            float s = 0.f;
            #pragma unroll
            for (int t = 0; t < 4; t++) {
                const float e = __expf(acc[g][t][r] - M);
                acc[g][t][r] = e;
                s += e;
            }
            s += __shfl_xor(s, 1, 64);
            s += __shfl_xor(s, 2, 64);
            s += __shfl_xor(s, 4, 64);
            s += __shfl_xor(s, 8, 64);
            if (arow == 0) ss_[wv][row] = s;
        }
    }
    __syncthreads();
    #pragma unroll
    for (int g = 0; g < 2; g++) {
        #pragma unroll
        for (int r = 0; r < 4; r++) {
            const int row = g*16 + aq*4 + r;
            float s = ss_[0][row];
            #pragma unroll
            for (int w = 1; w < 8; w++) s += ss_[w][row];
            iv[g][r] = 1.0f / s;
        }
    }
    // all waves are past the QK phase (2 barriers above) — safe to overwrite sQ
    #pragma unroll
    for (int g = 0; g < 2; g++) {
        #pragma unroll
        for (int t = 0; t < 4; t++) {
            const int col = (wv*4 + t)*16 + arow;
            #pragma unroll
            for (int r = 0; r < 4; r++)
                pb[(g*16 + aq*4 + r)*520 + col] = f2bf(acc[g][t][r] * iv[g][r]);
        }
    }
    __syncthreads();

    const int nbase = (wv < 5) ? 2*wv : 10 + (wv - 5);
    const int ncnt  = (wv < 5) ? 2 : 1;
    f32x4 pacc[2][2];
    #pragma unroll
    for (int g = 0; g < 2; g++)
        #pragma unroll
        for (int t = 0; t < 2; t++) pacc[g][t] = (f32x4){0.f,0.f,0.f,0.f};

    for (int k0 = 0; k0 < NN; k0 += 32) {
        const short8 a0 = *(const short8*)&pb[arow*520 + k0 + aq*8];
        const short8 a1 = *(const short8*)&pb[(16 + arow)*520 + k0 + aq*8];
        #pragma unroll
        for (int t = 0; t < 2; t++) {
            if (t < ncnt) {
                const size_t vb = (size_t)((nbase+t)*16 + arow)*NN + k0 + aq*8;
                const short8 bh = *(const short8*)&Vh[vb];
                const short8 bl = *(const short8*)&Vl[vb];
                pacc[0][t] = __builtin_amdgcn_mfma_f32_16x16x32_bf16(a0, bh, pacc[0][t], 0, 0, 0);
                pacc[0][t] = __builtin_amdgcn_mfma_f32_16x16x32_bf16(a0, bl, pacc[0][t], 0, 0, 0);
                pacc[1][t] = __builtin_amdgcn_mfma_f32_16x16x32_bf16(a1, bh, pacc[1][t], 0, 0, 0);
                pacc[1][t] = __builtin_amdgcn_mfma_f32_16x16x32_bf16(a1, bl, pacc[1][t], 0, 0, 0);
            }
        }
    }

    #pragma unroll
    for (int t = 0; t < 2; t++) {
        if (t < ncnt) {
            const int col = (nbase+t)*16 + arow;
            #pragma unroll
            for (int g = 0; g < 2; g++) {
                #pragma unroll
                for (int r = 0; r < 4; r++) {
                    const int row = q0 + g*16 + aq*4 + r;
                    const short v = (col < DH) ? f2bf(pacc[g][t][r]) : (short)0;
                    cb[((size_t)b*NN + row)*224 + col] = v;
                }
            }
        }
    }
    if (wv == 7) {
        const int col = 208 + arow;
        #pragma unroll
        for (int g = 0; g < 2; g++) {
            #pragma unroll
            for (int r = 0; r < 4; r++) {
                const int row = q0 + g*16 + aq*4 + r;
                cb[((size_t)b*NN + row)*224 + col] = 0;
            }
        }
    }
}

// ---------------------------------------------------------------------------
// down (per half, MFMA, split-W): relu([hb|cb] @ W_down) + degree_table -> hsg
// ---------------------------------------------------------------------------
__global__ __launch_bounds__(256) void down_mfma(
    const short* __restrict__ hbH1, const short* __restrict__ hbH2,
    const short* __restrict__ cb1, const short* __restrict__ cb2,
    const int* __restrict__ deg1, const int* __restrict__ deg2,
    const short* __restrict__ WbTH, const short* __restrict__ WbTL,
    const float* __restrict__ degree_table,
    float* __restrict__ hsg1, float* __restrict__ hsg2, const int half)
{
    const int side = blockIdx.y;
    const short* X0 = side ? hbH2 : hbH1;
    const short* X1 = side ? cb2 : cb1;
    const int*   dgp = side ? deg2 : deg1;
    float* hsg = side ? hsg2 : hsg1;

    const int nl0 = blockIdx.x * 64;
    const int ng0 = half*HBN + nl0;
    const int b = ng0 >> 9;

    __shared__ short As[64*40];
    __shared__ short BsH[208*40];
    __shared__ short BsL[208*40];
    __shared__ float part[208];

    const int tid = threadIdx.x;
    const int wv = tid >> 6, lane = tid & 63;
    const int arow = lane & 15, aq = lane >> 4;

    if (tid < 208) part[tid] = 0.f;

    f32x4 acc[13];
    #pragma unroll
    for (int t = 0; t < 13; t++) acc[t] = (f32x4){0.f,0.f,0.f,0.f};

    const int sr = tid >> 2, sc = (tid & 3) * 8;

    for (int phase = 0; phase < 2; phase++) {
        const short* X = phase ? X1 : X0;
        for (int k0 = 0; k0 < 224; k0 += 32) {
            __syncthreads();
            *(short8*)&As[sr*40 + sc] =
                *(const short8*)&X[(size_t)(nl0+sr)*224 + k0 + sc];
            const int kkg = phase*224 + k0;
            #pragma unroll
            for (int pass = 0; pass < 4; pass++) {
                const int f = pass*256 + tid;
                if (f < 832) {
                    const int d = f >> 2, cc = (f & 3) * 8;
                    *(short8*)&BsH[d*40 + cc] = *(const short8*)&WbTH[(size_t)d*448 + kkg + cc];
                    *(short8*)&BsL[d*40 + cc] = *(const short8*)&WbTL[(size_t)d*448 + kkg + cc];
                }
            }
            __syncthreads();
            const short8 a = *(const short8*)&As[(16*wv + arow)*40 + aq*8];
            #pragma unroll
            for (int t = 0; t < 13; t++) {
                const short8 bh = *(const short8*)&BsH[(t*16 + arow)*40 + aq*8];
                const short8 bl = *(const short8*)&BsL[(t*16 + arow)*40 + aq*8];
                acc[t] = __builtin_amdgcn_mfma_f32_16x16x32_bf16(a, bh, acc[t], 0, 0, 0);
                acc[t] = __builtin_amdgcn_mfma_f32_16x16x32_bf16(a, bl, acc[t], 0, 0, 0);
            }
        }
    }
    __syncthreads();

    int dgc[4];
    #pragma unroll
    for (int r = 0; r < 4; r++) {
        int d = dgp[ng0 + 16*wv + aq*4 + r];
        dgc[r] = d > 199 ? 199 : d;
    }
    #pragma unroll
    for (int nt = 0; nt < 13; nt++) {
        const int col = nt*16 + arow;
        float s = 0.f;
        if (col < DH) {
            #pragma unroll
            for (int r = 0; r < 4; r++)
                s += fmaxf(acc[nt][r], 0.f) + degree_table[dgc[r]*DH + col];
        }
        s += __shfl_xor(s, 16, 64);
        s += __shfl_xor(s, 32, 64);
        if (lane < 16 && col < DH) atomicAdd(&part[col], s);
    }
    __syncthreads();
    if (tid < DH) unsafeAtomicAdd(&hsg[b*206 + tid], part[tid] * (1.0f/512.0f));
}

// ---------------------------------------------------------------------------
// Kernel 6: interaction mean over nodes -> hsg cols 200..205
// ---------------------------------------------------------------------------
__global__ __launch_bounds__(192) void inter_kernel(
    const float* __restrict__ i1, const float* __restrict__ i2,
    float* __restrict__ hsg1, float* __restrict__ hsg2)
{
    const int side = blockIdx.y;
    const float* it = side ? i2 : i1;
    float* hsg = side ? hsg2 : hsg1;
    const int b = blockIdx.x;
    __shared__ float red[192];
    const int tid = threadIdx.x;
    const int j = tid % 6, seg = tid / 6;
    float s = 0.0f;
    for (int n = seg*16; n < seg*16 + 16; n++)
        s += it[(size_t)b*NN*DI + n*DI + j];
    red[tid] = s;
    __syncthreads();
    if (tid < 6) {
        float tot = 0.0f;
        for (int sg2 = 0; sg2 < 32; sg2++) tot += red[sg2*6 + tid];
        hsg[b*206 + 200 + tid] = tot * (1.0f/512.0f);
    }
}

// ---------------------------------------------------------------------------
// Kernel 7: final MLP, one block per batch row
// ---------------------------------------------------------------------------
__global__ __launch_bounds__(256) void mlp_kernel(
    const float* __restrict__ hsg1, const float* __restrict__ hsg2,
    const float* __restrict__ W_f1, const float* __restrict__ b_f1,
    const float* __restrict__ W_f2, const float* __restrict__ b_f2,
    const float* __restrict__ W_f3, const float* __restrict__ b_f3,
    const float* __restrict__ W_f4, const float* __restrict__ b_f4,
    float* __restrict__ out)
{
    const int b = blockIdx.x;
    __shared__ float x[618];
    __shared__ float y1[400];
    __shared__ float y2[200];
    __shared__ float y3[100];
    __shared__ float red[256];
    const int tid = threadIdx.x;

    if (tid < 206) {
        const float a = hsg1[b*206 + tid], bb = hsg2[b*206 + tid];
        x[tid] = a; x[206 + tid] = bb; x[412 + tid] = a - bb;
    }
    __syncthreads();
    for (int c = tid; c < 400; c += 256) {
        float acc = b_f1[c];
        for (int k = 0; k < 618; k++) acc += x[k]*W_f1[(size_t)k*400 + c];
        y1[c] = fmaxf(acc, 0.0f);
    }
    __syncthreads();
    if (tid < 200) {
        float acc = b_f2[tid];
        for (int k = 0; k < 400; k++) acc += y1[k]*W_f2[k*200 + tid];
        y2[tid] = fmaxf(acc, 0.0f);
    }
    __syncthreads();
    if (tid < 100) {
        float acc = b_f3[tid];
        for (int k = 0; k < 200; k++) acc += y2[k]*W_f3[k*100 + tid];
        y3[tid] = fmaxf(acc, 0.0f);
    }
    __syncthreads();
    red[tid] = (tid < 100) ? y3[tid]*W_f4[tid] : 0.0f;
    __syncthreads();
    for (int s = 128; s > 0; s >>= 1) {
        if (tid < s) red[tid] += red[tid + s];
        __syncthreads();
    }
    if (tid == 0) out[b] = red[0] + b_f4[0];
}

// ---------------------------------------------------------------------------
extern "C" void kernel_launch(void* const* d_in, const int* in_sizes, int n_in,
                              void* d_out, int out_size, void* d_ws, size_t ws_size,
                              hipStream_t stream)
{
    const float* atom1  = (const float*)d_in[0];
    const float* atom2  = (const float*)d_in[1];
    const float* coords1= (const float*)d_in[2];
    const float* coords2= (const float*)d_in[3];
    const float* efeat1 = (const float*)d_in[4];
    const float* efeat2 = (const float*)d_in[5];
    const float* inter1 = (const float*)d_in[6];
    const float* inter2 = (const float*)d_in[7];
    const int*   esrc1  = (const int*)d_in[8];
    const int*   edst1  = (const int*)d_in[9];
    const int*   esrc2  = (const int*)d_in[10];
    const int*   edst2  = (const int*)d_in[11];
    const float* W_atom = (const float*)d_in[12];
    const float* W_edge = (const float*)d_in[13];
    const float* W_rbf  = (const float*)d_in[14];
    const float* b_rbf  = (const float*)d_in[15];
    const float* ln_g   = (const float*)d_in[16];
    const float* ln_b   = (const float*)d_in[17];
    const float* W_down = (const float*)d_in[18];
    const float* deg_tab= (const float*)d_in[19];
    const float* W_f1   = (const float*)d_in[20];
    const float* b_f1   = (const float*)d_in[21];
    const float* W_f2   = (const float*)d_in[22];
    const float* b_f2   = (const float*)d_in[23];
    const float* W_f3   = (const float*)d_in[24];
    const float* b_f3   = (const float*)d_in[25];
    const float* W_f4   = (const float*)d_in[26];
    const float* b_f4   = (const float*)d_in[27];
    float* out = (float*)d_out;

    // ---- workspace layout (~133 MB)
    float* ws = (float*)d_ws;
    const size_t HSZ = (size_t)BN*DH;              // per-side h floats
    float* h1  = ws;
    float* h2  = h1 + HSZ;
    // pool: max(feat 2*(EE+16)*32 shorts, bf16 pool 10*HB shorts)
    short* pool = (short*)(h2 + HSZ);
    const size_t FSZ = (size_t)(EE+16)*32;
    short* featH1 = pool;
    short* featH2 = featH1 + FSZ;
    const size_t HB = (size_t)32*NN*224;           // 3,670,016 shorts
    short* hbH1 = pool;           short* hbL1 = hbH1 + HB;
    short* hbH2 = hbL1 + HB;      short* hbL2 = hbH2 + HB;
    short* hTH1 = hbL2 + HB;      short* hTL1 = hTH1 + HB;
    short* hTH2 = hTL1 + HB;      short* hTL2 = hTH2 + HB;
    short* cb1  = hTL2 + HB;      short* cb2  = cb1 + HB;
    size_t pool_sz = 2*FSZ > 10*HB ? 2*FSZ : 10*HB;
    short* after = pool + pool_sz;
    short* WTH = after;                            // [208][32]
    short* WTL = WTH + 208*32;
    short* WbTH = WTL + 208*32;                    // [208][448]
    short* WbTL = WbTH + 208*448;
    float* hsg1 = (float*)(WbTL + 208*448);
    float* hsg2 = hsg1 + (size_t)BB*206;
    int* deg1 = (int*)(hsg2 + (size_t)BB*206);
    int* deg2 = deg1 + BN;
    int* start1 = deg2 + BN;                       // BN+1 entries
    int* start2 = start1 + (BN+1);
    int* cursor1 = start2 + (BN+1);
    int* cursor2 = cursor1 + BN;
    int* rank1 = cursor2 + BN;
    int* rank2 = rank1 + EE;

    hipMemsetAsync(deg1, 0, 2*(size_t)BN*sizeof(int), stream);
    hipMemsetAsync(hsg1, 0, 2*(size_t)BB*206*sizeof(float), stream);

    node_kernel<<<dim3(BN/4, 2), 256, 0, stream>>>(
        atom1, atom2, W_atom, ln_g, ln_b, h1, h2);

    hist_kernel<<<EE/256, 256, 0, stream>>>(edst1, edst2, deg1, deg2);
    scan_kernel<<<2, 1024, 0, stream>>>(deg1, deg2, start1, start2, cursor1, cursor2);
    scatter_kernel<<<EE/256, 256, 0, stream>>>(edst1, edst2, cursor1, cursor2,
                                               rank1, rank2);

    featgen_kernel<<<dim3(EE/256, 2), 256, 0, stream>>>(
        efeat1, efeat2, esrc1, esrc2, edst1, edst2, coords1, coords2,
        rank1, rank2, featH1, featH2);
    featpad_kernel<<<1, 256, 0, stream>>>(featH1, featH2);

    prep_wt_kernel<<<(208*32 + 255)/256, 256, 0, stream>>>(
        W_edge, W_rbf, b_rbf, WTH, WTL);

    gather_mfma<<<dim3(BN/16, 2), 256, 0, stream>>>(
        featH1, featH2, start1, start2, WTH, WTL, ln_g, ln_b, h1, h2);

    prep_w_kernel<<<(208*448 + 255)/256, 256, 0, stream>>>(W_down, WbTH, WbTL);

    for (int half = 0; half < 2; half++) {
        cvt_kernel<<<dim3(HBN/64, 2), 256, 0, stream>>>(
            h1, h2, half, hbH1, hbL1, hbH2, hbL2, hTH1, hTL1, hTH2, hTL2);
        // dir0: c1 = softmax_rows(h1@h2^T) @ h2
        attn_kernel<<<dim3(NN/32, 32), 512, 0, stream>>>(
            hbH1, hbL1, hbH2, hbL2, hTH2, hTL2, cb1);
        // dir1: c2 = softmax_rows(h2@h1^T) @ h1
        attn_kernel<<<dim3(NN/32, 32), 512, 0, stream>>>(
            hbH2, hbL2, hbH1, hbL1, hTH1, hTL1, cb2);
        down_mfma<<<dim3(HBN/64, 2), 256, 0, stream>>>(
            hbH1, hbH2, cb1, cb2, deg1, deg2, WbTH, WbTL, deg_tab,
            hsg1, hsg2, half);
    }

    inter_kernel<<<dim3(BB, 2), 192, 0, stream>>>(inter1, inter2, hsg1, hsg2);

    mlp_kernel<<<BB, 256, 0, stream>>>(
        hsg1, hsg2, W_f1, b_f1, W_f2, b_f2, W_f3, b_f3, W_f4, b_f4, out);
}

// Round 7
// 928.465 us; speedup vs baseline: 1.4688x; 1.0515x over previous
//
#include <hip/hip_runtime.h>
#include <cstddef>
#include <cstdint>

// Problem constants
#define BB   64
#define NN   512
#define BN   (BB*NN)          // 32768
#define HBN  16384            // nodes per half
#define EE   524288
#define DA   70
#define DE   14
#define DH   200
#define DI   6
#define T_SCALE 0.07071067811865475f   // sqrt(1/200)

typedef __attribute__((ext_vector_type(8))) short short8;
typedef __attribute__((ext_vector_type(4))) float f32x4;

__device__ __forceinline__ short f2bf(float x) {
    union { float f; unsigned u; } v; v.f = x;
    const unsigned r = v.u + 0x7FFFu + ((v.u >> 16) & 1u);   // RNE
    return (short)(r >> 16);
}
__device__ __forceinline__ float bf2f(short s) {
    union { unsigned u; float f; } v;
    v.u = ((unsigned)(unsigned short)s) << 16;
    return v.f;
}

// 16-lane (row) sum via DPP — pure VALU, no DS pipe, no address VGPRs.
__device__ __forceinline__ float dpp16_sum(float x) {
    union { float f; int i; } a, b;
    a.f = x;
    b.i = __builtin_amdgcn_update_dpp(0, a.i, 0xB1, 0xF, 0xF, false); a.f += b.f;
    b.i = __builtin_amdgcn_update_dpp(0, a.i, 0x4E, 0xF, 0xF, false); a.f += b.f;
    b.i = __builtin_amdgcn_update_dpp(0, a.i, 0x141, 0xF, 0xF, false); a.f += b.f;
    b.i = __builtin_amdgcn_update_dpp(0, a.i, 0x140, 0xF, 0xF, false); a.f += b.f;
    return a.f;
}

// ---------------------------------------------------------------------------
// Kernel 1: per-node  h = layernorm(relu(atom @ W_atom))
// ---------------------------------------------------------------------------
__global__ __launch_bounds__(256) void node_kernel(
    const float* __restrict__ atom1, const float* __restrict__ atom2,
    const float* __restrict__ W_atom,
    const float* __restrict__ ln_g, const float* __restrict__ ln_b,
    float* __restrict__ h1, float* __restrict__ h2)
{
    const int side = blockIdx.y;
    const float* atom = side ? atom2 : atom1;
    float* h = side ? h2 : h1;
    const int node0 = blockIdx.x * 4;
    const int tid = threadIdx.x;

    __shared__ float arow[4][DA];
    __shared__ float vals[4][DH];

    for (int i = tid; i < 4*DA; i += 256) {
        const int n = i / DA, k = i % DA;
        arow[n][k] = atom[(size_t)(node0+n)*DA + k];
    }
    __syncthreads();

    if (tid < DH) {
        float a0 = 0.f, a1 = 0.f, a2 = 0.f, a3 = 0.f;
        #pragma unroll 7
        for (int k = 0; k < DA; k++) {
            const float w = W_atom[k*DH + tid];
            a0 += arow[0][k]*w; a1 += arow[1][k]*w;
            a2 += arow[2][k]*w; a3 += arow[3][k]*w;
        }
        vals[0][tid] = fmaxf(a0, 0.f);
        vals[1][tid] = fmaxf(a1, 0.f);
        vals[2][tid] = fmaxf(a2, 0.f);
        vals[3][tid] = fmaxf(a3, 0.f);
    }
    __syncthreads();

    const int wv = tid >> 6, lane = tid & 63;
    float v0 = vals[wv][lane];
    float v1 = vals[wv][64+lane];
    float v2 = vals[wv][128+lane];
    float v3 = (lane < 8) ? vals[wv][192+lane] : 0.0f;
    float s  = v0+v1+v2+v3;
    float s2 = v0*v0+v1*v1+v2*v2+v3*v3;
    #pragma unroll
    for (int off = 1; off < 64; off <<= 1) {
        s  += __shfl_xor(s,  off, 64);
        s2 += __shfl_xor(s2, off, 64);
    }
    const float mean = s * (1.0f/DH);
    const float var  = s2 * (1.0f/DH) - mean*mean;
    const float rstd = rsqrtf(var + 1e-5f);
    const size_t base = (size_t)(node0+wv)*DH;
    h[base + lane]       = ln_g[lane]     *(v0-mean)*rstd + ln_b[lane];
    h[base + 64 + lane]  = ln_g[64+lane]  *(v1-mean)*rstd + ln_b[64+lane];
    h[base + 128 + lane] = ln_g[128+lane] *(v2-mean)*rstd + ln_b[128+lane];
    if (lane < 8)
        h[base + 192 + lane] = ln_g[192+lane]*(v3-mean)*rstd + ln_b[192+lane];
}

// ---------------------------------------------------------------------------
// hist: degree count + per-edge arrival rank (the atomic's return value).
// rank[e] in [0, deg) is a valid within-node permutation — the counting-sort
// scatter pass is redundant: final slot = start[dst] + rank[e] (featgen).
// ---------------------------------------------------------------------------
__global__ __launch_bounds__(256) void hist_kernel(
    const int* __restrict__ edst1, const int* __restrict__ edst2,
    int* __restrict__ deg1, int* __restrict__ deg2,
    int* __restrict__ rank1, int* __restrict__ rank2)
{
    const int e = blockIdx.x*256 + threadIdx.x;
    rank1[e] = atomicAdd(&deg1[edst1[e]], 1);
    rank2[e] = atomicAdd(&deg2[edst2[e]], 1);
}

__global__ __launch_bounds__(1024) void scan_kernel(
    const int* __restrict__ deg1, const int* __restrict__ deg2,
    int* __restrict__ start1, int* __restrict__ start2)
{
    const int side = blockIdx.x;
    const int* deg   = side ? deg2 : deg1;
    int* start  = side ? start2 : start1;

    __shared__ int part[1024];
    const int t = threadIdx.x;
    const int base = t * 32;
    int local[32];
    int sum = 0;
    #pragma unroll
    for (int i = 0; i < 8; i++) {        // int4 vector loads (16B/lane)
        const int4 v = *(const int4*)&deg[base + i*4];
        local[4*i+0] = v.x; local[4*i+1] = v.y;
        local[4*i+2] = v.z; local[4*i+3] = v.w;
        sum += v.x + v.y + v.z + v.w;
    }
    part[t] = sum;
    __syncthreads();
    for (int off = 1; off < 1024; off <<= 1) {
        int v = (t >= off) ? part[t-off] : 0;
        __syncthreads();
        part[t] += v;
        __syncthreads();
    }
    int run = part[t] - sum;   // exclusive
    #pragma unroll
    for (int i = 0; i < 32; i++) {
        start[base+i] = run;
        run += local[i];
    }
    if (t == 1023) start[BN] = run;   // sentinel == EE
}

// ---------------------------------------------------------------------------
// featgen: per-edge feature row -> featH[start[dst]+rank[e]][32] bf16
//   k 0..13 = ef, 14..29 = rbf, 30 = 1.0 (bias hook), 31 = 0
// ---------------------------------------------------------------------------
__global__ __launch_bounds__(256) void featgen_kernel(
    const float* __restrict__ efeat1, const float* __restrict__ efeat2,
    const int* __restrict__ esrc1, const int* __restrict__ esrc2,
    const int* __restrict__ edst1, const int* __restrict__ edst2,
    const float* __restrict__ coords1, const float* __restrict__ coords2,
    const int* __restrict__ rank1, const int* __restrict__ rank2,
    const int* __restrict__ start1, const int* __restrict__ start2,
    short* __restrict__ featH1, short* __restrict__ featH2)
{
    const int side = blockIdx.y;
    const float* ef     = side ? efeat2  : efeat1;
    const int*   esrc   = side ? esrc2   : esrc1;
    const int*   edst   = side ? edst2   : edst1;
    const float* coords = side ? coords2 : coords1;
    const int*   rank   = side ? rank2   : rank1;
    const int*   start  = side ? start2  : start1;
    short* featH = side ? featH2 : featH1;

    const int e = blockIdx.x*256 + threadIdx.x;
    const int src = esrc[e], dst = edst[e];

    short f[32];
    #pragma unroll
    for (int k = 0; k < 14; k++) f[k] = f2bf(ef[(size_t)e*DE + k]);

    const float dx = coords[src*3+0] - coords[dst*3+0];
    const float dy = coords[src*3+1] - coords[dst*3+1];
    const float dz = coords[src*3+2] - coords[dst*3+2];
    const float dist = sqrtf(dx*dx + dy*dy + dz*dz + 1e-12f);
    #pragma unroll
    for (int k = 0; k < 16; k++) {
        const float t = 3.2f*dist - 1.0666666667f*(float)k;
        f[14+k] = f2bf(__expf(-t*t));
    }
    f[30] = f2bf(1.0f);
    f[31] = 0;

    const int slot = start[dst] + rank[e];
    short* out = featH + (size_t)slot*32;
    #pragma unroll
    for (int q = 0; q < 4; q++)
        *(short8*)&out[q*8] = *(short8*)&f[q*8];
}

// ---------------------------------------------------------------------------
// prep_wt: build WT[208][32] hi/lo for the edge projection.
// Blocks 26/27 zero the 16-row feat pad (folded featpad_kernel).
// ---------------------------------------------------------------------------
__global__ __launch_bounds__(256) void prep_wt_kernel(
    const float* __restrict__ W_edge, const float* __restrict__ W_rbf,
    const float* __restrict__ b_rbf,
    short* __restrict__ WTH, short* __restrict__ WTL,
    short* __restrict__ featH1, short* __restrict__ featH2)
{
    const int bid = blockIdx.x;
    if (bid >= 26) {
        short* f = (bid == 26) ? featH1 : featH2;
        f[(size_t)EE*32 + threadIdx.x] = 0;
        f[(size_t)EE*32 + 256 + threadIdx.x] = 0;
        return;
    }
    const int idx = bid*256 + threadIdx.x;
    const int c = idx >> 5, k = idx & 31;
    float v = 0.f;
    if (c < 100) {
        if (k < 14) v = W_edge[k*100 + c];
    } else if (c < 200) {
        const int cc = c - 100;
        if (k >= 14 && k < 30) v = W_rbf[(k-14)*100 + cc];
        else if (k == 30) v = b_rbf[cc];
    }
    const short hi = f2bf(v);
    WTH[idx] = hi;
    WTL[idx] = f2bf(v - bf2f(hi));
}

// ---------------------------------------------------------------------------
// gather_mfma v7 (unchanged): 132 us, VALU-dominated (53%), VALU:MFMA 4.3:1
// matches static op count — structural floor for this formulation.
// ---------------------------------------------------------------------------
__global__ __launch_bounds__(256, 2) void gather_mfma(
    const short* __restrict__ featH1, const short* __restrict__ featH2,
    const int* __restrict__ start1, const int* __restrict__ start2,
    const short* __restrict__ WTH, const short* __restrict__ WTL,
    const float* __restrict__ ln_g, const float* __restrict__ ln_b,
    float* __restrict__ h1, float* __restrict__ h2)
{
    __shared__ short sWH[208*40];    // 16.6 KB, stride-40 (80B) rows
    __shared__ short sWL[208*40];    // 16.6 KB
    __shared__ float plane[4][216];

    const int tid = threadIdx.x;
    const int wv = tid >> 6, lane = tid & 63;
    const int arow = lane & 15, aq = lane >> 4;

    // stage W once per block (832 short8 per array)
    for (int f = tid; f < 832; f += 256) {
        const int d = f >> 2, cc = (f & 3) * 8;
        *(short8*)&sWH[d*40 + cc] = *(const short8*)&WTH[f*8];
        *(short8*)&sWL[d*40 + cc] = *(const short8*)&WTL[f*8];
    }
    __syncthreads();

    const int side = blockIdx.y;
    const short* feat = side ? featH2 : featH1;
    const int*  start = side ? start2 : start1;
    float* h = side ? h2 : h1;

    const int c0 = blockIdx.x*16 + wv*4;     // wave's first node (of 4)

    // hoist ln params (lane-mapped)
    const float g0 = ln_g[lane],      bb0 = ln_b[lane];
    const float g1 = ln_g[64+lane],   bb1 = ln_b[64+lane];
    const float g2 = ln_g[128+lane],  bb2 = ln_b[128+lane];
    const float g3 = (lane < 8) ? ln_g[192+lane] : 0.f;
    const float bb3 = (lane < 8) ? ln_b[192+lane] : 0.f;

    // 5 start values for the 4 nodes, one load, then readlane
    const int sidx = (lane < 5) ? lane : 4;
    const int sv = start[c0 + sidx];

    const int lb = arow*40 + aq*8;           // LDS element offset in a W tile

    #pragma unroll 1
    for (int ni = 0; ni < 4; ni++) {
        const int st = __builtin_amdgcn_readlane(sv, ni);
        const int en = __builtin_amdgcn_readlane(sv, ni + 1);
        const int dg = en - st;
        const int node = c0 + ni;
        const size_t hbase = (size_t)node * DH;

        // hoist h RMW loads (consumed at node end, hidden under tiles)
        const float hv0 = h[hbase + lane];
        const float hv1 = h[hbase + 64 + lane];
        const float hv2 = h[hbase + 128 + lane];
        const float hv3 = (lane < 8) ? h[hbase + 192 + lane] : 0.f;

        float colacc[13];
        #pragma unroll
        for (int nt = 0; nt < 13; nt++) colacc[nt] = 0.f;
        float musum = 0.f;

        short8 aC = *(const short8*)&feat[(size_t)(st + arow)*32 + aq*8];

        for (int t0 = 0; t0 < dg; t0 += 16) {
            // prefetch next tile; overshoot lands in next node's rows or the
            // zeroed 16-row pad (start[BN]=EE sentinel) — discarded if unused
            const short8 aN = *(const short8*)&feat[(size_t)(st + t0 + 16 + arow)*32 + aq*8];

            f32x4 acc[13];
            #pragma unroll
            for (int nt = 0; nt < 13; nt++) {
                const short8 whv = *(const short8*)&sWH[nt*640 + lb];
                const short8 wlv = *(const short8*)&sWL[nt*640 + lb];
                f32x4 z = (f32x4){0.f,0.f,0.f,0.f};
                z = __builtin_amdgcn_mfma_f32_16x16x32_bf16(aC, whv, z, 0, 0, 0);
                z = __builtin_amdgcn_mfma_f32_16x16x32_bf16(aC, wlv, z, 0, 0, 0);
                acc[nt] = z;
            }
            // relu + per-row (per-edge) stats; row = t0 + aq*4 + r
            float sr[4] = {0.f,0.f,0.f,0.f}, s2r[4] = {0.f,0.f,0.f,0.f};
            #pragma unroll
            for (int nt = 0; nt < 13; nt++) {
                #pragma unroll
                for (int r = 0; r < 4; r++) {
                    const float v = fmaxf(acc[nt][r], 0.f);
                    acc[nt][r] = v;
                    sr[r] += v; s2r[r] += v*v;
                }
            }
            // 16-lane sum across arow via DPP (VALU-only)
            #pragma unroll
            for (int r = 0; r < 4; r++) {
                sr[r]  = dpp16_sum(sr[r]);
                s2r[r] = dpp16_sum(s2r[r]);
            }
            #pragma unroll
            for (int r = 0; r < 4; r++) {
                const bool valid = (t0 + aq*4 + r) < dg;
                const float mean = sr[r] * (1.0f/DH);
                const float var  = s2r[r] * (1.0f/DH) - mean*mean;
                const float rs   = rsqrtf(var + 1e-5f);
                const float rstd = valid ? rs : 0.f;
                musum += valid ? mean*rs : 0.f;
                #pragma unroll
                for (int nt = 0; nt < 13; nt++)
                    colacc[nt] += rstd*acc[nt][r];
            }
            aC = aN;
        }

        // reduce over the 4 aq groups (rows partition)
        #pragma unroll
        for (int nt = 0; nt < 13; nt++) {
            colacc[nt] += __shfl_xor(colacc[nt], 16, 64);
            colacc[nt] += __shfl_xor(colacc[nt], 32, 64);
        }
        musum += __shfl_xor(musum, 16, 64);
        musum += __shfl_xor(musum, 32, 64);

        if (aq == 0) {
            #pragma unroll
            for (int nt = 0; nt < 13; nt++)
                plane[wv][nt*16 + arow] = colacc[nt];
        }
        // wave-internal LDS producer/consumer: DS pipe is in-order per wave —
        // no barrier (and the next node's writes issue after these reads)

        const float dgf = (float)dg;
        h[hbase + lane]       = hv0 + g0*(plane[wv][lane]     - musum) + dgf*bb0;
        h[hbase + 64 + lane]  = hv1 + g1*(plane[wv][64+lane]  - musum) + dgf*bb1;
        h[hbase + 128 + lane] = hv2 + g2*(plane[wv][128+lane] - musum) + dgf*bb2;
        if (lane < 8)
            h[hbase + 192 + lane] = hv3 + g3*(plane[wv][192+lane] - musum) + dgf*bb3;
    }
}

// ---------------------------------------------------------------------------
// cvt (per half): h fp32 -> hb hi/lo [16384][224] rows + hbT hi/lo [32][224][512]
// ---------------------------------------------------------------------------
__global__ __launch_bounds__(256) void cvt_kernel(
    const float* __restrict__ h1, const float* __restrict__ h2, const int half,
    short* __restrict__ hbH1, short* __restrict__ hbL1,
    short* __restrict__ hbH2, short* __restrict__ hbL2,
    short* __restrict__ hTH1, short* __restrict__ hTL1,
    short* __restrict__ hTH2, short* __restrict__ hTL2)
{
    const int side = blockIdx.y;
    const float* h = side ? h2 : h1;
    short* hbH = side ? hbH2 : hbH1;
    short* hbL = side ? hbL2 : hbL1;
    short* hTH = side ? hTH2 : hTH1;
    short* hTL = side ? hTL2 : hTL1;

    const int nl0 = blockIdx.x * 64;          // local node
    const int bl = nl0 >> 9, m0 = nl0 & 511;
    const int ng0 = half*HBN + nl0;

    __shared__ short tH[64][226];
    __shared__ short tL[64][226];
    const int tid = threadIdx.x;
    for (int i = tid; i < 64*224; i += 256) {
        const int r = i / 224, c = i - r*224;
        const float v = (c < DH) ? h[(size_t)(ng0+r)*DH + c] : 0.f;
        const short hi = f2bf(v);
        const short lo = f2bf(v - bf2f(hi));
        tH[r][c] = hi; tL[r][c] = lo;
        hbH[(size_t)(nl0+r)*224 + c] = hi;
        hbL[(size_t)(nl0+r)*224 + c] = lo;
    }
    __syncthreads();
    for (int i = tid; i < 224*64; i += 256) {
        const int c = i >> 6, m = i & 63;
        const size_t o = ((size_t)bl*224 + c)*NN + m0 + m;
        hTH[o] = tH[m][c];
        hTL[o] = tL[m][c];
    }
}

// ---------------------------------------------------------------------------
// prep_w: W_down[400][200] -> WbTHI/LO[208][448] (transposed, padded, split)
// ---------------------------------------------------------------------------
__global__ __launch_bounds__(256) void prep_w_kernel(
    const float* __restrict__ W_down,
    short* __restrict__ WbTHI, short* __restrict__ WbTLO)
{
    const int idx = blockIdx.x*256 + threadIdx.x;
    if (idx >= 208*448) return;
    const int c = idx / 448, kk = idx - c*448;
    float v = 0.f;
    if (c < 200) {
        if (kk < 200) v = W_down[(size_t)kk*DH + c];
        else if (kk >= 224 && kk < 424) v = W_down[(size_t)(200 + kk - 224)*DH + c];
    }
    const short hi = f2bf(v);
    WbTHI[idx] = hi;
    WbTLO[idx] = f2bf(v - bf2f(hi));
}

// ---------------------------------------------------------------------------
// Fused attention v6 (unchanged from round 6): 32 Q-rows/block, 512 thr.
// ---------------------------------------------------------------------------
__global__ __launch_bounds__(512, 2) void attn_kernel(
    const short* __restrict__ QH, const short* __restrict__ QL,
    const short* __restrict__ KH, const short* __restrict__ KL,
    const short* __restrict__ VTH, const short* __restrict__ VTL,
    short* __restrict__ cb)
{
    const int id = blockIdx.x + (blockIdx.y << 4);   // gridDim.x == 16
    const int j  = id >> 3;
    const int b  = (id & 7)*4 + (j >> 4);            // half-local batch
    const int q0 = (j & 15) << 5;                    // 32 q-rows
    const short* Qh = QH + (size_t)b*NN*224;
    const short* Ql = QL + (size_t)b*NN*224;
    const short* Kh = KH + (size_t)b*NN*224;
    const short* Kl = KL + (size_t)b*NN*224;
    const short* Vh = VTH + (size_t)b*224*NN;
    const short* Vl = VTL + (size_t)b*224*NN;

    __shared__ short smem[32*520];            // 33.3 KB: pb, aliases sQ
    short* sQh = smem;                        // [32][232] = 7424 shorts
    short* sQl = smem + 7424;                 // [32][232]
    short* pb  = smem;                        // [32][520]
    __shared__ float sm_[8][32];
    __shared__ float ss_[8][32];

    const int tid = threadIdx.x;
    const int wv = tid >> 6, lane = tid & 63;
    const int arow = lane & 15, aq = lane >> 4;

    // stage Q (32 rows x 224, hi/lo) cooperatively
    for (int i = tid; i < 896; i += 512) {
        const int r = i / 28, c = (i - r*28) * 8;
        *(short8*)&sQh[r*232 + c] = *(const short8*)&Qh[(size_t)(q0 + r)*224 + c];
        *(short8*)&sQl[r*232 + c] = *(const short8*)&Ql[(size_t)(q0 + r)*224 + c];
    }
    __syncthreads();

    f32x4 acc[2][4];
    #pragma unroll
    for (int g = 0; g < 2; g++)
        #pragma unroll
        for (int t = 0; t < 4; t++) acc[g][t] = (f32x4){0.f,0.f,0.f,0.f};

    const int qb = arow*232 + aq*8;
    #pragma unroll 1
    for (int k = 0; k < 7; k++) {
        const short8 qh0 = *(const short8*)&sQh[qb + k*32];
        const short8 ql0 = *(const short8*)&sQl[qb + k*32];
        const short8 qh1 = *(const short8*)&sQh[qb + 16*232 + k*32];
        const short8 ql1 = *(const short8*)&sQl[qb + 16*232 + k*32];
        #pragma unroll
        for (int t = 0; t < 4; t++) {
            const size_t kb = (size_t)((wv*4 + t)*16 + arow)*224 + k*32 + aq*8;
            const short8 bh = *(const short8*)&Kh[kb];
            const short8 bl = *(const short8*)&Kl[kb];
            acc[0][t] = __builtin_amdgcn_mfma_f32_16x16x32_bf16(qh0, bh, acc[0][t], 0, 0, 0);
            acc[0][t] = __builtin_amdgcn_mfma_f32_16x16x32_bf16(qh0, bl, acc[0][t], 0, 0, 0);
            acc[0][t] = __builtin_amdgcn_mfma_f32_16x16x32_bf16(ql0, bh, acc[0][t], 0, 0, 0);
            acc[1][t] = __builtin_amdgcn_mfma_f32_16x16x32_bf16(qh1, bh, acc[1][t], 0, 0, 0);
            acc[1][t] = __builtin_amdgcn_mfma_f32_16x16x32_bf16(qh1, bl, acc[1][t], 0, 0, 0);
            acc[1][t] = __builtin_amdgcn_mfma_f32_16x16x32_bf16(ql1, bh, acc[1][t], 0, 0, 0);
        }
    }

    float iv[2][4];
    #pragma unroll
    for (int g = 0; g < 2; g++) {
        #pragma unroll
        for (int r = 0; r < 4; r++) {
            float m = -1e30f;
            #pragma unroll
            for (int t = 0; t < 4; t++) {
                acc[g][t][r] *= T_SCALE;
                m = fmaxf(m, acc[g][t][r]);
            }
            m = fmaxf(m, __shfl_xor(m, 1, 64));
            m = fmaxf(m, __shfl_xor(m, 2, 64));
            m = fmaxf(m, __shfl_xor(m, 4, 64));
            m = fmaxf(m, __shfl_xor(m, 8, 64));
            if (arow == 0) sm_[wv][g*16 + aq*4 + r] = m;
        }
    }
    __syncthreads();
    #pragma unroll
    for (int g = 0; g < 2; g++) {
        #pragma unroll
        for (int r = 0; r < 4; r++) {
            const int row = g*16 + aq*4 + r;
            float M = sm_[0][row];
            #pragma unroll
            for (int w = 1; w < 8; w++) M = fmaxf(M, sm_[w][row]);
            float s = 0.f;
            #pragma unroll
            for (int t = 0; t < 4; t++) {
                const float e = __expf(acc[g][t][r] - M);
                acc[g][t][r] = e;
                s += e;
            }
            s += __shfl_xor(s, 1, 64);
            s += __shfl_xor(s, 2, 64);
            s += __shfl_xor(s, 4, 64);
            s += __shfl_xor(s, 8, 64);
            if (arow == 0) ss_[wv][row] = s;
        }
    }
    __syncthreads();
    #pragma unroll
    for (int g = 0; g < 2; g++) {
        #pragma unroll
        for (int r = 0; r < 4; r++) {
            const int row = g*16 + aq*4 + r;
            float s = ss_[0][row];
            #pragma unroll
            for (int w = 1; w < 8; w++) s += ss_[w][row];
            iv[g][r] = 1.0f / s;
        }
    }
    // all waves are past the QK phase (2 barriers above) — safe to overwrite sQ
    #pragma unroll
    for (int g = 0; g < 2; g++) {
        #pragma unroll
        for (int t = 0; t < 4; t++) {
            const int col = (wv*4 + t)*16 + arow;
            #pragma unroll
            for (int r = 0; r < 4; r++)
                pb[(g*16 + aq*4 + r)*520 + col] = f2bf(acc[g][t][r] * iv[g][r]);
        }
    }
    __syncthreads();

    const int nbase = (wv < 5) ? 2*wv : 10 + (wv - 5);
    const int ncnt  = (wv < 5) ? 2 : 1;
    f32x4 pacc[2][2];
    #pragma unroll
    for (int g = 0; g < 2; g++)
        #pragma unroll
        for (int t = 0; t < 2; t++) pacc[g][t] = (f32x4){0.f,0.f,0.f,0.f};

    for (int k0 = 0; k0 < NN; k0 += 32) {
        const short8 a0 = *(const short8*)&pb[arow*520 + k0 + aq*8];
        const short8 a1 = *(const short8*)&pb[(16 + arow)*520 + k0 + aq*8];
        #pragma unroll
        for (int t = 0; t < 2; t++) {
            if (t < ncnt) {
                const size_t vb = (size_t)((nbase+t)*16 + arow)*NN + k0 + aq*8;
                const short8 bh = *(const short8*)&Vh[vb];
                const short8 bl = *(const short8*)&Vl[vb];
                pacc[0][t] = __builtin_amdgcn_mfma_f32_16x16x32_bf16(a0, bh, pacc[0][t], 0, 0, 0);
                pacc[0][t] = __builtin_amdgcn_mfma_f32_16x16x32_bf16(a0, bl, pacc[0][t], 0, 0, 0);
                pacc[1][t] = __builtin_amdgcn_mfma_f32_16x16x32_bf16(a1, bh, pacc[1][t], 0, 0, 0);
                pacc[1][t] = __builtin_amdgcn_mfma_f32_16x16x32_bf16(a1, bl, pacc[1][t], 0, 0, 0);
            }
        }
    }

    #pragma unroll
    for (int t = 0; t < 2; t++) {
        if (t < ncnt) {
            const int col = (nbase+t)*16 + arow;
            #pragma unroll
            for (int g = 0; g < 2; g++) {
                #pragma unroll
                for (int r = 0; r < 4; r++) {
                    const int row = q0 + g*16 + aq*4 + r;
                    const short v = (col < DH) ? f2bf(pacc[g][t][r]) : (short)0;
                    cb[((size_t)b*NN + row)*224 + col] = v;
                }
            }
        }
    }
    if (wv == 7) {
        const int col = 208 + arow;
        #pragma unroll
        for (int g = 0; g < 2; g++) {
            #pragma unroll
            for (int r = 0; r < 4; r++) {
                const int row = q0 + g*16 + aq*4 + r;
                cb[((size_t)b*NN + row)*224 + col] = 0;
            }
        }
    }
}

// ---------------------------------------------------------------------------
// down v2 (512 thr, 128 nodes/block): halves per-node W staging traffic
// (was 26.6 KB x 14 per 64 nodes) and per-node barrier count. 8 waves x
// 16-row tiles; acc[13] = 52 VGPR < cap 128 @ (512,2). LDS ~44.5 KB.
// ---------------------------------------------------------------------------
__global__ __launch_bounds__(512, 2) void down_mfma(
    const short* __restrict__ hbH1, const short* __restrict__ hbH2,
    const short* __restrict__ cb1, const short* __restrict__ cb2,
    const int* __restrict__ deg1, const int* __restrict__ deg2,
    const short* __restrict__ WbTH, const short* __restrict__ WbTL,
    const float* __restrict__ degree_table,
    float* __restrict__ hsg1, float* __restrict__ hsg2, const int half)
{
    const int side = blockIdx.y;
    const short* X0 = side ? hbH2 : hbH1;
    const short* X1 = side ? cb2 : cb1;
    const int*   dgp = side ? deg2 : deg1;
    float* hsg = side ? hsg2 : hsg1;

    const int nl0 = blockIdx.x * 128;
    const int ng0 = half*HBN + nl0;
    const int b = ng0 >> 9;

    __shared__ short As[128*40];
    __shared__ short BsH[208*40];
    __shared__ short BsL[208*40];
    __shared__ float part[208];

    const int tid = threadIdx.x;
    const int wv = tid >> 6, lane = tid & 63;
    const int arow = lane & 15, aq = lane >> 4;

    if (tid < 208) part[tid] = 0.f;

    f32x4 acc[13];
    #pragma unroll
    for (int t = 0; t < 13; t++) acc[t] = (f32x4){0.f,0.f,0.f,0.f};

    const int sr = tid >> 2, sc = (tid & 3) * 8;

    for (int phase = 0; phase < 2; phase++) {
        const short* X = phase ? X1 : X0;
        for (int k0 = 0; k0 < 224; k0 += 32) {
            __syncthreads();
            *(short8*)&As[sr*40 + sc] =
                *(const short8*)&X[(size_t)(nl0+sr)*224 + k0 + sc];
            const int kkg = phase*224 + k0;
            #pragma unroll
            for (int pass = 0; pass < 2; pass++) {
                const int f = pass*512 + tid;
                if (f < 832) {
                    const int d = f >> 2, cc = (f & 3) * 8;
                    *(short8*)&BsH[d*40 + cc] = *(const short8*)&WbTH[(size_t)d*448 + kkg + cc];
                    *(short8*)&BsL[d*40 + cc] = *(const short8*)&WbTL[(size_t)d*448 + kkg + cc];
                }
            }
            __syncthreads();
            const short8 a = *(const short8*)&As[(16*wv + arow)*40 + aq*8];
            #pragma unroll
            for (int t = 0; t < 13; t++) {
                const short8 bh = *(const short8*)&BsH[(t*16 + arow)*40 + aq*8];
                const short8 bl = *(const short8*)&BsL[(t*16 + arow)*40 + aq*8];
                acc[t] = __builtin_amdgcn_mfma_f32_16x16x32_bf16(a, bh, acc[t], 0, 0, 0);
                acc[t] = __builtin_amdgcn_mfma_f32_16x16x32_bf16(a, bl, acc[t], 0, 0, 0);
            }
        }
    }
    __syncthreads();

    int dgc[4];
    #pragma unroll
    for (int r = 0; r < 4; r++) {
        int d = dgp[ng0 + 16*wv + aq*4 + r];
        dgc[r] = d > 199 ? 199 : d;
    }
    #pragma unroll
    for (int nt = 0; nt < 13; nt++) {
        const int col = nt*16 + arow;
        float s = 0.f;
        if (col < DH) {
            #pragma unroll
            for (int r = 0; r < 4; r++)
                s += fmaxf(acc[nt][r], 0.f) + degree_table[dgc[r]*DH + col];
        }
        s += __shfl_xor(s, 16, 64);
        s += __shfl_xor(s, 32, 64);
        if (lane < 16 && col < DH) atomicAdd(&part[col], s);
    }
    __syncthreads();
    if (tid < DH) unsafeAtomicAdd(&hsg[b*206 + tid], part[tid] * (1.0f/512.0f));
}

// ---------------------------------------------------------------------------
// Kernel 7: final MLP, one block per batch row (interaction means folded in)
// ---------------------------------------------------------------------------
__global__ __launch_bounds__(256) void mlp_kernel(
    const float* __restrict__ hsg1, const float* __restrict__ hsg2,
    const float* __restrict__ i1, const float* __restrict__ i2,
    const float* __restrict__ W_f1, const float* __restrict__ b_f1,
    const float* __restrict__ W_f2, const float* __restrict__ b_f2,
    const float* __restrict__ W_f3, const float* __restrict__ b_f3,
    const float* __restrict__ W_f4, const float* __restrict__ b_f4,
    float* __restrict__ out)
{
    const int b = blockIdx.x;
    __shared__ float x[618];
    __shared__ float y1[400];
    __shared__ float y2[200];
    __shared__ float y3[100];
    __shared__ float red[256];
    const int tid = threadIdx.x;

    // interaction means (folded inter_kernel); y2 used as scratch pre-layer2
    if (tid < 192) {
        const int j = tid % 6, seg = tid / 6;
        float s1 = 0.f, s2 = 0.f;
        for (int n = seg*16; n < seg*16 + 16; n++) {
            s1 += i1[(size_t)b*NN*DI + n*DI + j];
            s2 += i2[(size_t)b*NN*DI + n*DI + j];
        }
        red[tid] = s1;
        y2[tid] = s2;
    }
    __syncthreads();
    if (tid < 206) {
        float a, bb;
        if (tid < 200) {
            a = hsg1[b*206 + tid]; bb = hsg2[b*206 + tid];
        } else {
            const int j = tid - 200;
            float t1 = 0.f, t2 = 0.f;
            for (int sg = 0; sg < 32; sg++) { t1 += red[sg*6 + j]; t2 += y2[sg*6 + j]; }
            a = t1 * (1.0f/512.0f); bb = t2 * (1.0f/512.0f);
        }
        x[tid] = a; x[206 + tid] = bb; x[412 + tid] = a - bb;
    }
    __syncthreads();
    for (int c = tid; c < 400; c += 256) {
        float acc = b_f1[c];
        for (int k = 0; k < 618; k++) acc += x[k]*W_f1[(size_t)k*400 + c];
        y1[c] = fmaxf(acc, 0.0f);
    }
    __syncthreads();
    if (tid < 200) {
        float acc = b_f2[tid];
        for (int k = 0; k < 400; k++) acc += y1[k]*W_f2[k*200 + tid];
        y2[tid] = fmaxf(acc, 0.0f);
    }
    __syncthreads();
    if (tid < 100) {
        float acc = b_f3[tid];
        for (int k = 0; k < 200; k++) acc += y2[k]*W_f3[k*100 + tid];
        y3[tid] = fmaxf(acc, 0.0f);
    }
    __syncthreads();
    red[tid] = (tid < 100) ? y3[tid]*W_f4[tid] : 0.0f;
    __syncthreads();
    for (int s = 128; s > 0; s >>= 1) {
        if (tid < s) red[tid] += red[tid + s];
        __syncthreads();
    }
    if (tid == 0) out[b] = red[0] + b_f4[0];
}

// ---------------------------------------------------------------------------
extern "C" void kernel_launch(void* const* d_in, const int* in_sizes, int n_in,
                              void* d_out, int out_size, void* d_ws, size_t ws_size,
                              hipStream_t stream)
{
    const float* atom1  = (const float*)d_in[0];
    const float* atom2  = (const float*)d_in[1];
    const float* coords1= (const float*)d_in[2];
    const float* coords2= (const float*)d_in[3];
    const float* efeat1 = (const float*)d_in[4];
    const float* efeat2 = (const float*)d_in[5];
    const float* inter1 = (const float*)d_in[6];
    const float* inter2 = (const float*)d_in[7];
    const int*   esrc1  = (const int*)d_in[8];
    const int*   edst1  = (const int*)d_in[9];
    const int*   esrc2  = (const int*)d_in[10];
    const int*   edst2  = (const int*)d_in[11];
    const float* W_atom = (const float*)d_in[12];
    const float* W_edge = (const float*)d_in[13];
    const float* W_rbf  = (const float*)d_in[14];
    const float* b_rbf  = (const float*)d_in[15];
    const float* ln_g   = (const float*)d_in[16];
    const float* ln_b   = (const float*)d_in[17];
    const float* W_down = (const float*)d_in[18];
    const float* deg_tab= (const float*)d_in[19];
    const float* W_f1   = (const float*)d_in[20];
    const float* b_f1   = (const float*)d_in[21];
    const float* W_f2   = (const float*)d_in[22];
    const float* b_f2   = (const float*)d_in[23];
    const float* W_f3   = (const float*)d_in[24];
    const float* b_f3   = (const float*)d_in[25];
    const float* W_f4   = (const float*)d_in[26];
    const float* b_f4   = (const float*)d_in[27];
    float* out = (float*)d_out;

    // ---- workspace layout (~133 MB)
    float* ws = (float*)d_ws;
    const size_t HSZ = (size_t)BN*DH;              // per-side h floats
    float* h1  = ws;
    float* h2  = h1 + HSZ;
    // pool: max(feat 2*(EE+16)*32 shorts, bf16 pool 10*HB shorts)
    short* pool = (short*)(h2 + HSZ);
    const size_t FSZ = (size_t)(EE+16)*32;
    short* featH1 = pool;
    short* featH2 = featH1 + FSZ;
    const size_t HB = (size_t)32*NN*224;           // 3,670,016 shorts
    short* hbH1 = pool;           short* hbL1 = hbH1 + HB;
    short* hbH2 = hbL1 + HB;      short* hbL2 = hbH2 + HB;
    short* hTH1 = hbL2 + HB;      short* hTL1 = hTH1 + HB;
    short* hTH2 = hTL1 + HB;      short* hTL2 = hTH2 + HB;
    short* cb1  = hTL2 + HB;      short* cb2  = cb1 + HB;
    size_t pool_sz = 2*FSZ > 10*HB ? 2*FSZ : 10*HB;
    short* after = pool + pool_sz;
    short* WTH = after;                            // [208][32]
    short* WTL = WTH + 208*32;
    short* WbTH = WTL + 208*32;                    // [208][448]
    short* WbTL = WbTH + 208*448;
    float* hsg1 = (float*)(WbTL + 208*448);
    float* hsg2 = hsg1 + (size_t)BB*206;
    int* deg1 = (int*)(hsg2 + (size_t)BB*206);
    int* deg2 = deg1 + BN;
    int* start1 = deg2 + BN;                       // BN+1 entries
    int* start2 = start1 + (BN+1);
    int* cursor1 = start2 + (BN+1);                // unused (kept for layout)
    int* cursor2 = cursor1 + BN;
    int* rank1 = cursor2 + BN;
    int* rank2 = rank1 + EE;

    hipMemsetAsync(deg1, 0, 2*(size_t)BN*sizeof(int), stream);
    hipMemsetAsync(hsg1, 0, 2*(size_t)BB*206*sizeof(float), stream);

    node_kernel<<<dim3(BN/4, 2), 256, 0, stream>>>(
        atom1, atom2, W_atom, ln_g, ln_b, h1, h2);

    hist_kernel<<<EE/256, 256, 0, stream>>>(edst1, edst2, deg1, deg2,
                                            rank1, rank2);
    scan_kernel<<<2, 1024, 0, stream>>>(deg1, deg2, start1, start2);

    featgen_kernel<<<dim3(EE/256, 2), 256, 0, stream>>>(
        efeat1, efeat2, esrc1, esrc2, edst1, edst2, coords1, coords2,
        rank1, rank2, start1, start2, featH1, featH2);

    prep_wt_kernel<<<28, 256, 0, stream>>>(
        W_edge, W_rbf, b_rbf, WTH, WTL, featH1, featH2);

    gather_mfma<<<dim3(BN/16, 2), 256, 0, stream>>>(
        featH1, featH2, start1, start2, WTH, WTL, ln_g, ln_b, h1, h2);

    prep_w_kernel<<<(208*448 + 255)/256, 256, 0, stream>>>(W_down, WbTH, WbTL);

    for (int half = 0; half < 2; half++) {
        cvt_kernel<<<dim3(HBN/64, 2), 256, 0, stream>>>(
            h1, h2, half, hbH1, hbL1, hbH2, hbL2, hTH1, hTL1, hTH2, hTL2);
        // dir0: c1 = softmax_rows(h1@h2^T) @ h2
        attn_kernel<<<dim3(NN/32, 32), 512, 0, stream>>>(
            hbH1, hbL1, hbH2, hbL2, hTH2, hTL2, cb1);
        // dir1: c2 = softmax_rows(h2@h1^T) @ h1
        attn_kernel<<<dim3(NN/32, 32), 512, 0, stream>>>(
            hbH2, hbL2, hbH1, hbL1, hTH1, hTL1, cb2);
        down_mfma<<<dim3(HBN/128, 2), 512, 0, stream>>>(
            hbH1, hbH2, cb1, cb2, deg1, deg2, WbTH, WbTL, deg_tab,
            hsg1, hsg2, half);
    }

    mlp_kernel<<<BB, 256, 0, stream>>>(
        hsg1, hsg2, inter1, inter2,
        W_f1, b_f1, W_f2, b_f2, W_f3, b_f3, W_f4, b_f4, out);
}

// Round 8
// 891.135 us; speedup vs baseline: 1.5303x; 1.0419x over previous
//
#include <hip/hip_runtime.h>
#include <cstddef>
#include <cstdint>

// Problem constants
#define BB   64
#define NN   512
#define BN   (BB*NN)          // 32768
#define HBN  16384            // nodes per half
#define EE   524288
#define DA   70
#define DE   14
#define DH   200
#define DI   6
#define T_SCALE 0.07071067811865475f   // sqrt(1/200)

typedef __attribute__((ext_vector_type(8))) short short8;
typedef __attribute__((ext_vector_type(4))) float f32x4;

__device__ __forceinline__ short f2bf(float x) {
    union { float f; unsigned u; } v; v.f = x;
    const unsigned r = v.u + 0x7FFFu + ((v.u >> 16) & 1u);   // RNE
    return (short)(r >> 16);
}
__device__ __forceinline__ float bf2f(short s) {
    union { unsigned u; float f; } v;
    v.u = ((unsigned)(unsigned short)s) << 16;
    return v.f;
}

// 16-lane (row) sum via DPP — pure VALU, no DS pipe, no address VGPRs.
__device__ __forceinline__ float dpp16_sum(float x) {
    union { float f; int i; } a, b;
    a.f = x;
    b.i = __builtin_amdgcn_update_dpp(0, a.i, 0xB1, 0xF, 0xF, false); a.f += b.f;
    b.i = __builtin_amdgcn_update_dpp(0, a.i, 0x4E, 0xF, 0xF, false); a.f += b.f;
    b.i = __builtin_amdgcn_update_dpp(0, a.i, 0x141, 0xF, 0xF, false); a.f += b.f;
    b.i = __builtin_amdgcn_update_dpp(0, a.i, 0x140, 0xF, 0xF, false); a.f += b.f;
    return a.f;
}

// ---------------------------------------------------------------------------
// prologue: fused node(16/block) + hist + prep_w + prep_wt(+featpad).
// All four phases are mutually independent; block-range dispatch.
//   blocks [0,4096):    node — h = layernorm(relu(atom @ W_atom)), 16 nodes
//   blocks [4096,6144): hist — degree + arrival rank
//   blocks [6144,6508): prep_w — W_down -> WbTH/WbTL
//   blocks [6508,6536): prep_wt — WT hi/lo + feat 16-row pad zero
// node upgrade: 16 nodes/block amortizes the 56KB W_atom L2 re-read 4x
// (918 -> 230 MB L2 traffic). Per-node math bit-identical (same k order,
// same wave-LN reduction).
// ---------------------------------------------------------------------------
__global__ __launch_bounds__(256) void prologue_kernel(
    const float* __restrict__ atom1, const float* __restrict__ atom2,
    const float* __restrict__ W_atom,
    const float* __restrict__ ln_g, const float* __restrict__ ln_b,
    float* __restrict__ h1, float* __restrict__ h2,
    const int* __restrict__ edst1, const int* __restrict__ edst2,
    int* __restrict__ deg1, int* __restrict__ deg2,
    int* __restrict__ rank1, int* __restrict__ rank2,
    const float* __restrict__ W_edge, const float* __restrict__ W_rbf,
    const float* __restrict__ b_rbf,
    short* __restrict__ WTH, short* __restrict__ WTL,
    short* __restrict__ featH1, short* __restrict__ featH2,
    const float* __restrict__ W_down,
    short* __restrict__ WbTH, short* __restrict__ WbTL)
{
    const int bid = blockIdx.x;
    const int tid = threadIdx.x;

    if (bid < 4096) {
        // ---- node phase: 16 nodes per block
        const int side = bid >> 11;
        const float* atom = side ? atom2 : atom1;
        float* h = side ? h2 : h1;
        const int node0 = (bid & 2047) * 16;

        __shared__ float arow[16][DA];    // 4.4 KB
        __shared__ float vals[16][DH];    // 12.8 KB

        for (int i = tid; i < 16*DA; i += 256) {
            const int n = i / DA, k = i % DA;
            arow[n][k] = atom[(size_t)(node0+n)*DA + k];
        }
        __syncthreads();

        if (tid < DH) {
            float a[16];
            #pragma unroll
            for (int n = 0; n < 16; n++) a[n] = 0.f;
            for (int k = 0; k < DA; k++) {
                const float w = W_atom[k*DH + tid];
                #pragma unroll
                for (int n = 0; n < 16; n++) a[n] += arow[n][k]*w;
            }
            #pragma unroll
            for (int n = 0; n < 16; n++) vals[n][tid] = fmaxf(a[n], 0.f);
        }
        __syncthreads();

        const int wv = tid >> 6, lane = tid & 63;
        #pragma unroll 1
        for (int rr = 0; rr < 4; rr++) {
            const int n = rr*4 + wv;
            float v0 = vals[n][lane];
            float v1 = vals[n][64+lane];
            float v2 = vals[n][128+lane];
            float v3 = (lane < 8) ? vals[n][192+lane] : 0.0f;
            float s  = v0+v1+v2+v3;
            float s2 = v0*v0+v1*v1+v2*v2+v3*v3;
            #pragma unroll
            for (int off = 1; off < 64; off <<= 1) {
                s  += __shfl_xor(s,  off, 64);
                s2 += __shfl_xor(s2, off, 64);
            }
            const float mean = s * (1.0f/DH);
            const float var  = s2 * (1.0f/DH) - mean*mean;
            const float rstd = rsqrtf(var + 1e-5f);
            const size_t base = (size_t)(node0+n)*DH;
            h[base + lane]       = ln_g[lane]     *(v0-mean)*rstd + ln_b[lane];
            h[base + 64 + lane]  = ln_g[64+lane]  *(v1-mean)*rstd + ln_b[64+lane];
            h[base + 128 + lane] = ln_g[128+lane] *(v2-mean)*rstd + ln_b[128+lane];
            if (lane < 8)
                h[base + 192 + lane] = ln_g[192+lane]*(v3-mean)*rstd + ln_b[192+lane];
        }
        return;
    }

    if (bid < 6144) {
        // ---- hist phase
        const int e = (bid - 4096)*256 + tid;
        rank1[e] = atomicAdd(&deg1[edst1[e]], 1);
        rank2[e] = atomicAdd(&deg2[edst2[e]], 1);
        return;
    }

    if (bid < 6508) {
        // ---- prep_w phase
        const int idx = (bid - 6144)*256 + tid;
        if (idx >= 208*448) return;
        const int c = idx / 448, kk = idx - c*448;
        float v = 0.f;
        if (c < 200) {
            if (kk < 200) v = W_down[(size_t)kk*DH + c];
            else if (kk >= 224 && kk < 424) v = W_down[(size_t)(200 + kk - 224)*DH + c];
        }
        const short hi = f2bf(v);
        WbTH[idx] = hi;
        WbTL[idx] = f2bf(v - bf2f(hi));
        return;
    }

    // ---- prep_wt phase (26 blocks WT, 2 blocks feat pad)
    {
        const int pb = bid - 6508;
        if (pb >= 26) {
            short* f = (pb == 26) ? featH1 : featH2;
            f[(size_t)EE*32 + tid] = 0;
            f[(size_t)EE*32 + 256 + tid] = 0;
            return;
        }
        const int idx = pb*256 + tid;
        const int c = idx >> 5, k = idx & 31;
        float v = 0.f;
        if (c < 100) {
            if (k < 14) v = W_edge[k*100 + c];
        } else if (c < 200) {
            const int cc = c - 100;
            if (k >= 14 && k < 30) v = W_rbf[(k-14)*100 + cc];
            else if (k == 30) v = b_rbf[cc];
        }
        const short hi = f2bf(v);
        WTH[idx] = hi;
        WTL[idx] = f2bf(v - bf2f(hi));
    }
}

__global__ __launch_bounds__(1024) void scan_kernel(
    const int* __restrict__ deg1, const int* __restrict__ deg2,
    int* __restrict__ start1, int* __restrict__ start2)
{
    const int side = blockIdx.x;
    const int* deg   = side ? deg2 : deg1;
    int* start  = side ? start2 : start1;

    __shared__ int part[1024];
    const int t = threadIdx.x;
    const int base = t * 32;
    int local[32];
    int sum = 0;
    #pragma unroll
    for (int i = 0; i < 8; i++) {        // int4 vector loads (16B/lane)
        const int4 v = *(const int4*)&deg[base + i*4];
        local[4*i+0] = v.x; local[4*i+1] = v.y;
        local[4*i+2] = v.z; local[4*i+3] = v.w;
        sum += v.x + v.y + v.z + v.w;
    }
    part[t] = sum;
    __syncthreads();
    for (int off = 1; off < 1024; off <<= 1) {
        int v = (t >= off) ? part[t-off] : 0;
        __syncthreads();
        part[t] += v;
        __syncthreads();
    }
    int run = part[t] - sum;   // exclusive
    #pragma unroll
    for (int i = 0; i < 32; i++) {
        start[base+i] = run;
        run += local[i];
    }
    if (t == 1023) start[BN] = run;   // sentinel == EE
}

// ---------------------------------------------------------------------------
// featgen: per-edge feature row -> featH[start[dst]+rank[e]][32] bf16
//   k 0..13 = ef, 14..29 = rbf, 30 = 1.0 (bias hook), 31 = 0
// ---------------------------------------------------------------------------
__global__ __launch_bounds__(256) void featgen_kernel(
    const float* __restrict__ efeat1, const float* __restrict__ efeat2,
    const int* __restrict__ esrc1, const int* __restrict__ esrc2,
    const int* __restrict__ edst1, const int* __restrict__ edst2,
    const float* __restrict__ coords1, const float* __restrict__ coords2,
    const int* __restrict__ rank1, const int* __restrict__ rank2,
    const int* __restrict__ start1, const int* __restrict__ start2,
    short* __restrict__ featH1, short* __restrict__ featH2)
{
    const int side = blockIdx.y;
    const float* ef     = side ? efeat2  : efeat1;
    const int*   esrc   = side ? esrc2   : esrc1;
    const int*   edst   = side ? edst2   : edst1;
    const float* coords = side ? coords2 : coords1;
    const int*   rank   = side ? rank2   : rank1;
    const int*   start  = side ? start2  : start1;
    short* featH = side ? featH2 : featH1;

    const int e = blockIdx.x*256 + threadIdx.x;
    const int src = esrc[e], dst = edst[e];

    short f[32];
    #pragma unroll
    for (int k = 0; k < 14; k++) f[k] = f2bf(ef[(size_t)e*DE + k]);

    const float dx = coords[src*3+0] - coords[dst*3+0];
    const float dy = coords[src*3+1] - coords[dst*3+1];
    const float dz = coords[src*3+2] - coords[dst*3+2];
    const float dist = sqrtf(dx*dx + dy*dy + dz*dz + 1e-12f);
    #pragma unroll
    for (int k = 0; k < 16; k++) {
        const float t = 3.2f*dist - 1.0666666667f*(float)k;
        f[14+k] = f2bf(__expf(-t*t));
    }
    f[30] = f2bf(1.0f);
    f[31] = 0;

    const int slot = start[dst] + rank[e];
    short* out = featH + (size_t)slot*32;
    #pragma unroll
    for (int q = 0; q < 4; q++)
        *(short8*)&out[q*8] = *(short8*)&f[q*8];
}

// ---------------------------------------------------------------------------
// gather_mfma v7 (unchanged): 132-138 us, VALU-dominated (51%), VALU:MFMA
// 4.3:1 matches static op count — structural floor for this formulation.
// ---------------------------------------------------------------------------
__global__ __launch_bounds__(256, 2) void gather_mfma(
    const short* __restrict__ featH1, const short* __restrict__ featH2,
    const int* __restrict__ start1, const int* __restrict__ start2,
    const short* __restrict__ WTH, const short* __restrict__ WTL,
    const float* __restrict__ ln_g, const float* __restrict__ ln_b,
    float* __restrict__ h1, float* __restrict__ h2)
{
    __shared__ short sWH[208*40];    // 16.6 KB, stride-40 (80B) rows
    __shared__ short sWL[208*40];    // 16.6 KB
    __shared__ float plane[4][216];

    const int tid = threadIdx.x;
    const int wv = tid >> 6, lane = tid & 63;
    const int arow = lane & 15, aq = lane >> 4;

    // stage W once per block (832 short8 per array)
    for (int f = tid; f < 832; f += 256) {
        const int d = f >> 2, cc = (f & 3) * 8;
        *(short8*)&sWH[d*40 + cc] = *(const short8*)&WTH[f*8];
        *(short8*)&sWL[d*40 + cc] = *(const short8*)&WTL[f*8];
    }
    __syncthreads();

    const int side = blockIdx.y;
    const short* feat = side ? featH2 : featH1;
    const int*  start = side ? start2 : start1;
    float* h = side ? h2 : h1;

    const int c0 = blockIdx.x*16 + wv*4;     // wave's first node (of 4)

    // hoist ln params (lane-mapped)
    const float g0 = ln_g[lane],      bb0 = ln_b[lane];
    const float g1 = ln_g[64+lane],   bb1 = ln_b[64+lane];
    const float g2 = ln_g[128+lane],  bb2 = ln_b[128+lane];
    const float g3 = (lane < 8) ? ln_g[192+lane] : 0.f;
    const float bb3 = (lane < 8) ? ln_b[192+lane] : 0.f;

    // 5 start values for the 4 nodes, one load, then readlane
    const int sidx = (lane < 5) ? lane : 4;
    const int sv = start[c0 + sidx];

    const int lb = arow*40 + aq*8;           // LDS element offset in a W tile

    #pragma unroll 1
    for (int ni = 0; ni < 4; ni++) {
        const int st = __builtin_amdgcn_readlane(sv, ni);
        const int en = __builtin_amdgcn_readlane(sv, ni + 1);
        const int dg = en - st;
        const int node = c0 + ni;
        const size_t hbase = (size_t)node * DH;

        // hoist h RMW loads (consumed at node end, hidden under tiles)
        const float hv0 = h[hbase + lane];
        const float hv1 = h[hbase + 64 + lane];
        const float hv2 = h[hbase + 128 + lane];
        const float hv3 = (lane < 8) ? h[hbase + 192 + lane] : 0.f;

        float colacc[13];
        #pragma unroll
        for (int nt = 0; nt < 13; nt++) colacc[nt] = 0.f;
        float musum = 0.f;

        short8 aC = *(const short8*)&feat[(size_t)(st + arow)*32 + aq*8];

        for (int t0 = 0; t0 < dg; t0 += 16) {
            // prefetch next tile; overshoot lands in next node's rows or the
            // zeroed 16-row pad (start[BN]=EE sentinel) — discarded if unused
            const short8 aN = *(const short8*)&feat[(size_t)(st + t0 + 16 + arow)*32 + aq*8];

            f32x4 acc[13];
            #pragma unroll
            for (int nt = 0; nt < 13; nt++) {
                const short8 whv = *(const short8*)&sWH[nt*640 + lb];
                const short8 wlv = *(const short8*)&sWL[nt*640 + lb];
                f32x4 z = (f32x4){0.f,0.f,0.f,0.f};
                z = __builtin_amdgcn_mfma_f32_16x16x32_bf16(aC, whv, z, 0, 0, 0);
                z = __builtin_amdgcn_mfma_f32_16x16x32_bf16(aC, wlv, z, 0, 0, 0);
                acc[nt] = z;
            }
            // relu + per-row (per-edge) stats; row = t0 + aq*4 + r
            float sr[4] = {0.f,0.f,0.f,0.f}, s2r[4] = {0.f,0.f,0.f,0.f};
            #pragma unroll
            for (int nt = 0; nt < 13; nt++) {
                #pragma unroll
                for (int r = 0; r < 4; r++) {
                    const float v = fmaxf(acc[nt][r], 0.f);
                    acc[nt][r] = v;
                    sr[r] += v; s2r[r] += v*v;
                }
            }
            // 16-lane sum across arow via DPP (VALU-only)
            #pragma unroll
            for (int r = 0; r < 4; r++) {
                sr[r]  = dpp16_sum(sr[r]);
                s2r[r] = dpp16_sum(s2r[r]);
            }
            #pragma unroll
            for (int r = 0; r < 4; r++) {
                const bool valid = (t0 + aq*4 + r) < dg;
                const float mean = sr[r] * (1.0f/DH);
                const float var  = s2r[r] * (1.0f/DH) - mean*mean;
                const float rs   = rsqrtf(var + 1e-5f);
                const float rstd = valid ? rs : 0.f;
                musum += valid ? mean*rs : 0.f;
                #pragma unroll
                for (int nt = 0; nt < 13; nt++)
                    colacc[nt] += rstd*acc[nt][r];
            }
            aC = aN;
        }

        // reduce over the 4 aq groups (rows partition)
        #pragma unroll
        for (int nt = 0; nt < 13; nt++) {
            colacc[nt] += __shfl_xor(colacc[nt], 16, 64);
            colacc[nt] += __shfl_xor(colacc[nt], 32, 64);
        }
        musum += __shfl_xor(musum, 16, 64);
        musum += __shfl_xor(musum, 32, 64);

        if (aq == 0) {
            #pragma unroll
            for (int nt = 0; nt < 13; nt++)
                plane[wv][nt*16 + arow] = colacc[nt];
        }
        // wave-internal LDS producer/consumer: DS pipe is in-order per wave —
        // no barrier (and the next node's writes issue after these reads)

        const float dgf = (float)dg;
        h[hbase + lane]       = hv0 + g0*(plane[wv][lane]     - musum) + dgf*bb0;
        h[hbase + 64 + lane]  = hv1 + g1*(plane[wv][64+lane]  - musum) + dgf*bb1;
        h[hbase + 128 + lane] = hv2 + g2*(plane[wv][128+lane] - musum) + dgf*bb2;
        if (lane < 8)
            h[hbase + 192 + lane] = hv3 + g3*(plane[wv][192+lane] - musum) + dgf*bb3;
    }
}

// ---------------------------------------------------------------------------
// cvt (per half): h fp32 -> hb hi/lo [16384][224] rows + hbT hi/lo [32][224][512]
// ---------------------------------------------------------------------------
__global__ __launch_bounds__(256) void cvt_kernel(
    const float* __restrict__ h1, const float* __restrict__ h2, const int half,
    short* __restrict__ hbH1, short* __restrict__ hbL1,
    short* __restrict__ hbH2, short* __restrict__ hbL2,
    short* __restrict__ hTH1, short* __restrict__ hTL1,
    short* __restrict__ hTH2, short* __restrict__ hTL2)
{
    const int side = blockIdx.y;
    const float* h = side ? h2 : h1;
    short* hbH = side ? hbH2 : hbH1;
    short* hbL = side ? hbL2 : hbL1;
    short* hTH = side ? hTH2 : hTH1;
    short* hTL = side ? hTL2 : hTL1;

    const int nl0 = blockIdx.x * 64;          // local node
    const int bl = nl0 >> 9, m0 = nl0 & 511;
    const int ng0 = half*HBN + nl0;

    __shared__ short tH[64][226];
    __shared__ short tL[64][226];
    const int tid = threadIdx.x;
    for (int i = tid; i < 64*224; i += 256) {
        const int r = i / 224, c = i - r*224;
        const float v = (c < DH) ? h[(size_t)(ng0+r)*DH + c] : 0.f;
        const short hi = f2bf(v);
        const short lo = f2bf(v - bf2f(hi));
        tH[r][c] = hi; tL[r][c] = lo;
        hbH[(size_t)(nl0+r)*224 + c] = hi;
        hbL[(size_t)(nl0+r)*224 + c] = lo;
    }
    __syncthreads();
    for (int i = tid; i < 224*64; i += 256) {
        const int c = i >> 6, m = i & 63;
        const size_t o = ((size_t)bl*224 + c)*NN + m0 + m;
        hTH[o] = tH[m][c];
        hTL[o] = tL[m][c];
    }
}

// ---------------------------------------------------------------------------
// Fused attention v7: both directions in ONE dispatch (1024 blocks, 512 thr).
// Block id mapping: [xcd:3][qb:4][dir:1][b01:1][r:1] — XCD k concurrently
// holds 2 batches x BOTH dirs (working set 2 x 1.8MB <= 4MB L2), so a
// batch's hb/hT arrays are served once per XCD for both directions.
// Body identical to v6 (bit-identical numerics).
// ---------------------------------------------------------------------------
__global__ __launch_bounds__(512, 2) void attn_kernel(
    const short* __restrict__ hbH1, const short* __restrict__ hbL1,
    const short* __restrict__ hbH2, const short* __restrict__ hbL2,
    const short* __restrict__ hTH1, const short* __restrict__ hTL1,
    const short* __restrict__ hTH2, const short* __restrict__ hTL2,
    short* __restrict__ cb1, short* __restrict__ cb2)
{
    const int id  = blockIdx.x;                // 0..1023
    const int xcd = id & 7, m = id >> 3;       // m 0..127
    const int r   = m >> 6;
    const int b01 = (m >> 5) & 1;
    const int dir = (m >> 4) & 1;
    const int qb  = m & 15;
    const int b   = xcd*4 + r*2 + b01;         // half-local batch 0..31
    const int q0  = qb << 5;                   // 32 q-rows

    const short *Qh, *Ql, *Kh, *Kl, *Vh, *Vl;
    short* cb;
    if (dir == 0) {
        Qh = hbH1 + (size_t)b*NN*224;  Ql = hbL1 + (size_t)b*NN*224;
        Kh = hbH2 + (size_t)b*NN*224;  Kl = hbL2 + (size_t)b*NN*224;
        Vh = hTH2 + (size_t)b*224*NN;  Vl = hTL2 + (size_t)b*224*NN;
        cb = cb1;
    } else {
        Qh = hbH2 + (size_t)b*NN*224;  Ql = hbL2 + (size_t)b*NN*224;
        Kh = hbH1 + (size_t)b*NN*224;  Kl = hbL1 + (size_t)b*NN*224;
        Vh = hTH1 + (size_t)b*224*NN;  Vl = hTL1 + (size_t)b*224*NN;
        cb = cb2;
    }

    __shared__ short smem[32*520];            // 33.3 KB: pb, aliases sQ
    short* sQh = smem;                        // [32][232] = 7424 shorts
    short* sQl = smem + 7424;                 // [32][232]
    short* pb  = smem;                        // [32][520]
    __shared__ float sm_[8][32];
    __shared__ float ss_[8][32];

    const int tid = threadIdx.x;
    const int wv = tid >> 6, lane = tid & 63;
    const int arow = lane & 15, aq = lane >> 4;

    // stage Q (32 rows x 224, hi/lo) cooperatively
    for (int i = tid; i < 896; i += 512) {
        const int rr = i / 28, c = (i - rr*28) * 8;
        *(short8*)&sQh[rr*232 + c] = *(const short8*)&Qh[(size_t)(q0 + rr)*224 + c];
        *(short8*)&sQl[rr*232 + c] = *(const short8*)&Ql[(size_t)(q0 + rr)*224 + c];
    }
    __syncthreads();

    f32x4 acc[2][4];
    #pragma unroll
    for (int g = 0; g < 2; g++)
        #pragma unroll
        for (int t = 0; t < 4; t++) acc[g][t] = (f32x4){0.f,0.f,0.f,0.f};

    const int qb_off = arow*232 + aq*8;
    #pragma unroll 1
    for (int k = 0; k < 7; k++) {
        const short8 qh0 = *(const short8*)&sQh[qb_off + k*32];
        const short8 ql0 = *(const short8*)&sQl[qb_off + k*32];
        const short8 qh1 = *(const short8*)&sQh[qb_off + 16*232 + k*32];
        const short8 ql1 = *(const short8*)&sQl[qb_off + 16*232 + k*32];
        #pragma unroll
        for (int t = 0; t < 4; t++) {
            const size_t kb = (size_t)((wv*4 + t)*16 + arow)*224 + k*32 + aq*8;
            const short8 bh = *(const short8*)&Kh[kb];
            const short8 bl = *(const short8*)&Kl[kb];
            acc[0][t] = __builtin_amdgcn_mfma_f32_16x16x32_bf16(qh0, bh, acc[0][t], 0, 0, 0);
            acc[0][t] = __builtin_amdgcn_mfma_f32_16x16x32_bf16(qh0, bl, acc[0][t], 0, 0, 0);
            acc[0][t] = __builtin_amdgcn_mfma_f32_16x16x32_bf16(ql0, bh, acc[0][t], 0, 0, 0);
            acc[1][t] = __builtin_amdgcn_mfma_f32_16x16x32_bf16(qh1, bh, acc[1][t], 0, 0, 0);
            acc[1][t] = __builtin_amdgcn_mfma_f32_16x16x32_bf16(qh1, bl, acc[1][t], 0, 0, 0);
            acc[1][t] = __builtin_amdgcn_mfma_f32_16x16x32_bf16(ql1, bh, acc[1][t], 0, 0, 0);
        }
    }

    float iv[2][4];
    #pragma unroll
    for (int g = 0; g < 2; g++) {
        #pragma unroll
        for (int r2 = 0; r2 < 4; r2++) {
            float mx = -1e30f;
            #pragma unroll
            for (int t = 0; t < 4; t++) {
                acc[g][t][r2] *= T_SCALE;
                mx = fmaxf(mx, acc[g][t][r2]);
            }
            mx = fmaxf(mx, __shfl_xor(mx, 1, 64));
            mx = fmaxf(mx, __shfl_xor(mx, 2, 64));
            mx = fmaxf(mx, __shfl_xor(mx, 4, 64));
            mx = fmaxf(mx, __shfl_xor(mx, 8, 64));
            if (arow == 0) sm_[wv][g*16 + aq*4 + r2] = mx;
        }
    }
    __syncthreads();
    #pragma unroll
    for (int g = 0; g < 2; g++) {
        #pragma unroll
        for (int r2 = 0; r2 < 4; r2++) {
            const int row = g*16 + aq*4 + r2;
            float M = sm_[0][row];
            #pragma unroll
            for (int w = 1; w < 8; w++) M = fmaxf(M, sm_[w][row]);
            float s = 0.f;
            #pragma unroll
            for (int t = 0; t < 4; t++) {
                const float e = __expf(acc[g][t][r2] - M);
                acc[g][t][r2] = e;
                s += e;
            }
            s += __shfl_xor(s, 1, 64);
            s += __shfl_xor(s, 2, 64);
            s += __shfl_xor(s, 4, 64);
            s += __shfl_xor(s, 8, 64);
            if (arow == 0) ss_[wv][row] = s;
        }
    }
    __syncthreads();
    #pragma unroll
    for (int g = 0; g < 2; g++) {
        #pragma unroll
        for (int r2 = 0; r2 < 4; r2++) {
            const int row = g*16 + aq*4 + r2;
            float s = ss_[0][row];
            #pragma unroll
            for (int w = 1; w < 8; w++) s += ss_[w][row];
            iv[g][r2] = 1.0f / s;
        }
    }
    // all waves are past the QK phase (2 barriers above) — safe to overwrite sQ
    #pragma unroll
    for (int g = 0; g < 2; g++) {
        #pragma unroll
        for (int t = 0; t < 4; t++) {
            const int col = (wv*4 + t)*16 + arow;
            #pragma unroll
            for (int r2 = 0; r2 < 4; r2++)
                pb[(g*16 + aq*4 + r2)*520 + col] = f2bf(acc[g][t][r2] * iv[g][r2]);
        }
    }
    __syncthreads();

    const int nbase = (wv < 5) ? 2*wv : 10 + (wv - 5);
    const int ncnt  = (wv < 5) ? 2 : 1;
    f32x4 pacc[2][2];
    #pragma unroll
    for (int g = 0; g < 2; g++)
        #pragma unroll
        for (int t = 0; t < 2; t++) pacc[g][t] = (f32x4){0.f,0.f,0.f,0.f};

    for (int k0 = 0; k0 < NN; k0 += 32) {
        const short8 a0 = *(const short8*)&pb[arow*520 + k0 + aq*8];
        const short8 a1 = *(const short8*)&pb[(16 + arow)*520 + k0 + aq*8];
        #pragma unroll
        for (int t = 0; t < 2; t++) {
            if (t < ncnt) {
                const size_t vb = (size_t)((nbase+t)*16 + arow)*NN + k0 + aq*8;
                const short8 bh = *(const short8*)&Vh[vb];
                const short8 bl = *(const short8*)&Vl[vb];
                pacc[0][t] = __builtin_amdgcn_mfma_f32_16x16x32_bf16(a0, bh, pacc[0][t], 0, 0, 0);
                pacc[0][t] = __builtin_amdgcn_mfma_f32_16x16x32_bf16(a0, bl, pacc[0][t], 0, 0, 0);
                pacc[1][t] = __builtin_amdgcn_mfma_f32_16x16x32_bf16(a1, bh, pacc[1][t], 0, 0, 0);
                pacc[1][t] = __builtin_amdgcn_mfma_f32_16x16x32_bf16(a1, bl, pacc[1][t], 0, 0, 0);
            }
        }
    }

    #pragma unroll
    for (int t = 0; t < 2; t++) {
        if (t < ncnt) {
            const int col = (nbase+t)*16 + arow;
            #pragma unroll
            for (int g = 0; g < 2; g++) {
                #pragma unroll
                for (int r2 = 0; r2 < 4; r2++) {
                    const int row = q0 + g*16 + aq*4 + r2;
                    const short v = (col < DH) ? f2bf(pacc[g][t][r2]) : (short)0;
                    cb[((size_t)b*NN + row)*224 + col] = v;
                }
            }
        }
    }
    if (wv == 7) {
        const int col = 208 + arow;
        #pragma unroll
        for (int g = 0; g < 2; g++) {
            #pragma unroll
            for (int r2 = 0; r2 < 4; r2++) {
                const int row = q0 + g*16 + aq*4 + r2;
                cb[((size_t)b*NN + row)*224 + col] = 0;
            }
        }
    }
}

// ---------------------------------------------------------------------------
// down v2 (512 thr, 128 nodes/block) — unchanged from round 7.
// ---------------------------------------------------------------------------
__global__ __launch_bounds__(512, 2) void down_mfma(
    const short* __restrict__ hbH1, const short* __restrict__ hbH2,
    const short* __restrict__ cb1, const short* __restrict__ cb2,
    const int* __restrict__ deg1, const int* __restrict__ deg2,
    const short* __restrict__ WbTH, const short* __restrict__ WbTL,
    const float* __restrict__ degree_table,
    float* __restrict__ hsg1, float* __restrict__ hsg2, const int half)
{
    const int side = blockIdx.y;
    const short* X0 = side ? hbH2 : hbH1;
    const short* X1 = side ? cb2 : cb1;
    const int*   dgp = side ? deg2 : deg1;
    float* hsg = side ? hsg2 : hsg1;

    const int nl0 = blockIdx.x * 128;
    const int ng0 = half*HBN + nl0;
    const int b = ng0 >> 9;

    __shared__ short As[128*40];
    __shared__ short BsH[208*40];
    __shared__ short BsL[208*40];
    __shared__ float part[208];

    const int tid = threadIdx.x;
    const int wv = tid >> 6, lane = tid & 63;
    const int arow = lane & 15, aq = lane >> 4;

    if (tid < 208) part[tid] = 0.f;

    f32x4 acc[13];
    #pragma unroll
    for (int t = 0; t < 13; t++) acc[t] = (f32x4){0.f,0.f,0.f,0.f};

    const int sr = tid >> 2, sc = (tid & 3) * 8;

    for (int phase = 0; phase < 2; phase++) {
        const short* X = phase ? X1 : X0;
        for (int k0 = 0; k0 < 224; k0 += 32) {
            __syncthreads();
            *(short8*)&As[sr*40 + sc] =
                *(const short8*)&X[(size_t)(nl0+sr)*224 + k0 + sc];
            const int kkg = phase*224 + k0;
            #pragma unroll
            for (int pass = 0; pass < 2; pass++) {
                const int f = pass*512 + tid;
                if (f < 832) {
                    const int d = f >> 2, cc = (f & 3) * 8;
                    *(short8*)&BsH[d*40 + cc] = *(const short8*)&WbTH[(size_t)d*448 + kkg + cc];
                    *(short8*)&BsL[d*40 + cc] = *(const short8*)&WbTL[(size_t)d*448 + kkg + cc];
                }
            }
            __syncthreads();
            const short8 a = *(const short8*)&As[(16*wv + arow)*40 + aq*8];
            #pragma unroll
            for (int t = 0; t < 13; t++) {
                const short8 bh = *(const short8*)&BsH[(t*16 + arow)*40 + aq*8];
                const short8 bl = *(const short8*)&BsL[(t*16 + arow)*40 + aq*8];
                acc[t] = __builtin_amdgcn_mfma_f32_16x16x32_bf16(a, bh, acc[t], 0, 0, 0);
                acc[t] = __builtin_amdgcn_mfma_f32_16x16x32_bf16(a, bl, acc[t], 0, 0, 0);
            }
        }
    }
    __syncthreads();

    int dgc[4];
    #pragma unroll
    for (int r = 0; r < 4; r++) {
        int d = dgp[ng0 + 16*wv + aq*4 + r];
        dgc[r] = d > 199 ? 199 : d;
    }
    #pragma unroll
    for (int nt = 0; nt < 13; nt++) {
        const int col = nt*16 + arow;
        float s = 0.f;
        if (col < DH) {
            #pragma unroll
            for (int r = 0; r < 4; r++)
                s += fmaxf(acc[nt][r], 0.f) + degree_table[dgc[r]*DH + col];
        }
        s += __shfl_xor(s, 16, 64);
        s += __shfl_xor(s, 32, 64);
        if (lane < 16 && col < DH) atomicAdd(&part[col], s);
    }
    __syncthreads();
    if (tid < DH) unsafeAtomicAdd(&hsg[b*206 + tid], part[tid] * (1.0f/512.0f));
}

// ---------------------------------------------------------------------------
// Kernel 7: final MLP, one block per batch row (interaction means folded in)
// ---------------------------------------------------------------------------
__global__ __launch_bounds__(256) void mlp_kernel(
    const float* __restrict__ hsg1, const float* __restrict__ hsg2,
    const float* __restrict__ i1, const float* __restrict__ i2,
    const float* __restrict__ W_f1, const float* __restrict__ b_f1,
    const float* __restrict__ W_f2, const float* __restrict__ b_f2,
    const float* __restrict__ W_f3, const float* __restrict__ b_f3,
    const float* __restrict__ W_f4, const float* __restrict__ b_f4,
    float* __restrict__ out)
{
    const int b = blockIdx.x;
    __shared__ float x[618];
    __shared__ float y1[400];
    __shared__ float y2[200];
    __shared__ float y3[100];
    __shared__ float red[256];
    const int tid = threadIdx.x;

    // interaction means (folded inter_kernel); y2 used as scratch pre-layer2
    if (tid < 192) {
        const int j = tid % 6, seg = tid / 6;
        float s1 = 0.f, s2 = 0.f;
        for (int n = seg*16; n < seg*16 + 16; n++) {
            s1 += i1[(size_t)b*NN*DI + n*DI + j];
            s2 += i2[(size_t)b*NN*DI + n*DI + j];
        }
        red[tid] = s1;
        y2[tid] = s2;
    }
    __syncthreads();
    if (tid < 206) {
        float a, bb;
        if (tid < 200) {
            a = hsg1[b*206 + tid]; bb = hsg2[b*206 + tid];
        } else {
            const int j = tid - 200;
            float t1 = 0.f, t2 = 0.f;
            for (int sg = 0; sg < 32; sg++) { t1 += red[sg*6 + j]; t2 += y2[sg*6 + j]; }
            a = t1 * (1.0f/512.0f); bb = t2 * (1.0f/512.0f);
        }
        x[tid] = a; x[206 + tid] = bb; x[412 + tid] = a - bb;
    }
    __syncthreads();
    for (int c = tid; c < 400; c += 256) {
        float acc = b_f1[c];
        for (int k = 0; k < 618; k++) acc += x[k]*W_f1[(size_t)k*400 + c];
        y1[c] = fmaxf(acc, 0.0f);
    }
    __syncthreads();
    if (tid < 200) {
        float acc = b_f2[tid];
        for (int k = 0; k < 400; k++) acc += y1[k]*W_f2[k*200 + tid];
        y2[tid] = fmaxf(acc, 0.0f);
    }
    __syncthreads();
    if (tid < 100) {
        float acc = b_f3[tid];
        for (int k = 0; k < 200; k++) acc += y2[k]*W_f3[k*100 + tid];
        y3[tid] = fmaxf(acc, 0.0f);
    }
    __syncthreads();
    red[tid] = (tid < 100) ? y3[tid]*W_f4[tid] : 0.0f;
    __syncthreads();
    for (int s = 128; s > 0; s >>= 1) {
        if (tid < s) red[tid] += red[tid + s];
        __syncthreads();
    }
    if (tid == 0) out[b] = red[0] + b_f4[0];
}

// ---------------------------------------------------------------------------
extern "C" void kernel_launch(void* const* d_in, const int* in_sizes, int n_in,
                              void* d_out, int out_size, void* d_ws, size_t ws_size,
                              hipStream_t stream)
{
    const float* atom1  = (const float*)d_in[0];
    const float* atom2  = (const float*)d_in[1];
    const float* coords1= (const float*)d_in[2];
    const float* coords2= (const float*)d_in[3];
    const float* efeat1 = (const float*)d_in[4];
    const float* efeat2 = (const float*)d_in[5];
    const float* inter1 = (const float*)d_in[6];
    const float* inter2 = (const float*)d_in[7];
    const int*   esrc1  = (const int*)d_in[8];
    const int*   edst1  = (const int*)d_in[9];
    const int*   esrc2  = (const int*)d_in[10];
    const int*   edst2  = (const int*)d_in[11];
    const float* W_atom = (const float*)d_in[12];
    const float* W_edge = (const float*)d_in[13];
    const float* W_rbf  = (const float*)d_in[14];
    const float* b_rbf  = (const float*)d_in[15];
    const float* ln_g   = (const float*)d_in[16];
    const float* ln_b   = (const float*)d_in[17];
    const float* W_down = (const float*)d_in[18];
    const float* deg_tab= (const float*)d_in[19];
    const float* W_f1   = (const float*)d_in[20];
    const float* b_f1   = (const float*)d_in[21];
    const float* W_f2   = (const float*)d_in[22];
    const float* b_f2   = (const float*)d_in[23];
    const float* W_f3   = (const float*)d_in[24];
    const float* b_f3   = (const float*)d_in[25];
    const float* W_f4   = (const float*)d_in[26];
    const float* b_f4   = (const float*)d_in[27];
    float* out = (float*)d_out;

    // ---- workspace layout (~133 MB)
    float* ws = (float*)d_ws;
    const size_t HSZ = (size_t)BN*DH;              // per-side h floats
    float* h1  = ws;
    float* h2  = h1 + HSZ;
    // pool: max(feat 2*(EE+16)*32 shorts, bf16 pool 10*HB shorts)
    short* pool = (short*)(h2 + HSZ);
    const size_t FSZ = (size_t)(EE+16)*32;
    short* featH1 = pool;
    short* featH2 = featH1 + FSZ;
    const size_t HB = (size_t)32*NN*224;           // 3,670,016 shorts
    short* hbH1 = pool;           short* hbL1 = hbH1 + HB;
    short* hbH2 = hbL1 + HB;      short* hbL2 = hbH2 + HB;
    short* hTH1 = hbL2 + HB;      short* hTL1 = hTH1 + HB;
    short* hTH2 = hTL1 + HB;      short* hTL2 = hTH2 + HB;
    short* cb1  = hTL2 + HB;      short* cb2  = cb1 + HB;
    size_t pool_sz = 2*FSZ > 10*HB ? 2*FSZ : 10*HB;
    short* after = pool + pool_sz;
    short* WTH = after;                            // [208][32]
    short* WTL = WTH + 208*32;
    short* WbTH = WTL + 208*32;                    // [208][448]
    short* WbTL = WbTH + 208*448;
    float* hsg1 = (float*)(WbTL + 208*448);
    float* hsg2 = hsg1 + (size_t)BB*206;
    int* deg1 = (int*)(hsg2 + (size_t)BB*206);
    int* deg2 = deg1 + BN;
    int* start1 = deg2 + BN;                       // BN+1 entries
    int* start2 = start1 + (BN+1);
    int* cursor1 = start2 + (BN+1);                // unused (kept for layout)
    int* cursor2 = cursor1 + BN;
    int* rank1 = cursor2 + BN;
    int* rank2 = rank1 + EE;

    hipMemsetAsync(deg1, 0, 2*(size_t)BN*sizeof(int), stream);
    hipMemsetAsync(hsg1, 0, 2*(size_t)BB*206*sizeof(float), stream);

    // fused: node(16/block) + hist + prep_w + prep_wt(+featpad)
    prologue_kernel<<<6536, 256, 0, stream>>>(
        atom1, atom2, W_atom, ln_g, ln_b, h1, h2,
        edst1, edst2, deg1, deg2, rank1, rank2,
        W_edge, W_rbf, b_rbf, WTH, WTL, featH1, featH2,
        W_down, WbTH, WbTL);

    scan_kernel<<<2, 1024, 0, stream>>>(deg1, deg2, start1, start2);

    featgen_kernel<<<dim3(EE/256, 2), 256, 0, stream>>>(
        efeat1, efeat2, esrc1, esrc2, edst1, edst2, coords1, coords2,
        rank1, rank2, start1, start2, featH1, featH2);

    gather_mfma<<<dim3(BN/16, 2), 256, 0, stream>>>(
        featH1, featH2, start1, start2, WTH, WTL, ln_g, ln_b, h1, h2);

    for (int half = 0; half < 2; half++) {
        cvt_kernel<<<dim3(HBN/64, 2), 256, 0, stream>>>(
            h1, h2, half, hbH1, hbL1, hbH2, hbL2, hTH1, hTL1, hTH2, hTL2);
        // both directions in one dispatch
        attn_kernel<<<1024, 512, 0, stream>>>(
            hbH1, hbL1, hbH2, hbL2, hTH1, hTL1, hTH2, hTL2, cb1, cb2);
        down_mfma<<<dim3(HBN/128, 2), 512, 0, stream>>>(
            hbH1, hbH2, cb1, cb2, deg1, deg2, WbTH, WbTL, deg_tab,
            hsg1, hsg2, half);
    }

    mlp_kernel<<<BB, 256, 0, stream>>>(
        hsg1, hsg2, inter1, inter2,
        W_f1, b_f1, W_f2, b_f2, W_f3, b_f3, W_f4, b_f4, out);
}

// Round 9
// 833.092 us; speedup vs baseline: 1.6370x; 1.0697x over previous
//
#include <hip/hip_runtime.h>
#include <cstddef>
#include <cstdint>

// Problem constants
#define BB   64
#define NN   512
#define BN   (BB*NN)          // 32768
#define HBN  16384            // nodes per half
#define EE   524288
#define DA   70
#define DE   14
#define DH   200
#define DI   6
#define T_SCALE 0.07071067811865475f   // sqrt(1/200)

typedef __attribute__((ext_vector_type(8))) short short8;
typedef __attribute__((ext_vector_type(4))) float f32x4;

__device__ __forceinline__ short f2bf(float x) {
    union { float f; unsigned u; } v; v.f = x;
    const unsigned r = v.u + 0x7FFFu + ((v.u >> 16) & 1u);   // RNE
    return (short)(r >> 16);
}
__device__ __forceinline__ float bf2f(short s) {
    union { unsigned u; float f; } v;
    v.u = ((unsigned)(unsigned short)s) << 16;
    return v.f;
}

// 16-lane (row) sum via DPP — pure VALU, no DS pipe, no address VGPRs.
__device__ __forceinline__ float dpp16_sum(float x) {
    union { float f; int i; } a, b;
    a.f = x;
    b.i = __builtin_amdgcn_update_dpp(0, a.i, 0xB1, 0xF, 0xF, false); a.f += b.f;
    b.i = __builtin_amdgcn_update_dpp(0, a.i, 0x4E, 0xF, 0xF, false); a.f += b.f;
    b.i = __builtin_amdgcn_update_dpp(0, a.i, 0x141, 0xF, 0xF, false); a.f += b.f;
    b.i = __builtin_amdgcn_update_dpp(0, a.i, 0x140, 0xF, 0xF, false); a.f += b.f;
    return a.f;
}

// ---------------------------------------------------------------------------
// prologue: fused node(16/block) + hist + prep_w + prep_wt(+featpad).
// ---------------------------------------------------------------------------
__global__ __launch_bounds__(256) void prologue_kernel(
    const float* __restrict__ atom1, const float* __restrict__ atom2,
    const float* __restrict__ W_atom,
    const float* __restrict__ ln_g, const float* __restrict__ ln_b,
    float* __restrict__ h1, float* __restrict__ h2,
    const int* __restrict__ edst1, const int* __restrict__ edst2,
    int* __restrict__ deg1, int* __restrict__ deg2,
    int* __restrict__ rank1, int* __restrict__ rank2,
    const float* __restrict__ W_edge, const float* __restrict__ W_rbf,
    const float* __restrict__ b_rbf,
    short* __restrict__ WTH, short* __restrict__ WTL,
    short* __restrict__ featH1, short* __restrict__ featH2,
    const float* __restrict__ W_down,
    short* __restrict__ WbTH, short* __restrict__ WbTL)
{
    const int bid = blockIdx.x;
    const int tid = threadIdx.x;

    if (bid < 4096) {
        // ---- node phase: 16 nodes per block
        const int side = bid >> 11;
        const float* atom = side ? atom2 : atom1;
        float* h = side ? h2 : h1;
        const int node0 = (bid & 2047) * 16;

        __shared__ float arow[16][DA];    // 4.4 KB
        __shared__ float vals[16][DH];    // 12.8 KB

        for (int i = tid; i < 16*DA; i += 256) {
            const int n = i / DA, k = i % DA;
            arow[n][k] = atom[(size_t)(node0+n)*DA + k];
        }
        __syncthreads();

        if (tid < DH) {
            float a[16];
            #pragma unroll
            for (int n = 0; n < 16; n++) a[n] = 0.f;
            for (int k = 0; k < DA; k++) {
                const float w = W_atom[k*DH + tid];
                #pragma unroll
                for (int n = 0; n < 16; n++) a[n] += arow[n][k]*w;
            }
            #pragma unroll
            for (int n = 0; n < 16; n++) vals[n][tid] = fmaxf(a[n], 0.f);
        }
        __syncthreads();

        const int wv = tid >> 6, lane = tid & 63;
        #pragma unroll 1
        for (int rr = 0; rr < 4; rr++) {
            const int n = rr*4 + wv;
            float v0 = vals[n][lane];
            float v1 = vals[n][64+lane];
            float v2 = vals[n][128+lane];
            float v3 = (lane < 8) ? vals[n][192+lane] : 0.0f;
            float s  = v0+v1+v2+v3;
            float s2 = v0*v0+v1*v1+v2*v2+v3*v3;
            #pragma unroll
            for (int off = 1; off < 64; off <<= 1) {
                s  += __shfl_xor(s,  off, 64);
                s2 += __shfl_xor(s2, off, 64);
            }
            const float mean = s * (1.0f/DH);
            const float var  = s2 * (1.0f/DH) - mean*mean;
            const float rstd = rsqrtf(var + 1e-5f);
            const size_t base = (size_t)(node0+n)*DH;
            h[base + lane]       = ln_g[lane]     *(v0-mean)*rstd + ln_b[lane];
            h[base + 64 + lane]  = ln_g[64+lane]  *(v1-mean)*rstd + ln_b[64+lane];
            h[base + 128 + lane] = ln_g[128+lane] *(v2-mean)*rstd + ln_b[128+lane];
            if (lane < 8)
                h[base + 192 + lane] = ln_g[192+lane]*(v3-mean)*rstd + ln_b[192+lane];
        }
        return;
    }

    if (bid < 6144) {
        // ---- hist phase
        const int e = (bid - 4096)*256 + tid;
        rank1[e] = atomicAdd(&deg1[edst1[e]], 1);
        rank2[e] = atomicAdd(&deg2[edst2[e]], 1);
        return;
    }

    if (bid < 6508) {
        // ---- prep_w phase
        const int idx = (bid - 6144)*256 + tid;
        if (idx >= 208*448) return;
        const int c = idx / 448, kk = idx - c*448;
        float v = 0.f;
        if (c < 200) {
            if (kk < 200) v = W_down[(size_t)kk*DH + c];
            else if (kk >= 224 && kk < 424) v = W_down[(size_t)(200 + kk - 224)*DH + c];
        }
        const short hi = f2bf(v);
        WbTH[idx] = hi;
        WbTL[idx] = f2bf(v - bf2f(hi));
        return;
    }

    // ---- prep_wt phase (26 blocks WT, 2 blocks feat pad)
    {
        const int pb = bid - 6508;
        if (pb >= 26) {
            short* f = (pb == 26) ? featH1 : featH2;
            f[(size_t)EE*32 + tid] = 0;
            f[(size_t)EE*32 + 256 + tid] = 0;
            return;
        }
        const int idx = pb*256 + tid;
        const int c = idx >> 5, k = idx & 31;
        float v = 0.f;
        if (c < 100) {
            if (k < 14) v = W_edge[k*100 + c];
        } else if (c < 200) {
            const int cc = c - 100;
            if (k >= 14 && k < 30) v = W_rbf[(k-14)*100 + cc];
            else if (k == 30) v = b_rbf[cc];
        }
        const short hi = f2bf(v);
        WTH[idx] = hi;
        WTL[idx] = f2bf(v - bf2f(hi));
    }
}

__global__ __launch_bounds__(1024) void scan_kernel(
    const int* __restrict__ deg1, const int* __restrict__ deg2,
    int* __restrict__ start1, int* __restrict__ start2)
{
    const int side = blockIdx.x;
    const int* deg   = side ? deg2 : deg1;
    int* start  = side ? start2 : start1;

    __shared__ int part[1024];
    const int t = threadIdx.x;
    const int base = t * 32;
    int local[32];
    int sum = 0;
    #pragma unroll
    for (int i = 0; i < 8; i++) {        // int4 vector loads (16B/lane)
        const int4 v = *(const int4*)&deg[base + i*4];
        local[4*i+0] = v.x; local[4*i+1] = v.y;
        local[4*i+2] = v.z; local[4*i+3] = v.w;
        sum += v.x + v.y + v.z + v.w;
    }
    part[t] = sum;
    __syncthreads();
    for (int off = 1; off < 1024; off <<= 1) {
        int v = (t >= off) ? part[t-off] : 0;
        __syncthreads();
        part[t] += v;
        __syncthreads();
    }
    int run = part[t] - sum;   // exclusive
    #pragma unroll
    for (int i = 0; i < 32; i++) {
        start[base+i] = run;
        run += local[i];
    }
    if (t == 1023) start[BN] = run;   // sentinel == EE
}

// ---------------------------------------------------------------------------
// featgen: per-edge feature row -> featH[start[dst]+rank[e]][32] bf16
// ---------------------------------------------------------------------------
__global__ __launch_bounds__(256) void featgen_kernel(
    const float* __restrict__ efeat1, const float* __restrict__ efeat2,
    const int* __restrict__ esrc1, const int* __restrict__ esrc2,
    const int* __restrict__ edst1, const int* __restrict__ edst2,
    const float* __restrict__ coords1, const float* __restrict__ coords2,
    const int* __restrict__ rank1, const int* __restrict__ rank2,
    const int* __restrict__ start1, const int* __restrict__ start2,
    short* __restrict__ featH1, short* __restrict__ featH2)
{
    const int side = blockIdx.y;
    const float* ef     = side ? efeat2  : efeat1;
    const int*   esrc   = side ? esrc2   : esrc1;
    const int*   edst   = side ? edst2   : edst1;
    const float* coords = side ? coords2 : coords1;
    const int*   rank   = side ? rank2   : rank1;
    const int*   start  = side ? start2  : start1;
    short* featH = side ? featH2 : featH1;

    const int e = blockIdx.x*256 + threadIdx.x;
    const int src = esrc[e], dst = edst[e];

    short f[32];
    #pragma unroll
    for (int k = 0; k < 14; k++) f[k] = f2bf(ef[(size_t)e*DE + k]);

    const float dx = coords[src*3+0] - coords[dst*3+0];
    const float dy = coords[src*3+1] - coords[dst*3+1];
    const float dz = coords[src*3+2] - coords[dst*3+2];
    const float dist = sqrtf(dx*dx + dy*dy + dz*dz + 1e-12f);
    #pragma unroll
    for (int k = 0; k < 16; k++) {
        const float t = 3.2f*dist - 1.0666666667f*(float)k;
        f[14+k] = f2bf(__expf(-t*t));
    }
    f[30] = f2bf(1.0f);
    f[31] = 0;

    const int slot = start[dst] + rank[e];
    short* out = featH + (size_t)slot*32;
    #pragma unroll
    for (int q = 0; q < 4; q++)
        *(short8*)&out[q*8] = *(short8*)&f[q*8];
}

// ---------------------------------------------------------------------------
// gather_mfma v7 (unchanged): 133 us, VALU-bound at its structural floor.
// ---------------------------------------------------------------------------
__global__ __launch_bounds__(256, 2) void gather_mfma(
    const short* __restrict__ featH1, const short* __restrict__ featH2,
    const int* __restrict__ start1, const int* __restrict__ start2,
    const short* __restrict__ WTH, const short* __restrict__ WTL,
    const float* __restrict__ ln_g, const float* __restrict__ ln_b,
    float* __restrict__ h1, float* __restrict__ h2)
{
    __shared__ short sWH[208*40];    // 16.6 KB, stride-40 (80B) rows
    __shared__ short sWL[208*40];    // 16.6 KB
    __shared__ float plane[4][216];

    const int tid = threadIdx.x;
    const int wv = tid >> 6, lane = tid & 63;
    const int arow = lane & 15, aq = lane >> 4;

    // stage W once per block (832 short8 per array)
    for (int f = tid; f < 832; f += 256) {
        const int d = f >> 2, cc = (f & 3) * 8;
        *(short8*)&sWH[d*40 + cc] = *(const short8*)&WTH[f*8];
        *(short8*)&sWL[d*40 + cc] = *(const short8*)&WTL[f*8];
    }
    __syncthreads();

    const int side = blockIdx.y;
    const short* feat = side ? featH2 : featH1;
    const int*  start = side ? start2 : start1;
    float* h = side ? h2 : h1;

    const int c0 = blockIdx.x*16 + wv*4;     // wave's first node (of 4)

    // hoist ln params (lane-mapped)
    const float g0 = ln_g[lane],      bb0 = ln_b[lane];
    const float g1 = ln_g[64+lane],   bb1 = ln_b[64+lane];
    const float g2 = ln_g[128+lane],  bb2 = ln_b[128+lane];
    const float g3 = (lane < 8) ? ln_g[192+lane] : 0.f;
    const float bb3 = (lane < 8) ? ln_b[192+lane] : 0.f;

    // 5 start values for the 4 nodes, one load, then readlane
    const int sidx = (lane < 5) ? lane : 4;
    const int sv = start[c0 + sidx];

    const int lb = arow*40 + aq*8;           // LDS element offset in a W tile

    #pragma unroll 1
    for (int ni = 0; ni < 4; ni++) {
        const int st = __builtin_amdgcn_readlane(sv, ni);
        const int en = __builtin_amdgcn_readlane(sv, ni + 1);
        const int dg = en - st;
        const int node = c0 + ni;
        const size_t hbase = (size_t)node * DH;

        // hoist h RMW loads (consumed at node end, hidden under tiles)
        const float hv0 = h[hbase + lane];
        const float hv1 = h[hbase + 64 + lane];
        const float hv2 = h[hbase + 128 + lane];
        const float hv3 = (lane < 8) ? h[hbase + 192 + lane] : 0.f;

        float colacc[13];
        #pragma unroll
        for (int nt = 0; nt < 13; nt++) colacc[nt] = 0.f;
        float musum = 0.f;

        short8 aC = *(const short8*)&feat[(size_t)(st + arow)*32 + aq*8];

        for (int t0 = 0; t0 < dg; t0 += 16) {
            // prefetch next tile; overshoot lands in next node's rows or the
            // zeroed 16-row pad (start[BN]=EE sentinel) — discarded if unused
            const short8 aN = *(const short8*)&feat[(size_t)(st + t0 + 16 + arow)*32 + aq*8];

            f32x4 acc[13];
            #pragma unroll
            for (int nt = 0; nt < 13; nt++) {
                const short8 whv = *(const short8*)&sWH[nt*640 + lb];
                const short8 wlv = *(const short8*)&sWL[nt*640 + lb];
                f32x4 z = (f32x4){0.f,0.f,0.f,0.f};
                z = __builtin_amdgcn_mfma_f32_16x16x32_bf16(aC, whv, z, 0, 0, 0);
                z = __builtin_amdgcn_mfma_f32_16x16x32_bf16(aC, wlv, z, 0, 0, 0);
                acc[nt] = z;
            }
            // relu + per-row (per-edge) stats; row = t0 + aq*4 + r
            float sr[4] = {0.f,0.f,0.f,0.f}, s2r[4] = {0.f,0.f,0.f,0.f};
            #pragma unroll
            for (int nt = 0; nt < 13; nt++) {
                #pragma unroll
                for (int r = 0; r < 4; r++) {
                    const float v = fmaxf(acc[nt][r], 0.f);
                    acc[nt][r] = v;
                    sr[r] += v; s2r[r] += v*v;
                }
            }
            // 16-lane sum across arow via DPP (VALU-only)
            #pragma unroll
            for (int r = 0; r < 4; r++) {
                sr[r]  = dpp16_sum(sr[r]);
                s2r[r] = dpp16_sum(s2r[r]);
            }
            #pragma unroll
            for (int r = 0; r < 4; r++) {
                const bool valid = (t0 + aq*4 + r) < dg;
                const float mean = sr[r] * (1.0f/DH);
                const float var  = s2r[r] * (1.0f/DH) - mean*mean;
                const float rs   = rsqrtf(var + 1e-5f);
                const float rstd = valid ? rs : 0.f;
                musum += valid ? mean*rs : 0.f;
                #pragma unroll
                for (int nt = 0; nt < 13; nt++)
                    colacc[nt] += rstd*acc[nt][r];
            }
            aC = aN;
        }

        // reduce over the 4 aq groups (rows partition)
        #pragma unroll
        for (int nt = 0; nt < 13; nt++) {
            colacc[nt] += __shfl_xor(colacc[nt], 16, 64);
            colacc[nt] += __shfl_xor(colacc[nt], 32, 64);
        }
        musum += __shfl_xor(musum, 16, 64);
        musum += __shfl_xor(musum, 32, 64);

        if (aq == 0) {
            #pragma unroll
            for (int nt = 0; nt < 13; nt++)
                plane[wv][nt*16 + arow] = colacc[nt];
        }
        // wave-internal LDS producer/consumer: DS pipe is in-order per wave —
        // no barrier (and the next node's writes issue after these reads)

        const float dgf = (float)dg;
        h[hbase + lane]       = hv0 + g0*(plane[wv][lane]     - musum) + dgf*bb0;
        h[hbase + 64 + lane]  = hv1 + g1*(plane[wv][64+lane]  - musum) + dgf*bb1;
        h[hbase + 128 + lane] = hv2 + g2*(plane[wv][128+lane] - musum) + dgf*bb2;
        if (lane < 8)
            h[hbase + 192 + lane] = hv3 + g3*(plane[wv][192+lane] - musum) + dgf*bb3;
    }
}

// ---------------------------------------------------------------------------
// cvt (per half): h fp32 -> hb hi/lo [16384][224] rows + hbT hi/lo [32][224][512]
// ---------------------------------------------------------------------------
__global__ __launch_bounds__(256) void cvt_kernel(
    const float* __restrict__ h1, const float* __restrict__ h2, const int half,
    short* __restrict__ hbH1, short* __restrict__ hbL1,
    short* __restrict__ hbH2, short* __restrict__ hbL2,
    short* __restrict__ hTH1, short* __restrict__ hTL1,
    short* __restrict__ hTH2, short* __restrict__ hTL2)
{
    const int side = blockIdx.y;
    const float* h = side ? h2 : h1;
    short* hbH = side ? hbH2 : hbH1;
    short* hbL = side ? hbL2 : hbL1;
    short* hTH = side ? hTH2 : hTH1;
    short* hTL = side ? hTL2 : hTL1;

    const int nl0 = blockIdx.x * 64;          // local node
    const int bl = nl0 >> 9, m0 = nl0 & 511;
    const int ng0 = half*HBN + nl0;

    __shared__ short tH[64][226];
    __shared__ short tL[64][226];
    const int tid = threadIdx.x;
    for (int i = tid; i < 64*224; i += 256) {
        const int r = i / 224, c = i - r*224;
        const float v = (c < DH) ? h[(size_t)(ng0+r)*DH + c] : 0.f;
        const short hi = f2bf(v);
        const short lo = f2bf(v - bf2f(hi));
        tH[r][c] = hi; tL[r][c] = lo;
        hbH[(size_t)(nl0+r)*224 + c] = hi;
        hbL[(size_t)(nl0+r)*224 + c] = lo;
    }
    __syncthreads();
    for (int i = tid; i < 224*64; i += 256) {
        const int c = i >> 6, m = i & 63;
        const size_t o = ((size_t)bl*224 + c)*NN + m0 + m;
        hTH[o] = tH[m][c];
        hTL[o] = tL[m][c];
    }
}

// ---------------------------------------------------------------------------
// Fused attention v8: 64 Q-rows per block, 512 blocks x 512 threads, both
// dirs in one dispatch. Halves the per-dispatch K/V stream vs v7 (940 ->
// 470 MB) and doubles K-register reuse (each K frag feeds 4 q-row-groups).
// LDS: pb[64][520]=65KB aliases sQ(58KB); +4KB sm/ss -> 70.6KB, 2 blk/CU.
// Regs: acc[4][4]=64 + q 32 + K 8 + addr ~15 ~= 120 < cap 128 @ (512,2).
// Numerics bit-identical (same MFMA order per row, same 8-wave reductions).
// ---------------------------------------------------------------------------
__global__ __launch_bounds__(512, 2) void attn_kernel(
    const short* __restrict__ hbH1, const short* __restrict__ hbL1,
    const short* __restrict__ hbH2, const short* __restrict__ hbL2,
    const short* __restrict__ hTH1, const short* __restrict__ hTL1,
    const short* __restrict__ hTH2, const short* __restrict__ hTL2,
    short* __restrict__ cb1, short* __restrict__ cb2)
{
    const int id  = blockIdx.x;                // 0..511
    const int xcd = id & 7, m = id >> 3;       // m 0..63
    const int b2  = m >> 4;                    // 0..3
    const int dir = (m >> 3) & 1;
    const int qb  = m & 7;
    const int b   = xcd*4 + b2;                // half-local batch 0..31
    const int q0  = qb << 6;                   // 64 q-rows

    const short *Qh, *Ql, *Kh, *Kl, *Vh, *Vl;
    short* cb;
    if (dir == 0) {
        Qh = hbH1 + (size_t)b*NN*224;  Ql = hbL1 + (size_t)b*NN*224;
        Kh = hbH2 + (size_t)b*NN*224;  Kl = hbL2 + (size_t)b*NN*224;
        Vh = hTH2 + (size_t)b*224*NN;  Vl = hTL2 + (size_t)b*224*NN;
        cb = cb1;
    } else {
        Qh = hbH2 + (size_t)b*NN*224;  Ql = hbL2 + (size_t)b*NN*224;
        Kh = hbH1 + (size_t)b*NN*224;  Kl = hbL1 + (size_t)b*NN*224;
        Vh = hTH1 + (size_t)b*224*NN;  Vl = hTL1 + (size_t)b*224*NN;
        cb = cb2;
    }

    __shared__ short smem[64*520];            // 65 KB: pb, aliases sQ
    short* sQh = smem;                        // [64][232] = 14848 shorts
    short* sQl = smem + 14848;                // [64][232]
    short* pb  = smem;                        // [64][520]
    __shared__ float sm_[8][64];
    __shared__ float ss_[8][64];

    const int tid = threadIdx.x;
    const int wv = tid >> 6, lane = tid & 63;
    const int arow = lane & 15, aq = lane >> 4;

    // stage Q (64 rows x 224, hi/lo) cooperatively
    for (int i = tid; i < 1792; i += 512) {
        const int rr = i / 28, c = (i - rr*28) * 8;
        *(short8*)&sQh[rr*232 + c] = *(const short8*)&Qh[(size_t)(q0 + rr)*224 + c];
        *(short8*)&sQl[rr*232 + c] = *(const short8*)&Ql[(size_t)(q0 + rr)*224 + c];
    }
    __syncthreads();

    f32x4 acc[4][4];
    #pragma unroll
    for (int g = 0; g < 4; g++)
        #pragma unroll
        for (int t = 0; t < 4; t++) acc[g][t] = (f32x4){0.f,0.f,0.f,0.f};

    const int qb_off = arow*232 + aq*8;
    #pragma unroll 1
    for (int k = 0; k < 7; k++) {
        short8 qh[4], ql[4];
        #pragma unroll
        for (int g = 0; g < 4; g++) {
            qh[g] = *(const short8*)&sQh[qb_off + g*16*232 + k*32];
            ql[g] = *(const short8*)&sQl[qb_off + g*16*232 + k*32];
        }
        #pragma unroll
        for (int t = 0; t < 4; t++) {
            const size_t kb = (size_t)((wv*4 + t)*16 + arow)*224 + k*32 + aq*8;
            const short8 bh = *(const short8*)&Kh[kb];
            const short8 bl = *(const short8*)&Kl[kb];
            #pragma unroll
            for (int g = 0; g < 4; g++) {
                acc[g][t] = __builtin_amdgcn_mfma_f32_16x16x32_bf16(qh[g], bh, acc[g][t], 0, 0, 0);
                acc[g][t] = __builtin_amdgcn_mfma_f32_16x16x32_bf16(qh[g], bl, acc[g][t], 0, 0, 0);
                acc[g][t] = __builtin_amdgcn_mfma_f32_16x16x32_bf16(ql[g], bh, acc[g][t], 0, 0, 0);
            }
        }
    }

    #pragma unroll
    for (int g = 0; g < 4; g++) {
        #pragma unroll
        for (int r2 = 0; r2 < 4; r2++) {
            float mx = -1e30f;
            #pragma unroll
            for (int t = 0; t < 4; t++) {
                acc[g][t][r2] *= T_SCALE;
                mx = fmaxf(mx, acc[g][t][r2]);
            }
            mx = fmaxf(mx, __shfl_xor(mx, 1, 64));
            mx = fmaxf(mx, __shfl_xor(mx, 2, 64));
            mx = fmaxf(mx, __shfl_xor(mx, 4, 64));
            mx = fmaxf(mx, __shfl_xor(mx, 8, 64));
            if (arow == 0) sm_[wv][g*16 + aq*4 + r2] = mx;
        }
    }
    __syncthreads();
    #pragma unroll
    for (int g = 0; g < 4; g++) {
        #pragma unroll
        for (int r2 = 0; r2 < 4; r2++) {
            const int row = g*16 + aq*4 + r2;
            float M = sm_[0][row];
            #pragma unroll
            for (int w = 1; w < 8; w++) M = fmaxf(M, sm_[w][row]);
            float s = 0.f;
            #pragma unroll
            for (int t = 0; t < 4; t++) {
                const float e = __expf(acc[g][t][r2] - M);
                acc[g][t][r2] = e;
                s += e;
            }
            s += __shfl_xor(s, 1, 64);
            s += __shfl_xor(s, 2, 64);
            s += __shfl_xor(s, 4, 64);
            s += __shfl_xor(s, 8, 64);
            if (arow == 0) ss_[wv][row] = s;
        }
    }
    __syncthreads();
    // all waves are past the QK phase (2 barriers above) — safe to overwrite sQ
    #pragma unroll
    for (int g = 0; g < 4; g++) {
        #pragma unroll
        for (int r2 = 0; r2 < 4; r2++) {
            const int row = g*16 + aq*4 + r2;
            float s = ss_[0][row];
            #pragma unroll
            for (int w = 1; w < 8; w++) s += ss_[w][row];
            const float iv = 1.0f / s;
            #pragma unroll
            for (int t = 0; t < 4; t++) {
                const int col = (wv*4 + t)*16 + arow;
                pb[row*520 + col] = f2bf(acc[g][t][r2] * iv);
            }
        }
    }
    __syncthreads();

    const int nbase = (wv < 5) ? 2*wv : 10 + (wv - 5);
    const int ncnt  = (wv < 5) ? 2 : 1;
    f32x4 pacc[4][2];
    #pragma unroll
    for (int g = 0; g < 4; g++)
        #pragma unroll
        for (int t = 0; t < 2; t++) pacc[g][t] = (f32x4){0.f,0.f,0.f,0.f};

    for (int k0 = 0; k0 < NN; k0 += 32) {
        short8 a[4];
        #pragma unroll
        for (int g = 0; g < 4; g++)
            a[g] = *(const short8*)&pb[(g*16 + arow)*520 + k0 + aq*8];
        #pragma unroll
        for (int t = 0; t < 2; t++) {
            if (t < ncnt) {
                const size_t vb = (size_t)((nbase+t)*16 + arow)*NN + k0 + aq*8;
                const short8 bh = *(const short8*)&Vh[vb];
                const short8 bl = *(const short8*)&Vl[vb];
                #pragma unroll
                for (int g = 0; g < 4; g++) {
                    pacc[g][t] = __builtin_amdgcn_mfma_f32_16x16x32_bf16(a[g], bh, pacc[g][t], 0, 0, 0);
                    pacc[g][t] = __builtin_amdgcn_mfma_f32_16x16x32_bf16(a[g], bl, pacc[g][t], 0, 0, 0);
                }
            }
        }
    }

    #pragma unroll
    for (int t = 0; t < 2; t++) {
        if (t < ncnt) {
            const int col = (nbase+t)*16 + arow;
            #pragma unroll
            for (int g = 0; g < 4; g++) {
                #pragma unroll
                for (int r2 = 0; r2 < 4; r2++) {
                    const int row = q0 + g*16 + aq*4 + r2;
                    const short v = (col < DH) ? f2bf(pacc[g][t][r2]) : (short)0;
                    cb[((size_t)b*NN + row)*224 + col] = v;
                }
            }
        }
    }
    if (wv == 7) {
        const int col = 208 + arow;
        #pragma unroll
        for (int g = 0; g < 4; g++) {
            #pragma unroll
            for (int r2 = 0; r2 < 4; r2++) {
                const int row = q0 + g*16 + aq*4 + r2;
                cb[((size_t)b*NN + row)*224 + col] = 0;
            }
        }
    }
}

// ---------------------------------------------------------------------------
// down v2 (512 thr, 128 nodes/block) — unchanged.
// ---------------------------------------------------------------------------
__global__ __launch_bounds__(512, 2) void down_mfma(
    const short* __restrict__ hbH1, const short* __restrict__ hbH2,
    const short* __restrict__ cb1, const short* __restrict__ cb2,
    const int* __restrict__ deg1, const int* __restrict__ deg2,
    const short* __restrict__ WbTH, const short* __restrict__ WbTL,
    const float* __restrict__ degree_table,
    float* __restrict__ hsg1, float* __restrict__ hsg2, const int half)
{
    const int side = blockIdx.y;
    const short* X0 = side ? hbH2 : hbH1;
    const short* X1 = side ? cb2 : cb1;
    const int*   dgp = side ? deg2 : deg1;
    float* hsg = side ? hsg2 : hsg1;

    const int nl0 = blockIdx.x * 128;
    const int ng0 = half*HBN + nl0;
    const int b = ng0 >> 9;

    __shared__ short As[128*40];
    __shared__ short BsH[208*40];
    __shared__ short BsL[208*40];
    __shared__ float part[208];

    const int tid = threadIdx.x;
    const int wv = tid >> 6, lane = tid & 63;
    const int arow = lane & 15, aq = lane >> 4;

    if (tid < 208) part[tid] = 0.f;

    f32x4 acc[13];
    #pragma unroll
    for (int t = 0; t < 13; t++) acc[t] = (f32x4){0.f,0.f,0.f,0.f};

    const int sr = tid >> 2, sc = (tid & 3) * 8;

    for (int phase = 0; phase < 2; phase++) {
        const short* X = phase ? X1 : X0;
        for (int k0 = 0; k0 < 224; k0 += 32) {
            __syncthreads();
            *(short8*)&As[sr*40 + sc] =
                *(const short8*)&X[(size_t)(nl0+sr)*224 + k0 + sc];
            const int kkg = phase*224 + k0;
            #pragma unroll
            for (int pass = 0; pass < 2; pass++) {
                const int f = pass*512 + tid;
                if (f < 832) {
                    const int d = f >> 2, cc = (f & 3) * 8;
                    *(short8*)&BsH[d*40 + cc] = *(const short8*)&WbTH[(size_t)d*448 + kkg + cc];
                    *(short8*)&BsL[d*40 + cc] = *(const short8*)&WbTL[(size_t)d*448 + kkg + cc];
                }
            }
            __syncthreads();
            const short8 a = *(const short8*)&As[(16*wv + arow)*40 + aq*8];
            #pragma unroll
            for (int t = 0; t < 13; t++) {
                const short8 bh = *(const short8*)&BsH[(t*16 + arow)*40 + aq*8];
                const short8 bl = *(const short8*)&BsL[(t*16 + arow)*40 + aq*8];
                acc[t] = __builtin_amdgcn_mfma_f32_16x16x32_bf16(a, bh, acc[t], 0, 0, 0);
                acc[t] = __builtin_amdgcn_mfma_f32_16x16x32_bf16(a, bl, acc[t], 0, 0, 0);
            }
        }
    }
    __syncthreads();

    int dgc[4];
    #pragma unroll
    for (int r = 0; r < 4; r++) {
        int d = dgp[ng0 + 16*wv + aq*4 + r];
        dgc[r] = d > 199 ? 199 : d;
    }
    #pragma unroll
    for (int nt = 0; nt < 13; nt++) {
        const int col = nt*16 + arow;
        float s = 0.f;
        if (col < DH) {
            #pragma unroll
            for (int r = 0; r < 4; r++)
                s += fmaxf(acc[nt][r], 0.f) + degree_table[dgc[r]*DH + col];
        }
        s += __shfl_xor(s, 16, 64);
        s += __shfl_xor(s, 32, 64);
        if (lane < 16 && col < DH) atomicAdd(&part[col], s);
    }
    __syncthreads();
    if (tid < DH) unsafeAtomicAdd(&hsg[b*206 + tid], part[tid] * (1.0f/512.0f));
}

// ---------------------------------------------------------------------------
// Kernel 7: final MLP, one block per batch row (interaction means folded in)
// ---------------------------------------------------------------------------
__global__ __launch_bounds__(256) void mlp_kernel(
    const float* __restrict__ hsg1, const float* __restrict__ hsg2,
    const float* __restrict__ i1, const float* __restrict__ i2,
    const float* __restrict__ W_f1, const float* __restrict__ b_f1,
    const float* __restrict__ W_f2, const float* __restrict__ b_f2,
    const float* __restrict__ W_f3, const float* __restrict__ b_f3,
    const float* __restrict__ W_f4, const float* __restrict__ b_f4,
    float* __restrict__ out)
{
    const int b = blockIdx.x;
    __shared__ float x[618];
    __shared__ float y1[400];
    __shared__ float y2[200];
    __shared__ float y3[100];
    __shared__ float red[256];
    const int tid = threadIdx.x;

    // interaction means (folded inter_kernel); y2 used as scratch pre-layer2
    if (tid < 192) {
        const int j = tid % 6, seg = tid / 6;
        float s1 = 0.f, s2 = 0.f;
        for (int n = seg*16; n < seg*16 + 16; n++) {
            s1 += i1[(size_t)b*NN*DI + n*DI + j];
            s2 += i2[(size_t)b*NN*DI + n*DI + j];
        }
        red[tid] = s1;
        y2[tid] = s2;
    }
    __syncthreads();
    if (tid < 206) {
        float a, bb;
        if (tid < 200) {
            a = hsg1[b*206 + tid]; bb = hsg2[b*206 + tid];
        } else {
            const int j = tid - 200;
            float t1 = 0.f, t2 = 0.f;
            for (int sg = 0; sg < 32; sg++) { t1 += red[sg*6 + j]; t2 += y2[sg*6 + j]; }
            a = t1 * (1.0f/512.0f); bb = t2 * (1.0f/512.0f);
        }
        x[tid] = a; x[206 + tid] = bb; x[412 + tid] = a - bb;
    }
    __syncthreads();
    for (int c = tid; c < 400; c += 256) {
        float acc = b_f1[c];
        for (int k = 0; k < 618; k++) acc += x[k]*W_f1[(size_t)k*400 + c];
        y1[c] = fmaxf(acc, 0.0f);
    }
    __syncthreads();
    if (tid < 200) {
        float acc = b_f2[tid];
        for (int k = 0; k < 400; k++) acc += y1[k]*W_f2[k*200 + tid];
        y2[tid] = fmaxf(acc, 0.0f);
    }
    __syncthreads();
    if (tid < 100) {
        float acc = b_f3[tid];
        for (int k = 0; k < 200; k++) acc += y2[k]*W_f3[k*100 + tid];
        y3[tid] = fmaxf(acc, 0.0f);
    }
    __syncthreads();
    red[tid] = (tid < 100) ? y3[tid]*W_f4[tid] : 0.0f;
    __syncthreads();
    for (int s = 128; s > 0; s >>= 1) {
        if (tid < s) red[tid] += red[tid + s];
        __syncthreads();
    }
    if (tid == 0) out[b] = red[0] + b_f4[0];
}

// ---------------------------------------------------------------------------
extern "C" void kernel_launch(void* const* d_in, const int* in_sizes, int n_in,
                              void* d_out, int out_size, void* d_ws, size_t ws_size,
                              hipStream_t stream)
{
    const float* atom1  = (const float*)d_in[0];
    const float* atom2  = (const float*)d_in[1];
    const float* coords1= (const float*)d_in[2];
    const float* coords2= (const float*)d_in[3];
    const float* efeat1 = (const float*)d_in[4];
    const float* efeat2 = (const float*)d_in[5];
    const float* inter1 = (const float*)d_in[6];
    const float* inter2 = (const float*)d_in[7];
    const int*   esrc1  = (const int*)d_in[8];
    const int*   edst1  = (const int*)d_in[9];
    const int*   esrc2  = (const int*)d_in[10];
    const int*   edst2  = (const int*)d_in[11];
    const float* W_atom = (const float*)d_in[12];
    const float* W_edge = (const float*)d_in[13];
    const float* W_rbf  = (const float*)d_in[14];
    const float* b_rbf  = (const float*)d_in[15];
    const float* ln_g   = (const float*)d_in[16];
    const float* ln_b   = (const float*)d_in[17];
    const float* W_down = (const float*)d_in[18];
    const float* deg_tab= (const float*)d_in[19];
    const float* W_f1   = (const float*)d_in[20];
    const float* b_f1   = (const float*)d_in[21];
    const float* W_f2   = (const float*)d_in[22];
    const float* b_f2   = (const float*)d_in[23];
    const float* W_f3   = (const float*)d_in[24];
    const float* b_f3   = (const float*)d_in[25];
    const float* W_f4   = (const float*)d_in[26];
    const float* b_f4   = (const float*)d_in[27];
    float* out = (float*)d_out;

    // ---- workspace layout (~133 MB)
    float* ws = (float*)d_ws;
    const size_t HSZ = (size_t)BN*DH;              // per-side h floats
    float* h1  = ws;
    float* h2  = h1 + HSZ;
    // pool: max(feat 2*(EE+16)*32 shorts, bf16 pool 10*HB shorts)
    short* pool = (short*)(h2 + HSZ);
    const size_t FSZ = (size_t)(EE+16)*32;
    short* featH1 = pool;
    short* featH2 = featH1 + FSZ;
    const size_t HB = (size_t)32*NN*224;           // 3,670,016 shorts
    short* hbH1 = pool;           short* hbL1 = hbH1 + HB;
    short* hbH2 = hbL1 + HB;      short* hbL2 = hbH2 + HB;
    short* hTH1 = hbL2 + HB;      short* hTL1 = hTH1 + HB;
    short* hTH2 = hTL1 + HB;      short* hTL2 = hTH2 + HB;
    short* cb1  = hTL2 + HB;      short* cb2  = cb1 + HB;
    size_t pool_sz = 2*FSZ > 10*HB ? 2*FSZ : 10*HB;
    short* after = pool + pool_sz;
    short* WTH = after;                            // [208][32]
    short* WTL = WTH + 208*32;
    short* WbTH = WTL + 208*32;                    // [208][448]
    short* WbTL = WbTH + 208*448;
    float* hsg1 = (float*)(WbTL + 208*448);
    float* hsg2 = hsg1 + (size_t)BB*206;
    int* deg1 = (int*)(hsg2 + (size_t)BB*206);
    int* deg2 = deg1 + BN;
    int* start1 = deg2 + BN;                       // BN+1 entries
    int* start2 = start1 + (BN+1);
    int* cursor1 = start2 + (BN+1);                // unused (kept for layout)
    int* cursor2 = cursor1 + BN;
    int* rank1 = cursor2 + BN;
    int* rank2 = rank1 + EE;

    hipMemsetAsync(deg1, 0, 2*(size_t)BN*sizeof(int), stream);
    hipMemsetAsync(hsg1, 0, 2*(size_t)BB*206*sizeof(float), stream);

    // fused: node(16/block) + hist + prep_w + prep_wt(+featpad)
    prologue_kernel<<<6536, 256, 0, stream>>>(
        atom1, atom2, W_atom, ln_g, ln_b, h1, h2,
        edst1, edst2, deg1, deg2, rank1, rank2,
        W_edge, W_rbf, b_rbf, WTH, WTL, featH1, featH2,
        W_down, WbTH, WbTL);

    scan_kernel<<<2, 1024, 0, stream>>>(deg1, deg2, start1, start2);

    featgen_kernel<<<dim3(EE/256, 2), 256, 0, stream>>>(
        efeat1, efeat2, esrc1, esrc2, edst1, edst2, coords1, coords2,
        rank1, rank2, start1, start2, featH1, featH2);

    gather_mfma<<<dim3(BN/16, 2), 256, 0, stream>>>(
        featH1, featH2, start1, start2, WTH, WTL, ln_g, ln_b, h1, h2);

    for (int half = 0; half < 2; half++) {
        cvt_kernel<<<dim3(HBN/64, 2), 256, 0, stream>>>(
            h1, h2, half, hbH1, hbL1, hbH2, hbL2, hTH1, hTL1, hTH2, hTL2);
        // both directions in one dispatch, 64 q-rows per block
        attn_kernel<<<512, 512, 0, stream>>>(
            hbH1, hbL1, hbH2, hbL2, hTH1, hTL1, hTH2, hTL2, cb1, cb2);
        down_mfma<<<dim3(HBN/128, 2), 512, 0, stream>>>(
            hbH1, hbH2, cb1, cb2, deg1, deg2, WbTH, WbTL, deg_tab,
            hsg1, hsg2, half);
    }

    mlp_kernel<<<BB, 256, 0, stream>>>(
        hsg1, hsg2, inter1, inter2,
        W_f1, b_f1, W_f2, b_f2, W_f3, b_f3, W_f4, b_f4, out);
}

// Round 10
// 771.628 us; speedup vs baseline: 1.7674x; 1.0797x over previous
//
#include <hip/hip_runtime.h>
#include <cstddef>
#include <cstdint>

// Problem constants
#define BB   64
#define NN   512
#define BN   (BB*NN)          // 32768
#define HBN  16384            // nodes per half
#define EE   524288
#define DA   70
#define DE   14
#define DH   200
#define DI   6
#define T_SCALE 0.07071067811865475f   // sqrt(1/200)

typedef __attribute__((ext_vector_type(8))) short short8;
typedef __attribute__((ext_vector_type(4))) float f32x4;

__device__ __forceinline__ short f2bf(float x) {
    union { float f; unsigned u; } v; v.f = x;
    const unsigned r = v.u + 0x7FFFu + ((v.u >> 16) & 1u);   // RNE
    return (short)(r >> 16);
}
__device__ __forceinline__ float bf2f(short s) {
    union { unsigned u; float f; } v;
    v.u = ((unsigned)(unsigned short)s) << 16;
    return v.f;
}

// 16-lane (row) sum via DPP — pure VALU, no DS pipe, no address VGPRs.
__device__ __forceinline__ float dpp16_sum(float x) {
    union { float f; int i; } a, b;
    a.f = x;
    b.i = __builtin_amdgcn_update_dpp(0, a.i, 0xB1, 0xF, 0xF, false); a.f += b.f;
    b.i = __builtin_amdgcn_update_dpp(0, a.i, 0x4E, 0xF, 0xF, false); a.f += b.f;
    b.i = __builtin_amdgcn_update_dpp(0, a.i, 0x141, 0xF, 0xF, false); a.f += b.f;
    b.i = __builtin_amdgcn_update_dpp(0, a.i, 0x140, 0xF, 0xF, false); a.f += b.f;
    return a.f;
}

// ---------------------------------------------------------------------------
// prologue: fused node(16/block) + hist + prep_w + prep_wt(+featpad).
// Round-9 counters: VALUBusy 37%, HBM 9%, conflicts 0 -> DS-pipe issue-bound
// on 1120 broadcast ds_read_b32/wave in the node matmul. v2: float4 arow
// reads (272 ds_read_b128) — DS time ~halves. Accumulation order unchanged.
// ---------------------------------------------------------------------------
__global__ __launch_bounds__(256) void prologue_kernel(
    const float* __restrict__ atom1, const float* __restrict__ atom2,
    const float* __restrict__ W_atom,
    const float* __restrict__ ln_g, const float* __restrict__ ln_b,
    float* __restrict__ h1, float* __restrict__ h2,
    const int* __restrict__ edst1, const int* __restrict__ edst2,
    int* __restrict__ deg1, int* __restrict__ deg2,
    int* __restrict__ rank1, int* __restrict__ rank2,
    const float* __restrict__ W_edge, const float* __restrict__ W_rbf,
    const float* __restrict__ b_rbf,
    short* __restrict__ WTH, short* __restrict__ WTL,
    short* __restrict__ featH1, short* __restrict__ featH2,
    const float* __restrict__ W_down,
    short* __restrict__ WbTH, short* __restrict__ WbTL)
{
    const int bid = blockIdx.x;
    const int tid = threadIdx.x;

    if (bid < 4096) {
        // ---- node phase: 16 nodes per block
        const int side = bid >> 11;
        const float* atom = side ? atom2 : atom1;
        float* h = side ? h2 : h1;
        const int node0 = (bid & 2047) * 16;

        __shared__ float arow[16][72];    // padded rows -> 16B-aligned float4
        __shared__ float vals[16][DH];    // 12.8 KB

        for (int i = tid; i < 16*35; i += 256) {
            const int n = i / 35, k2 = i % 35;
            const float2 v = *(const float2*)&atom[(size_t)(node0+n)*DA + k2*2];
            arow[n][k2*2]   = v.x;
            arow[n][k2*2+1] = v.y;
        }
        if (tid < 32) arow[tid >> 1][70 + (tid & 1)] = 0.f;
        __syncthreads();

        if (tid < DH) {
            float a[16];
            #pragma unroll
            for (int n = 0; n < 16; n++) a[n] = 0.f;
            #pragma unroll 1
            for (int c4 = 0; c4 < 17; c4++) {
                const int k = c4*4;
                const float w0 = W_atom[(k+0)*DH + tid];
                const float w1 = W_atom[(k+1)*DH + tid];
                const float w2 = W_atom[(k+2)*DH + tid];
                const float w3 = W_atom[(k+3)*DH + tid];
                #pragma unroll
                for (int n = 0; n < 16; n++) {
                    const float4 av = *(const float4*)&arow[n][k];
                    a[n] += av.x*w0;
                    a[n] += av.y*w1;
                    a[n] += av.z*w2;
                    a[n] += av.w*w3;
                }
            }
            {   // tail k = 68, 69
                const float w0 = W_atom[68*DH + tid];
                const float w1 = W_atom[69*DH + tid];
                #pragma unroll
                for (int n = 0; n < 16; n++) {
                    a[n] += arow[n][68]*w0;
                    a[n] += arow[n][69]*w1;
                }
            }
            #pragma unroll
            for (int n = 0; n < 16; n++) vals[n][tid] = fmaxf(a[n], 0.f);
        }
        __syncthreads();

        const int wv = tid >> 6, lane = tid & 63;
        #pragma unroll 1
        for (int rr = 0; rr < 4; rr++) {
            const int n = rr*4 + wv;
            float v0 = vals[n][lane];
            float v1 = vals[n][64+lane];
            float v2 = vals[n][128+lane];
            float v3 = (lane < 8) ? vals[n][192+lane] : 0.0f;
            float s  = v0+v1+v2+v3;
            float s2 = v0*v0+v1*v1+v2*v2+v3*v3;
            #pragma unroll
            for (int off = 1; off < 64; off <<= 1) {
                s  += __shfl_xor(s,  off, 64);
                s2 += __shfl_xor(s2, off, 64);
            }
            const float mean = s * (1.0f/DH);
            const float var  = s2 * (1.0f/DH) - mean*mean;
            const float rstd = rsqrtf(var + 1e-5f);
            const size_t base = (size_t)(node0+n)*DH;
            h[base + lane]       = ln_g[lane]     *(v0-mean)*rstd + ln_b[lane];
            h[base + 64 + lane]  = ln_g[64+lane]  *(v1-mean)*rstd + ln_b[64+lane];
            h[base + 128 + lane] = ln_g[128+lane] *(v2-mean)*rstd + ln_b[128+lane];
            if (lane < 8)
                h[base + 192 + lane] = ln_g[192+lane]*(v3-mean)*rstd + ln_b[192+lane];
        }
        return;
    }

    if (bid < 6144) {
        // ---- hist phase
        const int e = (bid - 4096)*256 + tid;
        rank1[e] = atomicAdd(&deg1[edst1[e]], 1);
        rank2[e] = atomicAdd(&deg2[edst2[e]], 1);
        return;
    }

    if (bid < 6508) {
        // ---- prep_w phase
        const int idx = (bid - 6144)*256 + tid;
        if (idx >= 208*448) return;
        const int c = idx / 448, kk = idx - c*448;
        float v = 0.f;
        if (c < 200) {
            if (kk < 200) v = W_down[(size_t)kk*DH + c];
            else if (kk >= 224 && kk < 424) v = W_down[(size_t)(200 + kk - 224)*DH + c];
        }
        const short hi = f2bf(v);
        WbTH[idx] = hi;
        WbTL[idx] = f2bf(v - bf2f(hi));
        return;
    }

    // ---- prep_wt phase (26 blocks WT, 2 blocks feat pad)
    {
        const int pb = bid - 6508;
        if (pb >= 26) {
            short* f = (pb == 26) ? featH1 : featH2;
            f[(size_t)EE*32 + tid] = 0;
            f[(size_t)EE*32 + 256 + tid] = 0;
            return;
        }
        const int idx = pb*256 + tid;
        const int c = idx >> 5, k = idx & 31;
        float v = 0.f;
        if (c < 100) {
            if (k < 14) v = W_edge[k*100 + c];
        } else if (c < 200) {
            const int cc = c - 100;
            if (k >= 14 && k < 30) v = W_rbf[(k-14)*100 + cc];
            else if (k == 30) v = b_rbf[cc];
        }
        const short hi = f2bf(v);
        WTH[idx] = hi;
        WTL[idx] = f2bf(v - bf2f(hi));
    }
}

__global__ __launch_bounds__(1024) void scan_kernel(
    const int* __restrict__ deg1, const int* __restrict__ deg2,
    int* __restrict__ start1, int* __restrict__ start2)
{
    const int side = blockIdx.x;
    const int* deg   = side ? deg2 : deg1;
    int* start  = side ? start2 : start1;

    __shared__ int part[1024];
    const int t = threadIdx.x;
    const int base = t * 32;
    int local[32];
    int sum = 0;
    #pragma unroll
    for (int i = 0; i < 8; i++) {        // int4 vector loads (16B/lane)
        const int4 v = *(const int4*)&deg[base + i*4];
        local[4*i+0] = v.x; local[4*i+1] = v.y;
        local[4*i+2] = v.z; local[4*i+3] = v.w;
        sum += v.x + v.y + v.z + v.w;
    }
    part[t] = sum;
    __syncthreads();
    for (int off = 1; off < 1024; off <<= 1) {
        int v = (t >= off) ? part[t-off] : 0;
        __syncthreads();
        part[t] += v;
        __syncthreads();
    }
    int run = part[t] - sum;   // exclusive
    #pragma unroll
    for (int i = 0; i < 32; i++) {
        start[base+i] = run;
        run += local[i];
    }
    if (t == 1023) start[BN] = run;   // sentinel == EE
}

// ---------------------------------------------------------------------------
// featgen v2: float2 ef loads (7 instead of 14 scalars at 56B stride; the
// row base e*56B is always 8B-aligned). Values bit-identical.
// ---------------------------------------------------------------------------
__global__ __launch_bounds__(256) void featgen_kernel(
    const float* __restrict__ efeat1, const float* __restrict__ efeat2,
    const int* __restrict__ esrc1, const int* __restrict__ esrc2,
    const int* __restrict__ edst1, const int* __restrict__ edst2,
    const float* __restrict__ coords1, const float* __restrict__ coords2,
    const int* __restrict__ rank1, const int* __restrict__ rank2,
    const int* __restrict__ start1, const int* __restrict__ start2,
    short* __restrict__ featH1, short* __restrict__ featH2)
{
    const int side = blockIdx.y;
    const float* ef     = side ? efeat2  : efeat1;
    const int*   esrc   = side ? esrc2   : esrc1;
    const int*   edst   = side ? edst2   : edst1;
    const float* coords = side ? coords2 : coords1;
    const int*   rank   = side ? rank2   : rank1;
    const int*   start  = side ? start2  : start1;
    short* featH = side ? featH2 : featH1;

    const int e = blockIdx.x*256 + threadIdx.x;
    const int src = esrc[e], dst = edst[e];

    float efv[14];
    #pragma unroll
    for (int q = 0; q < 7; q++) {
        const float2 v = *(const float2*)&ef[(size_t)e*DE + q*2];
        efv[2*q]   = v.x;
        efv[2*q+1] = v.y;
    }
    short f[32];
    #pragma unroll
    for (int k = 0; k < 14; k++) f[k] = f2bf(efv[k]);

    const float dx = coords[src*3+0] - coords[dst*3+0];
    const float dy = coords[src*3+1] - coords[dst*3+1];
    const float dz = coords[src*3+2] - coords[dst*3+2];
    const float dist = sqrtf(dx*dx + dy*dy + dz*dz + 1e-12f);
    #pragma unroll
    for (int k = 0; k < 16; k++) {
        const float t = 3.2f*dist - 1.0666666667f*(float)k;
        f[14+k] = f2bf(__expf(-t*t));
    }
    f[30] = f2bf(1.0f);
    f[31] = 0;

    const int slot = start[dst] + rank[e];
    short* out = featH + (size_t)slot*32;
    #pragma unroll
    for (int q = 0; q < 4; q++)
        *(short8*)&out[q*8] = *(short8*)&f[q*8];
}

// ---------------------------------------------------------------------------
// gather_mfma v7 (unchanged): 133 us, VALU-bound at its structural floor.
// ---------------------------------------------------------------------------
__global__ __launch_bounds__(256, 2) void gather_mfma(
    const short* __restrict__ featH1, const short* __restrict__ featH2,
    const int* __restrict__ start1, const int* __restrict__ start2,
    const short* __restrict__ WTH, const short* __restrict__ WTL,
    const float* __restrict__ ln_g, const float* __restrict__ ln_b,
    float* __restrict__ h1, float* __restrict__ h2)
{
    __shared__ short sWH[208*40];    // 16.6 KB, stride-40 (80B) rows
    __shared__ short sWL[208*40];    // 16.6 KB
    __shared__ float plane[4][216];

    const int tid = threadIdx.x;
    const int wv = tid >> 6, lane = tid & 63;
    const int arow = lane & 15, aq = lane >> 4;

    // stage W once per block (832 short8 per array)
    for (int f = tid; f < 832; f += 256) {
        const int d = f >> 2, cc = (f & 3) * 8;
        *(short8*)&sWH[d*40 + cc] = *(const short8*)&WTH[f*8];
        *(short8*)&sWL[d*40 + cc] = *(const short8*)&WTL[f*8];
    }
    __syncthreads();

    const int side = blockIdx.y;
    const short* feat = side ? featH2 : featH1;
    const int*  start = side ? start2 : start1;
    float* h = side ? h2 : h1;

    const int c0 = blockIdx.x*16 + wv*4;     // wave's first node (of 4)

    // hoist ln params (lane-mapped)
    const float g0 = ln_g[lane],      bb0 = ln_b[lane];
    const float g1 = ln_g[64+lane],   bb1 = ln_b[64+lane];
    const float g2 = ln_g[128+lane],  bb2 = ln_b[128+lane];
    const float g3 = (lane < 8) ? ln_g[192+lane] : 0.f;
    const float bb3 = (lane < 8) ? ln_b[192+lane] : 0.f;

    // 5 start values for the 4 nodes, one load, then readlane
    const int sidx = (lane < 5) ? lane : 4;
    const int sv = start[c0 + sidx];

    const int lb = arow*40 + aq*8;           // LDS element offset in a W tile

    #pragma unroll 1
    for (int ni = 0; ni < 4; ni++) {
        const int st = __builtin_amdgcn_readlane(sv, ni);
        const int en = __builtin_amdgcn_readlane(sv, ni + 1);
        const int dg = en - st;
        const int node = c0 + ni;
        const size_t hbase = (size_t)node * DH;

        // hoist h RMW loads (consumed at node end, hidden under tiles)
        const float hv0 = h[hbase + lane];
        const float hv1 = h[hbase + 64 + lane];
        const float hv2 = h[hbase + 128 + lane];
        const float hv3 = (lane < 8) ? h[hbase + 192 + lane] : 0.f;

        float colacc[13];
        #pragma unroll
        for (int nt = 0; nt < 13; nt++) colacc[nt] = 0.f;
        float musum = 0.f;

        short8 aC = *(const short8*)&feat[(size_t)(st + arow)*32 + aq*8];

        for (int t0 = 0; t0 < dg; t0 += 16) {
            // prefetch next tile; overshoot lands in next node's rows or the
            // zeroed 16-row pad (start[BN]=EE sentinel) — discarded if unused
            const short8 aN = *(const short8*)&feat[(size_t)(st + t0 + 16 + arow)*32 + aq*8];

            f32x4 acc[13];
            #pragma unroll
            for (int nt = 0; nt < 13; nt++) {
                const short8 whv = *(const short8*)&sWH[nt*640 + lb];
                const short8 wlv = *(const short8*)&sWL[nt*640 + lb];
                f32x4 z = (f32x4){0.f,0.f,0.f,0.f};
                z = __builtin_amdgcn_mfma_f32_16x16x32_bf16(aC, whv, z, 0, 0, 0);
                z = __builtin_amdgcn_mfma_f32_16x16x32_bf16(aC, wlv, z, 0, 0, 0);
                acc[nt] = z;
            }
            // relu + per-row (per-edge) stats; row = t0 + aq*4 + r
            float sr[4] = {0.f,0.f,0.f,0.f}, s2r[4] = {0.f,0.f,0.f,0.f};
            #pragma unroll
            for (int nt = 0; nt < 13; nt++) {
                #pragma unroll
                for (int r = 0; r < 4; r++) {
                    const float v = fmaxf(acc[nt][r], 0.f);
                    acc[nt][r] = v;
                    sr[r] += v; s2r[r] += v*v;
                }
            }
            // 16-lane sum across arow via DPP (VALU-only)
            #pragma unroll
            for (int r = 0; r < 4; r++) {
                sr[r]  = dpp16_sum(sr[r]);
                s2r[r] = dpp16_sum(s2r[r]);
            }
            #pragma unroll
            for (int r = 0; r < 4; r++) {
                const bool valid = (t0 + aq*4 + r) < dg;
                const float mean = sr[r] * (1.0f/DH);
                const float var  = s2r[r] * (1.0f/DH) - mean*mean;
                const float rs   = rsqrtf(var + 1e-5f);
                const float rstd = valid ? rs : 0.f;
                musum += valid ? mean*rs : 0.f;
                #pragma unroll
                for (int nt = 0; nt < 13; nt++)
                    colacc[nt] += rstd*acc[nt][r];
            }
            aC = aN;
        }

        // reduce over the 4 aq groups (rows partition)
        #pragma unroll
        for (int nt = 0; nt < 13; nt++) {
            colacc[nt] += __shfl_xor(colacc[nt], 16, 64);
            colacc[nt] += __shfl_xor(colacc[nt], 32, 64);
        }
        musum += __shfl_xor(musum, 16, 64);
        musum += __shfl_xor(musum, 32, 64);

        if (aq == 0) {
            #pragma unroll
            for (int nt = 0; nt < 13; nt++)
                plane[wv][nt*16 + arow] = colacc[nt];
        }
        // wave-internal LDS producer/consumer: DS pipe is in-order per wave —
        // no barrier (and the next node's writes issue after these reads)

        const float dgf = (float)dg;
        h[hbase + lane]       = hv0 + g0*(plane[wv][lane]     - musum) + dgf*bb0;
        h[hbase + 64 + lane]  = hv1 + g1*(plane[wv][64+lane]  - musum) + dgf*bb1;
        h[hbase + 128 + lane] = hv2 + g2*(plane[wv][128+lane] - musum) + dgf*bb2;
        if (lane < 8)
            h[hbase + 192 + lane] = hv3 + g3*(plane[wv][192+lane] - musum) + dgf*bb3;
    }
}

// ---------------------------------------------------------------------------
// cvt (per half): h fp32 -> hb hi/lo [16384][224] rows + hbT hi/lo [32][224][512]
// ---------------------------------------------------------------------------
__global__ __launch_bounds__(256) void cvt_kernel(
    const float* __restrict__ h1, const float* __restrict__ h2, const int half,
    short* __restrict__ hbH1, short* __restrict__ hbL1,
    short* __restrict__ hbH2, short* __restrict__ hbL2,
    short* __restrict__ hTH1, short* __restrict__ hTL1,
    short* __restrict__ hTH2, short* __restrict__ hTL2)
{
    const int side = blockIdx.y;
    const float* h = side ? h2 : h1;
    short* hbH = side ? hbH2 : hbH1;
    short* hbL = side ? hbL2 : hbL1;
    short* hTH = side ? hTH2 : hTH1;
    short* hTL = side ? hTL2 : hTL1;

    const int nl0 = blockIdx.x * 64;          // local node
    const int bl = nl0 >> 9, m0 = nl0 & 511;
    const int ng0 = half*HBN + nl0;

    __shared__ short tH[64][226];
    __shared__ short tL[64][226];
    const int tid = threadIdx.x;
    for (int i = tid; i < 64*224; i += 256) {
        const int r = i / 224, c = i - r*224;
        const float v = (c < DH) ? h[(size_t)(ng0+r)*DH + c] : 0.f;
        const short hi = f2bf(v);
        const short lo = f2bf(v - bf2f(hi));
        tH[r][c] = hi; tL[r][c] = lo;
        hbH[(size_t)(nl0+r)*224 + c] = hi;
        hbL[(size_t)(nl0+r)*224 + c] = lo;
    }
    __syncthreads();
    for (int i = tid; i < 224*64; i += 256) {
        const int c = i >> 6, m = i & 63;
        const size_t o = ((size_t)bl*224 + c)*NN + m0 + m;
        hTH[o] = tH[m][c];
        hTL[o] = tL[m][c];
    }
}

// ---------------------------------------------------------------------------
// Fused attention v8 (unchanged): 64 Q-rows/block, 512 blocks x 512 thr,
// both dirs in one dispatch, XCD-partitioned.
// ---------------------------------------------------------------------------
__global__ __launch_bounds__(512, 2) void attn_kernel(
    const short* __restrict__ hbH1, const short* __restrict__ hbL1,
    const short* __restrict__ hbH2, const short* __restrict__ hbL2,
    const short* __restrict__ hTH1, const short* __restrict__ hTL1,
    const short* __restrict__ hTH2, const short* __restrict__ hTL2,
    short* __restrict__ cb1, short* __restrict__ cb2)
{
    const int id  = blockIdx.x;                // 0..511
    const int xcd = id & 7, m = id >> 3;       // m 0..63
    const int b2  = m >> 4;                    // 0..3
    const int dir = (m >> 3) & 1;
    const int qb  = m & 7;
    const int b   = xcd*4 + b2;                // half-local batch 0..31
    const int q0  = qb << 6;                   // 64 q-rows

    const short *Qh, *Ql, *Kh, *Kl, *Vh, *Vl;
    short* cb;
    if (dir == 0) {
        Qh = hbH1 + (size_t)b*NN*224;  Ql = hbL1 + (size_t)b*NN*224;
        Kh = hbH2 + (size_t)b*NN*224;  Kl = hbL2 + (size_t)b*NN*224;
        Vh = hTH2 + (size_t)b*224*NN;  Vl = hTL2 + (size_t)b*224*NN;
        cb = cb1;
    } else {
        Qh = hbH2 + (size_t)b*NN*224;  Ql = hbL2 + (size_t)b*NN*224;
        Kh = hbH1 + (size_t)b*NN*224;  Kl = hbL1 + (size_t)b*NN*224;
        Vh = hTH1 + (size_t)b*224*NN;  Vl = hTL1 + (size_t)b*224*NN;
        cb = cb2;
    }

    __shared__ short smem[64*520];            // 65 KB: pb, aliases sQ
    short* sQh = smem;                        // [64][232] = 14848 shorts
    short* sQl = smem + 14848;                // [64][232]
    short* pb  = smem;                        // [64][520]
    __shared__ float sm_[8][64];
    __shared__ float ss_[8][64];

    const int tid = threadIdx.x;
    const int wv = tid >> 6, lane = tid & 63;
    const int arow = lane & 15, aq = lane >> 4;

    // stage Q (64 rows x 224, hi/lo) cooperatively
    for (int i = tid; i < 1792; i += 512) {
        const int rr = i / 28, c = (i - rr*28) * 8;
        *(short8*)&sQh[rr*232 + c] = *(const short8*)&Qh[(size_t)(q0 + rr)*224 + c];
        *(short8*)&sQl[rr*232 + c] = *(const short8*)&Ql[(size_t)(q0 + rr)*224 + c];
    }
    __syncthreads();

    f32x4 acc[4][4];
    #pragma unroll
    for (int g = 0; g < 4; g++)
        #pragma unroll
        for (int t = 0; t < 4; t++) acc[g][t] = (f32x4){0.f,0.f,0.f,0.f};

    const int qb_off = arow*232 + aq*8;
    #pragma unroll 1
    for (int k = 0; k < 7; k++) {
        short8 qh[4], ql[4];
        #pragma unroll
        for (int g = 0; g < 4; g++) {
            qh[g] = *(const short8*)&sQh[qb_off + g*16*232 + k*32];
            ql[g] = *(const short8*)&sQl[qb_off + g*16*232 + k*32];
        }
        #pragma unroll
        for (int t = 0; t < 4; t++) {
            const size_t kb = (size_t)((wv*4 + t)*16 + arow)*224 + k*32 + aq*8;
            const short8 bh = *(const short8*)&Kh[kb];
            const short8 bl = *(const short8*)&Kl[kb];
            #pragma unroll
            for (int g = 0; g < 4; g++) {
                acc[g][t] = __builtin_amdgcn_mfma_f32_16x16x32_bf16(qh[g], bh, acc[g][t], 0, 0, 0);
                acc[g][t] = __builtin_amdgcn_mfma_f32_16x16x32_bf16(qh[g], bl, acc[g][t], 0, 0, 0);
                acc[g][t] = __builtin_amdgcn_mfma_f32_16x16x32_bf16(ql[g], bh, acc[g][t], 0, 0, 0);
            }
        }
    }

    #pragma unroll
    for (int g = 0; g < 4; g++) {
        #pragma unroll
        for (int r2 = 0; r2 < 4; r2++) {
            float mx = -1e30f;
            #pragma unroll
            for (int t = 0; t < 4; t++) {
                acc[g][t][r2] *= T_SCALE;
                mx = fmaxf(mx, acc[g][t][r2]);
            }
            mx = fmaxf(mx, __shfl_xor(mx, 1, 64));
            mx = fmaxf(mx, __shfl_xor(mx, 2, 64));
            mx = fmaxf(mx, __shfl_xor(mx, 4, 64));
            mx = fmaxf(mx, __shfl_xor(mx, 8, 64));
            if (arow == 0) sm_[wv][g*16 + aq*4 + r2] = mx;
        }
    }
    __syncthreads();
    #pragma unroll
    for (int g = 0; g < 4; g++) {
        #pragma unroll
        for (int r2 = 0; r2 < 4; r2++) {
            const int row = g*16 + aq*4 + r2;
            float M = sm_[0][row];
            #pragma unroll
            for (int w = 1; w < 8; w++) M = fmaxf(M, sm_[w][row]);
            float s = 0.f;
            #pragma unroll
            for (int t = 0; t < 4; t++) {
                const float e = __expf(acc[g][t][r2] - M);
                acc[g][t][r2] = e;
                s += e;
            }
            s += __shfl_xor(s, 1, 64);
            s += __shfl_xor(s, 2, 64);
            s += __shfl_xor(s, 4, 64);
            s += __shfl_xor(s, 8, 64);
            if (arow == 0) ss_[wv][row] = s;
        }
    }
    __syncthreads();
    // all waves are past the QK phase (2 barriers above) — safe to overwrite sQ
    #pragma unroll
    for (int g = 0; g < 4; g++) {
        #pragma unroll
        for (int r2 = 0; r2 < 4; r2++) {
            const int row = g*16 + aq*4 + r2;
            float s = ss_[0][row];
            #pragma unroll
            for (int w = 1; w < 8; w++) s += ss_[w][row];
            const float iv = 1.0f / s;
            #pragma unroll
            for (int t = 0; t < 4; t++) {
                const int col = (wv*4 + t)*16 + arow;
                pb[row*520 + col] = f2bf(acc[g][t][r2] * iv);
            }
        }
    }
    __syncthreads();

    const int nbase = (wv < 5) ? 2*wv : 10 + (wv - 5);
    const int ncnt  = (wv < 5) ? 2 : 1;
    f32x4 pacc[4][2];
    #pragma unroll
    for (int g = 0; g < 4; g++)
        #pragma unroll
        for (int t = 0; t < 2; t++) pacc[g][t] = (f32x4){0.f,0.f,0.f,0.f};

    for (int k0 = 0; k0 < NN; k0 += 32) {
        short8 a[4];
        #pragma unroll
        for (int g = 0; g < 4; g++)
            a[g] = *(const short8*)&pb[(g*16 + arow)*520 + k0 + aq*8];
        #pragma unroll
        for (int t = 0; t < 2; t++) {
            if (t < ncnt) {
                const size_t vb = (size_t)((nbase+t)*16 + arow)*NN + k0 + aq*8;
                const short8 bh = *(const short8*)&Vh[vb];
                const short8 bl = *(const short8*)&Vl[vb];
                #pragma unroll
                for (int g = 0; g < 4; g++) {
                    pacc[g][t] = __builtin_amdgcn_mfma_f32_16x16x32_bf16(a[g], bh, pacc[g][t], 0, 0, 0);
                    pacc[g][t] = __builtin_amdgcn_mfma_f32_16x16x32_bf16(a[g], bl, pacc[g][t], 0, 0, 0);
                }
            }
        }
    }

    #pragma unroll
    for (int t = 0; t < 2; t++) {
        if (t < ncnt) {
            const int col = (nbase+t)*16 + arow;
            #pragma unroll
            for (int g = 0; g < 4; g++) {
                #pragma unroll
                for (int r2 = 0; r2 < 4; r2++) {
                    const int row = q0 + g*16 + aq*4 + r2;
                    const short v = (col < DH) ? f2bf(pacc[g][t][r2]) : (short)0;
                    cb[((size_t)b*NN + row)*224 + col] = v;
                }
            }
        }
    }
    if (wv == 7) {
        const int col = 208 + arow;
        #pragma unroll
        for (int g = 0; g < 4; g++) {
            #pragma unroll
            for (int r2 = 0; r2 < 4; r2++) {
                const int row = q0 + g*16 + aq*4 + r2;
                cb[((size_t)b*NN + row)*224 + col] = 0;
            }
        }
    }
}

// ---------------------------------------------------------------------------
// down v2 (512 thr, 128 nodes/block) — unchanged.
// ---------------------------------------------------------------------------
__global__ __launch_bounds__(512, 2) void down_mfma(
    const short* __restrict__ hbH1, const short* __restrict__ hbH2,
    const short* __restrict__ cb1, const short* __restrict__ cb2,
    const int* __restrict__ deg1, const int* __restrict__ deg2,
    const short* __restrict__ WbTH, const short* __restrict__ WbTL,
    const float* __restrict__ degree_table,
    float* __restrict__ hsg1, float* __restrict__ hsg2, const int half)
{
    const int side = blockIdx.y;
    const short* X0 = side ? hbH2 : hbH1;
    const short* X1 = side ? cb2 : cb1;
    const int*   dgp = side ? deg2 : deg1;
    float* hsg = side ? hsg2 : hsg1;

    const int nl0 = blockIdx.x * 128;
    const int ng0 = half*HBN + nl0;
    const int b = ng0 >> 9;

    __shared__ short As[128*40];
    __shared__ short BsH[208*40];
    __shared__ short BsL[208*40];
    __shared__ float part[208];

    const int tid = threadIdx.x;
    const int wv = tid >> 6, lane = tid & 63;
    const int arow = lane & 15, aq = lane >> 4;

    if (tid < 208) part[tid] = 0.f;

    f32x4 acc[13];
    #pragma unroll
    for (int t = 0; t < 13; t++) acc[t] = (f32x4){0.f,0.f,0.f,0.f};

    const int sr = tid >> 2, sc = (tid & 3) * 8;

    for (int phase = 0; phase < 2; phase++) {
        const short* X = phase ? X1 : X0;
        for (int k0 = 0; k0 < 224; k0 += 32) {
            __syncthreads();
            *(short8*)&As[sr*40 + sc] =
                *(const short8*)&X[(size_t)(nl0+sr)*224 + k0 + sc];
            const int kkg = phase*224 + k0;
            #pragma unroll
            for (int pass = 0; pass < 2; pass++) {
                const int f = pass*512 + tid;
                if (f < 832) {
                    const int d = f >> 2, cc = (f & 3) * 8;
                    *(short8*)&BsH[d*40 + cc] = *(const short8*)&WbTH[(size_t)d*448 + kkg + cc];
                    *(short8*)&BsL[d*40 + cc] = *(const short8*)&WbTL[(size_t)d*448 + kkg + cc];
                }
            }
            __syncthreads();
            const short8 a = *(const short8*)&As[(16*wv + arow)*40 + aq*8];
            #pragma unroll
            for (int t = 0; t < 13; t++) {
                const short8 bh = *(const short8*)&BsH[(t*16 + arow)*40 + aq*8];
                const short8 bl = *(const short8*)&BsL[(t*16 + arow)*40 + aq*8];
                acc[t] = __builtin_amdgcn_mfma_f32_16x16x32_bf16(a, bh, acc[t], 0, 0, 0);
                acc[t] = __builtin_amdgcn_mfma_f32_16x16x32_bf16(a, bl, acc[t], 0, 0, 0);
            }
        }
    }
    __syncthreads();

    int dgc[4];
    #pragma unroll
    for (int r = 0; r < 4; r++) {
        int d = dgp[ng0 + 16*wv + aq*4 + r];
        dgc[r] = d > 199 ? 199 : d;
    }
    #pragma unroll
    for (int nt = 0; nt < 13; nt++) {
        const int col = nt*16 + arow;
        float s = 0.f;
        if (col < DH) {
            #pragma unroll
            for (int r = 0; r < 4; r++)
                s += fmaxf(acc[nt][r], 0.f) + degree_table[dgc[r]*DH + col];
        }
        s += __shfl_xor(s, 16, 64);
        s += __shfl_xor(s, 32, 64);
        if (lane < 16 && col < DH) atomicAdd(&part[col], s);
    }
    __syncthreads();
    if (tid < DH) unsafeAtomicAdd(&hsg[b*206 + tid], part[tid] * (1.0f/512.0f));
}

// ---------------------------------------------------------------------------
// Kernel 7: final MLP v2 — float4 broadcast reads of x/y1/y2 (same DS-pipe
// fix as prologue). Accumulation order unchanged (k ascending).
// ---------------------------------------------------------------------------
__global__ __launch_bounds__(256) void mlp_kernel(
    const float* __restrict__ hsg1, const float* __restrict__ hsg2,
    const float* __restrict__ i1, const float* __restrict__ i2,
    const float* __restrict__ W_f1, const float* __restrict__ b_f1,
    const float* __restrict__ W_f2, const float* __restrict__ b_f2,
    const float* __restrict__ W_f3, const float* __restrict__ b_f3,
    const float* __restrict__ W_f4, const float* __restrict__ b_f4,
    float* __restrict__ out)
{
    const int b = blockIdx.x;
    __shared__ float x[620];
    __shared__ float y1[400];
    __shared__ float y2[200];
    __shared__ float y3[100];
    __shared__ float red[256];
    const int tid = threadIdx.x;

    // interaction means (folded inter_kernel); y2 used as scratch pre-layer2
    if (tid < 192) {
        const int j = tid % 6, seg = tid / 6;
        float s1 = 0.f, s2 = 0.f;
        for (int n = seg*16; n < seg*16 + 16; n++) {
            s1 += i1[(size_t)b*NN*DI + n*DI + j];
            s2 += i2[(size_t)b*NN*DI + n*DI + j];
        }
        red[tid] = s1;
        y2[tid] = s2;
    }
    __syncthreads();
    if (tid < 206) {
        float a, bb;
        if (tid < 200) {
            a = hsg1[b*206 + tid]; bb = hsg2[b*206 + tid];
        } else {
            const int j = tid - 200;
            float t1 = 0.f, t2 = 0.f;
            for (int sg = 0; sg < 32; sg++) { t1 += red[sg*6 + j]; t2 += y2[sg*6 + j]; }
            a = t1 * (1.0f/512.0f); bb = t2 * (1.0f/512.0f);
        }
        x[tid] = a; x[206 + tid] = bb; x[412 + tid] = a - bb;
    }
    __syncthreads();
    for (int c = tid; c < 400; c += 256) {
        float acc = b_f1[c];
        for (int k4 = 0; k4 < 154; k4++) {
            const float4 xv = *(const float4*)&x[k4*4];
            const int k = k4*4;
            acc += xv.x*W_f1[(size_t)(k+0)*400 + c];
            acc += xv.y*W_f1[(size_t)(k+1)*400 + c];
            acc += xv.z*W_f1[(size_t)(k+2)*400 + c];
            acc += xv.w*W_f1[(size_t)(k+3)*400 + c];
        }
        acc += x[616]*W_f1[(size_t)616*400 + c];
        acc += x[617]*W_f1[(size_t)617*400 + c];
        y1[c] = fmaxf(acc, 0.0f);
    }
    __syncthreads();
    if (tid < 200) {
        float acc = b_f2[tid];
        for (int k4 = 0; k4 < 100; k4++) {
            const float4 yv = *(const float4*)&y1[k4*4];
            const int k = k4*4;
            acc += yv.x*W_f2[(k+0)*200 + tid];
            acc += yv.y*W_f2[(k+1)*200 + tid];
            acc += yv.z*W_f2[(k+2)*200 + tid];
            acc += yv.w*W_f2[(k+3)*200 + tid];
        }
        y2[tid] = fmaxf(acc, 0.0f);
    }
    __syncthreads();
    if (tid < 100) {
        float acc = b_f3[tid];
        for (int k4 = 0; k4 < 50; k4++) {
            const float4 yv = *(const float4*)&y2[k4*4];
            const int k = k4*4;
            acc += yv.x*W_f3[(k+0)*100 + tid];
            acc += yv.y*W_f3[(k+1)*100 + tid];
            acc += yv.z*W_f3[(k+2)*100 + tid];
            acc += yv.w*W_f3[(k+3)*100 + tid];
        }
        y3[tid] = fmaxf(acc, 0.0f);
    }
    __syncthreads();
    red[tid] = (tid < 100) ? y3[tid]*W_f4[tid] : 0.0f;
    __syncthreads();
    for (int s = 128; s > 0; s >>= 1) {
        if (tid < s) red[tid] += red[tid + s];
        __syncthreads();
    }
    if (tid == 0) out[b] = red[0] + b_f4[0];
}

// ---------------------------------------------------------------------------
extern "C" void kernel_launch(void* const* d_in, const int* in_sizes, int n_in,
                              void* d_out, int out_size, void* d_ws, size_t ws_size,
                              hipStream_t stream)
{
    const float* atom1  = (const float*)d_in[0];
    const float* atom2  = (const float*)d_in[1];
    const float* coords1= (const float*)d_in[2];
    const float* coords2= (const float*)d_in[3];
    const float* efeat1 = (const float*)d_in[4];
    const float* efeat2 = (const float*)d_in[5];
    const float* inter1 = (const float*)d_in[6];
    const float* inter2 = (const float*)d_in[7];
    const int*   esrc1  = (const int*)d_in[8];
    const int*   edst1  = (const int*)d_in[9];
    const int*   esrc2  = (const int*)d_in[10];
    const int*   edst2  = (const int*)d_in[11];
    const float* W_atom = (const float*)d_in[12];
    const float* W_edge = (const float*)d_in[13];
    const float* W_rbf  = (const float*)d_in[14];
    const float* b_rbf  = (const float*)d_in[15];
    const float* ln_g   = (const float*)d_in[16];
    const float* ln_b   = (const float*)d_in[17];
    const float* W_down = (const float*)d_in[18];
    const float* deg_tab= (const float*)d_in[19];
    const float* W_f1   = (const float*)d_in[20];
    const float* b_f1   = (const float*)d_in[21];
    const float* W_f2   = (const float*)d_in[22];
    const float* b_f2   = (const float*)d_in[23];
    const float* W_f3   = (const float*)d_in[24];
    const float* b_f3   = (const float*)d_in[25];
    const float* W_f4   = (const float*)d_in[26];
    const float* b_f4   = (const float*)d_in[27];
    float* out = (float*)d_out;

    // ---- workspace layout (~133 MB)
    float* ws = (float*)d_ws;
    const size_t HSZ = (size_t)BN*DH;              // per-side h floats
    float* h1  = ws;
    float* h2  = h1 + HSZ;
    // pool: max(feat 2*(EE+16)*32 shorts, bf16 pool 10*HB shorts)
    short* pool = (short*)(h2 + HSZ);
    const size_t FSZ = (size_t)(EE+16)*32;
    short* featH1 = pool;
    short* featH2 = featH1 + FSZ;
    const size_t HB = (size_t)32*NN*224;           // 3,670,016 shorts
    short* hbH1 = pool;           short* hbL1 = hbH1 + HB;
    short* hbH2 = hbL1 + HB;      short* hbL2 = hbH2 + HB;
    short* hTH1 = hbL2 + HB;      short* hTL1 = hTH1 + HB;
    short* hTH2 = hTL1 + HB;      short* hTL2 = hTH2 + HB;
    short* cb1  = hTL2 + HB;      short* cb2  = cb1 + HB;
    size_t pool_sz = 2*FSZ > 10*HB ? 2*FSZ : 10*HB;
    short* after = pool + pool_sz;
    short* WTH = after;                            // [208][32]
    short* WTL = WTH + 208*32;
    short* WbTH = WTL + 208*32;                    // [208][448]
    short* WbTL = WbTH + 208*448;
    float* hsg1 = (float*)(WbTL + 208*448);
    float* hsg2 = hsg1 + (size_t)BB*206;
    int* deg1 = (int*)(hsg2 + (size_t)BB*206);
    int* deg2 = deg1 + BN;
    int* start1 = deg2 + BN;                       // BN+1 entries
    int* start2 = start1 + (BN+1);
    int* cursor1 = start2 + (BN+1);                // unused (kept for layout)
    int* cursor2 = cursor1 + BN;
    int* rank1 = cursor2 + BN;
    int* rank2 = rank1 + EE;

    hipMemsetAsync(deg1, 0, 2*(size_t)BN*sizeof(int), stream);
    hipMemsetAsync(hsg1, 0, 2*(size_t)BB*206*sizeof(float), stream);

    // fused: node(16/block) + hist + prep_w + prep_wt(+featpad)
    prologue_kernel<<<6536, 256, 0, stream>>>(
        atom1, atom2, W_atom, ln_g, ln_b, h1, h2,
        edst1, edst2, deg1, deg2, rank1, rank2,
        W_edge, W_rbf, b_rbf, WTH, WTL, featH1, featH2,
        W_down, WbTH, WbTL);

    scan_kernel<<<2, 1024, 0, stream>>>(deg1, deg2, start1, start2);

    featgen_kernel<<<dim3(EE/256, 2), 256, 0, stream>>>(
        efeat1, efeat2, esrc1, esrc2, edst1, edst2, coords1, coords2,
        rank1, rank2, start1, start2, featH1, featH2);

    gather_mfma<<<dim3(BN/16, 2), 256, 0, stream>>>(
        featH1, featH2, start1, start2, WTH, WTL, ln_g, ln_b, h1, h2);

    for (int half = 0; half < 2; half++) {
        cvt_kernel<<<dim3(HBN/64, 2), 256, 0, stream>>>(
            h1, h2, half, hbH1, hbL1, hbH2, hbL2, hTH1, hTL1, hTH2, hTL2);
        // both directions in one dispatch, 64 q-rows per block
        attn_kernel<<<512, 512, 0, stream>>>(
            hbH1, hbL1, hbH2, hbL2, hTH1, hTL1, hTH2, hTL2, cb1, cb2);
        down_mfma<<<dim3(HBN/128, 2), 512, 0, stream>>>(
            hbH1, hbH2, cb1, cb2, deg1, deg2, WbTH, WbTL, deg_tab,
            hsg1, hsg2, half);
    }

    mlp_kernel<<<BB, 256, 0, stream>>>(
        hsg1, hsg2, inter1, inter2,
        W_f1, b_f1, W_f2, b_f2, W_f3, b_f3, W_f4, b_f4, out);
}